// Round 1
// baseline (2372.352 us; speedup 1.0000x reference)
//
#include <hip/hip_runtime.h>

#define EPSF 1e-4f

// ---------------------------------------------------------------- reduce
__device__ __forceinline__ float blockReduceSum(float v, float* red, int nthr){
    int t = threadIdx.x;
    red[t] = v; __syncthreads();
    for (int s = nthr >> 1; s > 0; s >>= 1){
        if (t < s) red[t] += red[t + s];
        __syncthreads();
    }
    float r = red[0]; __syncthreads();
    return r;
}

// ---------------------------------------------------------------- l2norm rows of 256
__global__ void l2norm_kernel(const float* __restrict__ x, float* __restrict__ out, int rows){
    __shared__ float red[256];
    int row = blockIdx.x, t = threadIdx.x;
    float v = x[(long)row*256 + t];
    float s = blockReduceSum(v*v, red, 256);
    float nrm = fmaxf(sqrtf(s), 1e-12f);
    out[(long)row*256 + t] = v / nrm;
}

// ---------------------------------------------------------------- Gram + affinity epilogue
// A[n,m] = exp(-scale*(2-2*dot(nf_n,nf_m))) * (d2x < r2) * (n!=m)
__global__ __launch_bounds__(256) void gram_kernel(const float* __restrict__ nf,
                                                   const float* __restrict__ xyz,
                                                   float* __restrict__ A,
                                                   int N, float r2, float scale){
    __shared__ float sa[32][65], sb[32][65];
    __shared__ float xa[64][3], xb[64][3];
    int tid = threadIdx.x;
    int tx = tid & 15, ty = tid >> 4;
    int n0 = blockIdx.y * 64, m0 = blockIdx.x * 64;
    if (tid < 192){
        xa[tid/3][tid%3] = xyz[(n0 + tid/3)*3 + tid%3];
        xb[tid/3][tid%3] = xyz[(m0 + tid/3)*3 + tid%3];
    }
    float acc[4][4] = {};
    for (int kt = 0; kt < 256; kt += 32){
        #pragma unroll
        for (int p = 0; p < 8; ++p){
            int idx = p*256 + tid;
            int k = idx & 31, i = idx >> 5;
            sa[k][i] = nf[(long)(n0+i)*256 + kt + k];
            sb[k][i] = nf[(long)(m0+i)*256 + kt + k];
        }
        __syncthreads();
        #pragma unroll
        for (int k = 0; k < 32; ++k){
            float a0=sa[k][ty*4+0],a1=sa[k][ty*4+1],a2=sa[k][ty*4+2],a3=sa[k][ty*4+3];
            float b0=sb[k][tx*4+0],b1=sb[k][tx*4+1],b2=sb[k][tx*4+2],b3=sb[k][tx*4+3];
            acc[0][0]+=a0*b0; acc[0][1]+=a0*b1; acc[0][2]+=a0*b2; acc[0][3]+=a0*b3;
            acc[1][0]+=a1*b0; acc[1][1]+=a1*b1; acc[1][2]+=a1*b2; acc[1][3]+=a1*b3;
            acc[2][0]+=a2*b0; acc[2][1]+=a2*b1; acc[2][2]+=a2*b2; acc[2][3]+=a2*b3;
            acc[3][0]+=a3*b0; acc[3][1]+=a3*b1; acc[3][2]+=a3*b2; acc[3][3]+=a3*b3;
        }
        __syncthreads();
    }
    #pragma unroll
    for (int r = 0; r < 4; ++r){
        #pragma unroll
        for (int c = 0; c < 4; ++c){
            int n = n0 + ty*4 + r, m = m0 + tx*4 + c;
            float dx = xa[ty*4+r][0]-xb[tx*4+c][0];
            float dy = xa[ty*4+r][1]-xb[tx*4+c][1];
            float dz = xa[ty*4+r][2]-xb[tx*4+c][2];
            float d2x = dx*dx + dy*dy + dz*dz;
            float val = 0.f;
            if (d2x < r2 && n != m) val = expf(-scale*(2.f - 2.f*acc[r][c]));
            A[(long)n*N + m] = val;
        }
    }
}

// ---------------------------------------------------------------- row sums -> dinv
__global__ void rowsum_kernel(const float* __restrict__ A, float* __restrict__ dinv, int N){
    __shared__ float red[256];
    int n = blockIdx.x, t = threadIdx.x;
    float s = 0.f;
    for (int m = t; m < N; m += 256) s += A[(long)n*N + m];
    s = blockReduceSum(s, red, 256);
    if (t == 0) dinv[n] = rsqrtf(s + EPSF);
}

// ---------------------------------------------------------------- out[n,c] = X[n,c]*dinv[n]
__global__ void scale_rows_kernel(const float* __restrict__ X, const float* __restrict__ dinv,
                                  float* __restrict__ out, int N, int C){
    long idx = (long)blockIdx.x*256 + threadIdx.x;
    if (idx < (long)N*C) out[idx] = X[idx] * dinv[idx / C];
}

// ---------------------------------------------------------------- Y += A @ Xs (split-K, C=256)
__global__ __launch_bounds__(256) void gemm_AXs_kernel(const float* __restrict__ A,
                                                       const float* __restrict__ Xs,
                                                       float* __restrict__ Y,
                                                       int N, int split){
    __shared__ float sa[32][65], sb[32][65];
    int tid = threadIdx.x, tx = tid & 15, ty = tid >> 4;
    int c0 = blockIdx.x * 64, n0 = blockIdx.y * 64;
    int L = N / split, mstart = blockIdx.z * L;
    float acc[4][4] = {};
    for (int mt = mstart; mt < mstart + L; mt += 32){
        #pragma unroll
        for (int p = 0; p < 8; ++p){
            int idx = p*256 + tid;
            int k = idx & 31, i = idx >> 5;
            sa[k][i] = A[(long)(n0+i)*N + mt + k];
            int j = idx & 63, kk = idx >> 6;
            sb[kk][j] = Xs[(long)(mt+kk)*256 + c0 + j];
        }
        __syncthreads();
        #pragma unroll
        for (int k = 0; k < 32; ++k){
            float a0=sa[k][ty*4+0],a1=sa[k][ty*4+1],a2=sa[k][ty*4+2],a3=sa[k][ty*4+3];
            float b0=sb[k][tx*4+0],b1=sb[k][tx*4+1],b2=sb[k][tx*4+2],b3=sb[k][tx*4+3];
            acc[0][0]+=a0*b0; acc[0][1]+=a0*b1; acc[0][2]+=a0*b2; acc[0][3]+=a0*b3;
            acc[1][0]+=a1*b0; acc[1][1]+=a1*b1; acc[1][2]+=a1*b2; acc[1][3]+=a1*b3;
            acc[2][0]+=a2*b0; acc[2][1]+=a2*b1; acc[2][2]+=a2*b2; acc[2][3]+=a2*b3;
            acc[3][0]+=a3*b0; acc[3][1]+=a3*b1; acc[3][2]+=a3*b2; acc[3][3]+=a3*b3;
        }
        __syncthreads();
    }
    #pragma unroll
    for (int r = 0; r < 4; ++r)
        #pragma unroll
        for (int c = 0; c < 4; ++c)
            atomicAdd(&Y[(long)(n0+ty*4+r)*256 + c0+tx*4+c], acc[r][c]);
}

// ---------------------------------------------------------------- generic X(R,Ci) @ W(Ci,Co) + bias [relu]
__global__ __launch_bounds__(256) void gemm_XW_kernel(const float* __restrict__ X,
                                                      const float* __restrict__ W,
                                                      const float* __restrict__ bias,
                                                      float* __restrict__ out,
                                                      int R, int Ci, int Co, int relu){
    __shared__ float sa[32][65], sb[32][65];
    int tid = threadIdx.x, tx = tid & 15, ty = tid >> 4;
    int c0 = blockIdx.x * 64, r0 = blockIdx.y * 64;
    float acc[4][4] = {};
    for (int kt = 0; kt < Ci; kt += 32){
        #pragma unroll
        for (int p = 0; p < 8; ++p){
            int idx = p*256 + tid;
            int k = idx & 31, i = idx >> 5;
            int rr = r0 + i;
            sa[k][i] = (rr < R) ? X[(long)rr*Ci + kt + k] : 0.f;
            int j = idx & 63, kk = idx >> 6;
            int cc = c0 + j;
            sb[kk][j] = (cc < Co) ? W[(long)(kt+kk)*Co + cc] : 0.f;
        }
        __syncthreads();
        #pragma unroll
        for (int k = 0; k < 32; ++k){
            float a0=sa[k][ty*4+0],a1=sa[k][ty*4+1],a2=sa[k][ty*4+2],a3=sa[k][ty*4+3];
            float b0=sb[k][tx*4+0],b1=sb[k][tx*4+1],b2=sb[k][tx*4+2],b3=sb[k][tx*4+3];
            acc[0][0]+=a0*b0; acc[0][1]+=a0*b1; acc[0][2]+=a0*b2; acc[0][3]+=a0*b3;
            acc[1][0]+=a1*b0; acc[1][1]+=a1*b1; acc[1][2]+=a1*b2; acc[1][3]+=a1*b3;
            acc[2][0]+=a2*b0; acc[2][1]+=a2*b1; acc[2][2]+=a2*b2; acc[2][3]+=a2*b3;
            acc[3][0]+=a3*b0; acc[3][1]+=a3*b1; acc[3][2]+=a3*b2; acc[3][3]+=a3*b3;
        }
        __syncthreads();
    }
    #pragma unroll
    for (int r = 0; r < 4; ++r){
        #pragma unroll
        for (int c = 0; c < 4; ++c){
            int rr = r0 + ty*4 + r, cc = c0 + tx*4 + c;
            if (rr < R && cc < Co){
                float v = acc[r][c] + (bias ? bias[cc] : 0.f);
                if (relu) v = fmaxf(v, 0.f);
                out[(long)rr*Co + cc] = v;
            }
        }
    }
}

// ---------------------------------------------------------------- row softmax (K<=64), in place, logits/tau
__global__ void softmax_kernel(float* __restrict__ x, int Kc, float tau){
    int row = blockIdx.x, lane = threadIdx.x;
    bool act = lane < Kc;
    float v = act ? x[(long)row*Kc + lane] / tau : -1e30f;
    float mx = v;
    #pragma unroll
    for (int o = 32; o; o >>= 1) mx = fmaxf(mx, __shfl_xor(mx, o, 64));
    float e = act ? expf(v - mx) : 0.f;
    float s = e;
    #pragma unroll
    for (int o = 32; o; o >>= 1) s += __shfl_xor(s, o, 64);
    if (act) x[(long)row*Kc + lane] = e / s;
}

// ---------------------------------------------------------------- cluster xyz sums + denom (raw)
__global__ void cluster_xyz_kernel(const float* __restrict__ s, const float* __restrict__ xyz,
                                   float* __restrict__ outx, float* __restrict__ outd,
                                   int N, int Kc, int xBS, int dBS){
    __shared__ float red[256];
    int b = blockIdx.y, k = blockIdx.x, t = threadIdx.x;
    s   += (long)b*N*Kc;
    xyz += (long)b*N*3;
    float a0=0,a1=0,a2=0,ad=0;
    for (int n = t; n < N; n += 256){
        float sv = s[(long)n*Kc + k];
        ad += sv;
        a0 += sv*xyz[n*3+0]; a1 += sv*xyz[n*3+1]; a2 += sv*xyz[n*3+2];
    }
    a0 = blockReduceSum(a0, red, 256);
    a1 = blockReduceSum(a1, red, 256);
    a2 = blockReduceSum(a2, red, 256);
    ad = blockReduceSum(ad, red, 256);
    if (t == 0){
        outx[b*xBS + k*3+0] = a0;
        outx[b*xBS + k*3+1] = a1;
        outx[b*xBS + k*3+2] = a2;
        outd[b*dBS + k] = ad;
    }
}

// ---------------------------------------------------------------- out[k,c] += s^T @ X  (split over n, C=256)
__global__ __launch_bounds__(256) void gemm_sTX_kernel(const float* __restrict__ s,
                                                       const float* __restrict__ X,
                                                       float* __restrict__ out,
                                                       int N, int Kc, int split,
                                                       long sBS, long xBS, long oBS){
    __shared__ float sa[32][65], sb[32][65];
    int tid = threadIdx.x, tx = tid & 15, ty = tid >> 4;
    int c0 = blockIdx.x * 64;
    int b = blockIdx.z / split, chunk = blockIdx.z % split;
    int L = N / split, nst = chunk * L;
    s += b*sBS; X += b*xBS; out += b*oBS;
    float acc[4][4] = {};
    for (int nt = nst; nt < nst + L; nt += 32){
        #pragma unroll
        for (int p = 0; p < 8; ++p){
            int idx = p*256 + tid;
            int i = idx & 63, k = idx >> 6;
            sa[k][i] = (i < Kc) ? s[(long)(nt+k)*Kc + i] : 0.f;
            int j = idx & 63, kk = idx >> 6;
            sb[kk][j] = X[(long)(nt+kk)*256 + c0 + j];
        }
        __syncthreads();
        #pragma unroll
        for (int k = 0; k < 32; ++k){
            float a0=sa[k][ty*4+0],a1=sa[k][ty*4+1],a2=sa[k][ty*4+2],a3=sa[k][ty*4+3];
            float b0=sb[k][tx*4+0],b1=sb[k][tx*4+1],b2=sb[k][tx*4+2],b3=sb[k][tx*4+3];
            acc[0][0]+=a0*b0; acc[0][1]+=a0*b1; acc[0][2]+=a0*b2; acc[0][3]+=a0*b3;
            acc[1][0]+=a1*b0; acc[1][1]+=a1*b1; acc[1][2]+=a1*b2; acc[1][3]+=a1*b3;
            acc[2][0]+=a2*b0; acc[2][1]+=a2*b1; acc[2][2]+=a2*b2; acc[2][3]+=a2*b3;
            acc[3][0]+=a3*b0; acc[3][1]+=a3*b1; acc[3][2]+=a3*b2; acc[3][3]+=a3*b3;
        }
        __syncthreads();
    }
    #pragma unroll
    for (int r = 0; r < 4; ++r){
        int kc = ty*4 + r;
        if (kc < Kc){
            #pragma unroll
            for (int c = 0; c < 4; ++c)
                atomicAdd(&out[(long)kc*256 + c0 + tx*4 + c], acc[r][c]);
        }
    }
}

// ---------------------------------------------------------------- divide cluster sums by denom+EPS
__global__ void divide_kernel(float* __restrict__ cfea, float* __restrict__ cxyz,
                              const float* __restrict__ den, int fBS, int xBS, int dBS){
    int b = blockIdx.y, k = blockIdx.x, t = threadIdx.x;
    float d = den[b*dBS + k] + EPSF;
    cfea[(long)b*fBS + k*256 + t] /= d;
    if (t < 3) cxyz[b*xBS + k*3 + t] /= d;
}

// ---------------------------------------------------------------- per-point level losses
// scal[0] += inv*(sum_k s*d2 + 1 - exp(-d2min/2));  scal[ndsSlot] += sum_c (l2norm(c2p)-nf)^2
__global__ __launch_bounds__(256) void level_loss_kernel(const float* __restrict__ s,
                                                         const float* __restrict__ pxyz,
                                                         const float* __restrict__ cxyz,
                                                         const float* __restrict__ cfea,
                                                         const float* __restrict__ nf,
                                                         float* __restrict__ scal,
                                                         int N, float inv, int ndsSlot){
    __shared__ float sl[64], cx[192], red[256];
    int b = blockIdx.y, n = blockIdx.x, t = threadIdx.x;
    s    += (long)b*N*64;
    pxyz += (long)b*N*3;
    nf   += (long)b*N*256;
    cxyz += (long)b*384;      // stride 128*3
    cfea += (long)b*32768;    // stride 128*256
    if (t < 64)  sl[t] = s[(long)n*64 + t];
    if (t < 192) cx[t] = cxyz[t];
    __syncthreads();
    float assv = 0.f, dm = 1e30f;
    if (t < 64){
        float dx = pxyz[n*3+0]-cx[t*3+0];
        float dy = pxyz[n*3+1]-cx[t*3+1];
        float dz = pxyz[n*3+2]-cx[t*3+2];
        float d2 = dx*dx + dy*dy + dz*dz;
        assv = sl[t]*d2; dm = d2;
    }
    float assSum = blockReduceSum(assv, red, 256);
    red[t] = dm; __syncthreads();
    for (int st = 128; st; st >>= 1){ if (t < st) red[t] = fminf(red[t], red[t+st]); __syncthreads(); }
    float dmin = red[0]; __syncthreads();
    float c2p = 0.f;
    #pragma unroll
    for (int k = 0; k < 64; ++k) c2p += sl[k]*cfea[k*256 + t];
    float nrm2 = blockReduceSum(c2p*c2p, red, 256);
    float nrm = fmaxf(sqrtf(nrm2), 1e-12f);
    float diff = c2p/nrm - nf[(long)n*256 + t];
    float nds = blockReduceSum(diff*diff, red, 256);
    if (t == 0){
        atomicAdd(&scal[0], inv*(assSum + 1.f - expf(-0.5f*dmin)));
        atomicAdd(&scal[ndsSlot], nds);
    }
}

// ---------------------------------------------------------------- knn affinity -> normalized adjacency (128 pts)
__global__ void knn_nac_kernel(const float* __restrict__ cxyz, float* __restrict__ nac){
    __shared__ float x[128][3];
    __shared__ float di[128];
    int b = blockIdx.x, n = threadIdx.x;
    x[n][0] = cxyz[b*384 + n*3+0];
    x[n][1] = cxyz[b*384 + n*3+1];
    x[n][2] = cxyz[b*384 + n*3+2];
    __syncthreads();
    float* Ab = nac + (long)b*16384;
    float xn0 = x[n][0], xn1 = x[n][1], xn2 = x[n][2];
    float last = -1.f;
    for (int p = 0; p < 8; ++p){
        float cur = 1e30f;
        for (int m = 0; m < 128; ++m){
            float dx = xn0-x[m][0], dy = xn1-x[m][1], dz = xn2-x[m][2];
            float d2 = dx*dx+dy*dy+dz*dz + (m==n ? 1e6f : 0.f);
            if (d2 > last && d2 < cur) cur = d2;
        }
        last = cur;
    }
    for (int m = 0; m < 128; ++m){
        float dx = xn0-x[m][0], dy = xn1-x[m][1], dz = xn2-x[m][2];
        float d2 = dx*dx+dy*dy+dz*dz;
        float v = (m != n && d2 <= last) ? expf(-d2) : 0.f;
        Ab[n*128 + m] = v;
    }
    __syncthreads();
    for (int m = 0; m < 128; ++m){
        float mx = fmaxf(Ab[n*128+m], Ab[m*128+n]);   // idempotent benign race
        Ab[n*128+m] = mx;
    }
    __syncthreads();
    float deg = 0.f;
    for (int m = 0; m < 128; ++m) deg += Ab[n*128+m];
    di[n] = rsqrtf(deg + EPSF);
    __syncthreads();
    for (int m = 0; m < 128; ++m) Ab[n*128+m] *= di[n]*di[m];
}

// ---------------------------------------------------------------- Y2 = na_c @ cfea  (128x128 @ 128x256)
__global__ void bmm_small_kernel(const float* __restrict__ nac, const float* __restrict__ cfea,
                                 float* __restrict__ Y2){
    __shared__ float row[128];
    int b = blockIdx.y, n = blockIdx.x, t = threadIdx.x;
    if (t < 128) row[t] = nac[(long)b*16384 + n*128 + t];
    __syncthreads();
    float acc = 0.f;
    #pragma unroll 4
    for (int k = 0; k < 128; ++k) acc += row[k]*cfea[(long)b*32768 + k*256 + t];
    Y2[(long)b*32768 + n*256 + t] = acc;
}

// ---------------------------------------------------------------- cut_loss_c
__global__ void cutc_kernel(const float* __restrict__ gs, const float* __restrict__ cxyz,
                            const float* __restrict__ cxyzg, float* __restrict__ scal, float inv){
    __shared__ float cg[48];
    __shared__ float red[128];
    int b = blockIdx.x, t = threadIdx.x;
    if (t < 48) cg[t] = cxyzg[b*48 + t];
    __syncthreads();
    float x0 = cxyz[b*384 + t*3+0], x1 = cxyz[b*384 + t*3+1], x2 = cxyz[b*384 + t*3+2];
    float acc = 0.f;
    #pragma unroll
    for (int k = 0; k < 16; ++k){
        float dx = x0-cg[k*3+0], dy = x1-cg[k*3+1], dz = x2-cg[k*3+2];
        acc += gs[b*2048 + t*16 + k]*(dx*dx+dy*dy+dz*dz);
    }
    acc = blockReduceSum(acc, red, 128);
    if (t == 0) atomicAdd(&scal[0], acc*inv);
}

// ---------------------------------------------------------------- cross attention (M=16, heads=4, dh=64)
__global__ __launch_bounds__(256) void attn_kernel(const float* __restrict__ q,
                                                   const float* __restrict__ kk,
                                                   const float* __restrict__ vv,
                                                   float* __restrict__ out){
    __shared__ float Ks[16][256], Vs[16][256];
    int b = blockIdx.y, n = blockIdx.x, t = threadIdx.x;
    #pragma unroll
    for (int p = 0; p < 16; ++p){
        int j = p*256 + t;
        Ks[j>>8][j&255] = kk[b*4096 + j];
        Vs[j>>8][j&255] = vv[b*4096 + j];
    }
    __syncthreads();
    float qv = q[((long)b*1024 + n)*256 + t];
    float sc[16];
    #pragma unroll
    for (int m = 0; m < 16; ++m){
        float v = qv * Ks[m][t];
        #pragma unroll
        for (int o = 32; o; o >>= 1) v += __shfl_xor(v, o, 64);
        sc[m] = v * 0.125f;
    }
    float mx = -1e30f;
    #pragma unroll
    for (int m = 0; m < 16; ++m) mx = fmaxf(mx, sc[m]);
    float sum = 0.f;
    #pragma unroll
    for (int m = 0; m < 16; ++m){ sc[m] = expf(sc[m]-mx); sum += sc[m]; }
    float o = 0.f;
    #pragma unroll
    for (int m = 0; m < 16; ++m) o += sc[m]*Vs[m][t];
    out[((long)b*1024 + n)*256 + t] = o / sum * 1.0f; // attn normalized below
}

// ---------------------------------------------------------------- quad for ass_loss (N=1024, per batch)
__global__ void quad_kernel(const float* __restrict__ A, const float* __restrict__ dinv,
                            const float* __restrict__ xyz, float* __restrict__ scal){
    __shared__ float red[256];
    int n = blockIdx.x, t = threadIdx.x;
    float a0=0,a1=0,a2=0;
    for (int m = t; m < 1024; m += 256){
        float w = A[(long)n*1024 + m]*dinv[m];
        a0 += w*xyz[m*3+0]; a1 += w*xyz[m*3+1]; a2 += w*xyz[m*3+2];
    }
    a0 = blockReduceSum(a0, red, 256);
    a1 = blockReduceSum(a1, red, 256);
    a2 = blockReduceSum(a2, red, 256);
    if (t == 0){
        float x0 = xyz[n*3+0], x1 = xyz[n*3+1], x2 = xyz[n*3+2];
        float contrib = (x0*x0+x1*x1+x2*x2) - dinv[n]*(x0*a0+x1*a1+x2*a2);
        atomicAdd(&scal[4], contrib);
    }
}

// ---------------------------------------------------------------- g_loss per-row term
__global__ void gloss_kernel(const float* __restrict__ agg, const float* __restrict__ gfea,
                             float* __restrict__ scal){
    __shared__ float red[256];
    int b = blockIdx.y, n = blockIdx.x, t = threadIdx.x;
    long base = ((long)b*1024 + n)*256 + t;
    float a = agg[base], g = gfea[base];
    float na2 = blockReduceSum(a*a, red, 256);
    float ng2 = blockReduceSum(g*g, red, 256);
    float nA = fmaxf(sqrtf(na2), 1e-12f), nG = fmaxf(sqrtf(ng2), 1e-12f);
    float diff = a/nA - g/nG;
    float d2 = blockReduceSum(diff*diff, red, 256);
    if (t == 0) atomicAdd(&scal[3], sqrtf(d2));
}

// ---------------------------------------------------------------- finalize scalars
__global__ void finalize_kernel(const float* __restrict__ scal, float* __restrict__ out){
    out[524288] = scal[0] + sqrtf(scal[1]) + sqrtf(scal[2]);
    out[524289] = scal[3]*0.5f + 1e-4f*scal[4]/2048.0f;
}

// ================================================================ launcher
extern "C" void kernel_launch(void* const* d_in, const int* in_sizes, int n_in,
                              void* d_out, int out_size, void* d_ws, size_t ws_size,
                              hipStream_t stream){
    const float* g_fea   = (const float*)d_in[0];
    const float* g_xyz   = (const float*)d_in[1];
    const float* p_fea_0 = (const float*)d_in[2];
    const float* p_xyz_0 = (const float*)d_in[3];
    const float* p_fea_1 = (const float*)d_in[4];
    const float* p_xyz_1 = (const float*)d_in[5];
    const float* lW1 = (const float*)d_in[6];
    const float* lb1 = (const float*)d_in[7];
    const float* lW2 = (const float*)d_in[8];
    const float* lb2 = (const float*)d_in[9];
    const float* gW1 = (const float*)d_in[10];
    const float* gb1 = (const float*)d_in[11];
    const float* gW2 = (const float*)d_in[12];
    const float* gb2 = (const float*)d_in[13];
    const float* Wq = (const float*)d_in[14];
    const float* Wk = (const float*)d_in[15];
    const float* Wv = (const float*)d_in[16];
    const float* Wo = (const float*)d_in[17];
    float* out = (float*)d_out;
    float* ws_f = (float*)d_ws;

    // ---- workspace layout (floats)
    constexpr long O_SCAL = 0;                       // 16 scalar slots
    constexpr long O_CFEA = 16;                      // (B,128,256) zeroed (atomic target)
    constexpr long O_CXYZ = O_CFEA + 2L*128*256;     // (B,128,3)
    constexpr long O_DEN  = O_CXYZ + 2L*128*3;       // (B,128)
    constexpr long O_CFG  = O_DEN  + 2L*128;         // (B,16,256) zeroed (atomic target)
    constexpr long O_CXG  = O_CFG  + 2L*16*256;      // (B,16,3)
    constexpr long O_DENG = O_CXG  + 2L*16*3;        // (B,16)
    constexpr long O_ZEND = O_DENG + 2L*16;
    constexpr long O_NF   = O_ZEND;                  // (2*4096,256)
    constexpr long O_XS   = O_NF   + 2L*4096*256;
    constexpr long O_Y    = O_XS   + 2L*4096*256;
    constexpr long O_H    = O_Y    + 2L*4096*256;    // (2N,128)
    constexpr long O_S    = O_H    + 2L*4096*128;    // (2N,64)
    constexpr long O_DINV = O_S    + 2L*4096*64;     // (2*4096)
    constexpr long O_A    = O_DINV + 2L*4096;        // (4096,4096) single batch
    constexpr long O_Q    = O_A    + 4096L*4096;
    constexpr long O_AO   = O_Q    + 2L*1024*256;
    constexpr long O_KK   = O_AO   + 2L*1024*256;
    constexpr long O_VV   = O_KK   + 32L*256;
    constexpr long O_NAC  = O_VV   + 32L*256;        // (B,128,128)
    constexpr long O_Y2   = O_NAC  + 2L*128*128;     // (B,128,256)
    constexpr long O_H2   = O_Y2   + 2L*128*256;     // (B*128,128)
    constexpr long O_LG2  = O_H2   + 2L*128*128;     // (B*128,16) -> gs in place

    hipMemsetAsync(ws_f + O_SCAL, 0, (size_t)O_ZEND*sizeof(float), stream);

    struct Lvl { const float* fea; const float* xyz; int N; int k0; int ndsSlot; };
    Lvl lv[2] = {{p_fea_0, p_xyz_0, 4096, 0, 1}, {p_fea_1, p_xyz_1, 2048, 64, 2}};

    float* nf   = ws_f + O_NF;
    float* Xs   = ws_f + O_XS;
    float* Yb   = ws_f + O_Y;
    float* hb   = ws_f + O_H;
    float* sb   = ws_f + O_S;
    float* dinv = ws_f + O_DINV;
    float* A    = ws_f + O_A;

    for (int L = 0; L < 2; ++L){
        int N = lv[L].N;
        const float* fea = lv[L].fea;
        const float* xyz = lv[L].xyz;
        l2norm_kernel<<<2*N, 256, 0, stream>>>(fea, nf, 2*N);
        for (int b = 0; b < 2; ++b){
            const float* nfb  = nf + (long)b*N*256;
            const float* xyzb = xyz + (long)b*N*3;
            gram_kernel<<<dim3(N/64, N/64), 256, 0, stream>>>(nfb, xyzb, A, N, 1.0f, 0.25f);
            rowsum_kernel<<<N, 256, 0, stream>>>(A, dinv + b*N, N);
            scale_rows_kernel<<<(N*256+255)/256, 256, 0, stream>>>(fea + (long)b*N*256, dinv + b*N,
                                                                   Xs + (long)b*N*256, N, 256);
            hipMemsetAsync(Yb + (long)b*N*256, 0, (size_t)N*256*sizeof(float), stream);
            gemm_AXs_kernel<<<dim3(4, N/64, 4), 256, 0, stream>>>(A, Xs + (long)b*N*256,
                                                                  Yb + (long)b*N*256, N, 4);
            scale_rows_kernel<<<(N*256+255)/256, 256, 0, stream>>>(Yb + (long)b*N*256, dinv + b*N,
                                                                   Yb + (long)b*N*256, N, 256);
        }
        gemm_XW_kernel<<<dim3(2, 2*N/64), 256, 0, stream>>>(Yb, lW1, lb1, hb, 2*N, 256, 128, 1);
        gemm_XW_kernel<<<dim3(1, 2*N/64), 256, 0, stream>>>(hb, lW2, lb2, sb, 2*N, 128, 64, 0);
        softmax_kernel<<<2*N, 64, 0, stream>>>(sb, 64, 0.1f);
        cluster_xyz_kernel<<<dim3(64, 2), 256, 0, stream>>>(sb, xyz, ws_f + O_CXYZ + lv[L].k0*3,
                                                            ws_f + O_DEN + lv[L].k0, N, 64, 384, 128);
        gemm_sTX_kernel<<<dim3(4, 1, 16), 256, 0, stream>>>(sb, fea, ws_f + O_CFEA + lv[L].k0*256,
                                                            N, 64, 8, (long)N*64, (long)N*256, 128L*256);
        divide_kernel<<<dim3(64, 2), 256, 0, stream>>>(ws_f + O_CFEA + lv[L].k0*256,
                                                       ws_f + O_CXYZ + lv[L].k0*3,
                                                       ws_f + O_DEN + lv[L].k0, 128*256, 384, 128);
        level_loss_kernel<<<dim3(N, 2), 256, 0, stream>>>(sb, xyz, ws_f + O_CXYZ + lv[L].k0*3,
                                                          ws_f + O_CFEA + lv[L].k0*256, nf,
                                                          ws_f + O_SCAL, N, 1.0f/(2.0f*N), lv[L].ndsSlot);
    }

    // ---- global cluster stage
    knn_nac_kernel<<<2, 128, 0, stream>>>(ws_f + O_CXYZ, ws_f + O_NAC);
    bmm_small_kernel<<<dim3(128, 2), 256, 0, stream>>>(ws_f + O_NAC, ws_f + O_CFEA, ws_f + O_Y2);
    gemm_XW_kernel<<<dim3(2, 4), 256, 0, stream>>>(ws_f + O_Y2, gW1, gb1, ws_f + O_H2, 256, 256, 128, 1);
    gemm_XW_kernel<<<dim3(1, 4), 256, 0, stream>>>(ws_f + O_H2, gW2, gb2, ws_f + O_LG2, 256, 128, 16, 0);
    softmax_kernel<<<256, 64, 0, stream>>>(ws_f + O_LG2, 16, 0.1f);
    cluster_xyz_kernel<<<dim3(16, 2), 256, 0, stream>>>(ws_f + O_LG2, ws_f + O_CXYZ,
                                                        ws_f + O_CXG, ws_f + O_DENG, 128, 16, 48, 16);
    gemm_sTX_kernel<<<dim3(4, 1, 2), 256, 0, stream>>>(ws_f + O_LG2, ws_f + O_CFEA, ws_f + O_CFG,
                                                       128, 16, 1, 128L*16, 128L*256, 16L*256);
    divide_kernel<<<dim3(16, 2), 256, 0, stream>>>(ws_f + O_CFG, ws_f + O_CXG, ws_f + O_DENG,
                                                   16*256, 48, 16);
    cutc_kernel<<<2, 128, 0, stream>>>(ws_f + O_LG2, ws_f + O_CXYZ, ws_f + O_CXG,
                                       ws_f + O_SCAL, 1.0f/256.0f);

    // ---- cross attention
    gemm_XW_kernel<<<dim3(4, 32), 256, 0, stream>>>(g_fea, Wq, nullptr, ws_f + O_Q, 2048, 256, 256, 0);
    gemm_XW_kernel<<<dim3(4, 1), 256, 0, stream>>>(ws_f + O_CFG, Wk, nullptr, ws_f + O_KK, 32, 256, 256, 0);
    gemm_XW_kernel<<<dim3(4, 1), 256, 0, stream>>>(ws_f + O_CFG, Wv, nullptr, ws_f + O_VV, 32, 256, 256, 0);
    attn_kernel<<<dim3(1024, 2), 256, 0, stream>>>(ws_f + O_Q, ws_f + O_KK, ws_f + O_VV, ws_f + O_AO);
    gemm_XW_kernel<<<dim3(4, 32), 256, 0, stream>>>(ws_f + O_AO, Wo, nullptr, out, 2048, 256, 256, 0);

    // ---- A_g stage (reuse nf, A, dinv)
    l2norm_kernel<<<2048, 256, 0, stream>>>(g_fea, nf, 2048);
    for (int b = 0; b < 2; ++b){
        gram_kernel<<<dim3(16, 16), 256, 0, stream>>>(nf + (long)b*1024*256, g_xyz + (long)b*1024*3,
                                                      A, 1024, 16.0f, 0.25f);
        rowsum_kernel<<<1024, 256, 0, stream>>>(A, dinv + b*1024, 1024);
        quad_kernel<<<1024, 256, 0, stream>>>(A, dinv + b*1024, g_xyz + (long)b*1024*3, ws_f + O_SCAL);
    }

    gloss_kernel<<<dim3(1024, 2), 256, 0, stream>>>(out, g_fea, ws_f + O_SCAL);
    finalize_kernel<<<1, 1, 0, stream>>>(ws_f + O_SCAL, out);
}

// Round 3
// 1124.960 us; speedup vs baseline: 2.1088x; 2.1088x over previous
//
#include <hip/hip_runtime.h>

#define EPSF 1e-4f

typedef __attribute__((ext_vector_type(8))) short bf16x8;
typedef __attribute__((ext_vector_type(4))) float f32x4;

__device__ __forceinline__ unsigned short f2bf(float f){
    unsigned int u = __float_as_uint(f);
    return (unsigned short)((u + 0x7FFF + ((u >> 16) & 1)) >> 16);
}
__device__ __forceinline__ float bf2f(unsigned short u){
    return __uint_as_float(((unsigned int)u) << 16);
}
__device__ __forceinline__ float waveSum(float v){
    #pragma unroll
    for (int o = 32; o; o >>= 1) v += __shfl_xor(v, o, 64);
    return v;
}
__device__ __forceinline__ float waveMin(float v){
    #pragma unroll
    for (int o = 32; o; o >>= 1) v = fminf(v, __shfl_xor(v, o, 64));
    return v;
}
__device__ __forceinline__ float blockReduceSum(float v, float* red, int nthr){
    int t = threadIdx.x;
    red[t] = v; __syncthreads();
    for (int s = nthr >> 1; s > 0; s >>= 1){
        if (t < s) red[t] += red[t + s];
        __syncthreads();
    }
    float r = red[0]; __syncthreads();
    return r;
}

// ---------------------------------------------------------------- l2norm rows of 256 -> f32 + bf16
__global__ void l2norm_kernel(const float* __restrict__ x, float* __restrict__ outf,
                              unsigned short* __restrict__ outb, int rows){
    __shared__ float red[256];
    int row = blockIdx.x, t = threadIdx.x;
    float v = x[(long)row*256 + t];
    float s = blockReduceSum(v*v, red, 256);
    float nrm = fmaxf(sqrtf(s), 1e-12f);
    float r = v / nrm;
    outf[(long)row*256 + t] = r;
    outb[(long)row*256 + t] = f2bf(r);
}

// ---------------------------------------------------------------- MFMA gram: A = exp(scale*(2dot-2)) * mask, bf16 out
// tile 128x128, 4 waves (2x2 of 64x64), K=256
__global__ __launch_bounds__(256) void gram_mfma_kernel(const unsigned short* __restrict__ nf,
                                                        const float* __restrict__ xyz,
                                                        unsigned short* __restrict__ A,
                                                        int N, float r2, float scale){
    __shared__ short tA[128*32], tB[128*32];
    __shared__ float xa[384], xb[384];
    int tid = threadIdx.x;
    int n0 = blockIdx.y*128, m0 = blockIdx.x*128;
    for (int i = tid; i < 384; i += 256){ xa[i] = xyz[n0*3 + i]; xb[i] = xyz[m0*3 + i]; }
    int w = tid >> 6, l = tid & 63;
    int wy = w >> 1, wx = w & 1;
    int lg = l >> 4, lr = l & 15;
    int srow = tid >> 2, sc = tid & 3;
    f32x4 zero = {0.f, 0.f, 0.f, 0.f};
    f32x4 acc[4][4];
    #pragma unroll
    for (int i = 0; i < 4; ++i)
        #pragma unroll
        for (int j = 0; j < 4; ++j) acc[i][j] = zero;
    for (int kt = 0; kt < 256; kt += 32){
        __syncthreads();
        #pragma unroll
        for (int p = 0; p < 2; ++p){
            int row = srow + p*64;
            uint4 va = *(const uint4*)(nf + (long)(n0+row)*256 + kt + sc*8);
            uint4 vb = *(const uint4*)(nf + (long)(m0+row)*256 + kt + sc*8);
            *(uint4*)(tA + row*32 + sc*8) = va;
            *(uint4*)(tB + row*32 + sc*8) = vb;
        }
        __syncthreads();
        bf16x8 af[4], bfr[4];
        #pragma unroll
        for (int f = 0; f < 4; ++f){
            af[f]  = *(const bf16x8*)(tA + (wy*64 + f*16 + lr)*32 + lg*8);
            bfr[f] = *(const bf16x8*)(tB + (wx*64 + f*16 + lr)*32 + lg*8);
        }
        #pragma unroll
        for (int i = 0; i < 4; ++i)
            #pragma unroll
            for (int j = 0; j < 4; ++j)
                acc[i][j] = __builtin_amdgcn_mfma_f32_16x16x32_bf16(af[i], bfr[j], acc[i][j], 0, 0, 0);
    }
    #pragma unroll
    for (int fi = 0; fi < 4; ++fi){
        #pragma unroll
        for (int fj = 0; fj < 4; ++fj){
            #pragma unroll
            for (int r = 0; r < 4; ++r){
                int n_ = wy*64 + fi*16 + lg*4 + r;
                int m_ = wx*64 + fj*16 + lr;
                float dx = xa[n_*3+0]-xb[m_*3+0];
                float dy = xa[n_*3+1]-xb[m_*3+1];
                float dz = xa[n_*3+2]-xb[m_*3+2];
                float d2x = dx*dx + dy*dy + dz*dz;
                int gn = n0 + n_, gm = m0 + m_;
                float dot = acc[fi][fj][r];
                float val = (d2x < r2 && gn != gm) ? expf(scale*(2.f*dot - 2.f)) : 0.f;
                A[(long)gn*N + gm] = f2bf(val);
            }
        }
    }
}

// ---------------------------------------------------------------- row sums of bf16 A -> dinv
__global__ void rowsum_kernel(const unsigned short* __restrict__ A, float* __restrict__ dinv, int N){
    __shared__ float red[256];
    int n = blockIdx.x, t = threadIdx.x;
    const uint4* row = (const uint4*)(A + (long)n*N);
    float s = 0.f;
    for (int i = t; i < N/8; i += 256){
        uint4 u = row[i];
        s += __uint_as_float(u.x << 16) + __uint_as_float(u.x & 0xFFFF0000u);
        s += __uint_as_float(u.y << 16) + __uint_as_float(u.y & 0xFFFF0000u);
        s += __uint_as_float(u.z << 16) + __uint_as_float(u.z & 0xFFFF0000u);
        s += __uint_as_float(u.w << 16) + __uint_as_float(u.w & 0xFFFF0000u);
    }
    s = blockReduceSum(s, red, 256);
    if (t == 0) dinv[n] = rsqrtf(s + EPSF);
}

// ---------------------------------------------------------------- XsT[c][m] = fea[m][c]*dinv[m], bf16
__global__ __launch_bounds__(256) void transpose_scale_kernel(const float* __restrict__ fea,
                                                              const float* __restrict__ dinv,
                                                              unsigned short* __restrict__ xsT, int N){
    __shared__ float tile[64][65];
    __shared__ float dl[64];
    int m0 = blockIdx.x*64, c0 = blockIdx.y*64;
    int t = threadIdx.x;
    int lr = t >> 2, lc = (t & 3)*16;
    #pragma unroll
    for (int j = 0; j < 4; ++j){
        float4 v = *(const float4*)(fea + (long)(m0+lr)*256 + c0 + lc + j*4);
        tile[lr][lc+j*4+0] = v.x; tile[lr][lc+j*4+1] = v.y;
        tile[lr][lc+j*4+2] = v.z; tile[lr][lc+j*4+3] = v.w;
    }
    if (t < 64) dl[t] = dinv[m0+t];
    __syncthreads();
    unsigned short vbuf[16] __attribute__((aligned(16)));
    #pragma unroll
    for (int j = 0; j < 16; ++j)
        vbuf[j] = f2bf(tile[lc+j][lr] * dl[lc+j]);
    long off = (long)(c0+lr)*N + m0 + lc;
    *(uint4*)(xsT + off)     = *(uint4*)&vbuf[0];
    *(uint4*)(xsT + off + 8) = *(uint4*)&vbuf[8];
}

// ---------------------------------------------------------------- MFMA A@XsT^T -> PY partials (split 2)
// grid (2 ctiles, N/128, 2 halves)
__global__ __launch_bounds__(256) void ax_mfma_kernel(const unsigned short* __restrict__ A,
                                                      const unsigned short* __restrict__ xsT,
                                                      float* __restrict__ PY, int N){
    __shared__ short tA[128*32], tB[128*32];
    int tid = threadIdx.x;
    int c0 = blockIdx.x*128, n0 = blockIdx.y*128;
    int half = blockIdx.z;
    int kbase = half*(N/2), kend = kbase + N/2;
    int w = tid >> 6, l = tid & 63;
    int wy = w >> 1, wx = w & 1;
    int lg = l >> 4, lr = l & 15;
    int srow = tid >> 2, sc = tid & 3;
    f32x4 zero = {0.f, 0.f, 0.f, 0.f};
    f32x4 acc[4][4];
    #pragma unroll
    for (int i = 0; i < 4; ++i)
        #pragma unroll
        for (int j = 0; j < 4; ++j) acc[i][j] = zero;
    for (int kt = kbase; kt < kend; kt += 32){
        __syncthreads();
        #pragma unroll
        for (int p = 0; p < 2; ++p){
            int row = srow + p*64;
            uint4 va = *(const uint4*)(A   + (long)(n0+row)*N + kt + sc*8);
            uint4 vb = *(const uint4*)(xsT + (long)(c0+row)*N + kt + sc*8);
            *(uint4*)(tA + row*32 + sc*8) = va;
            *(uint4*)(tB + row*32 + sc*8) = vb;
        }
        __syncthreads();
        bf16x8 af[4], bfr[4];
        #pragma unroll
        for (int f = 0; f < 4; ++f){
            af[f]  = *(const bf16x8*)(tA + (wy*64 + f*16 + lr)*32 + lg*8);
            bfr[f] = *(const bf16x8*)(tB + (wx*64 + f*16 + lr)*32 + lg*8);
        }
        #pragma unroll
        for (int i = 0; i < 4; ++i)
            #pragma unroll
            for (int j = 0; j < 4; ++j)
                acc[i][j] = __builtin_amdgcn_mfma_f32_16x16x32_bf16(af[i], bfr[j], acc[i][j], 0, 0, 0);
    }
    float* out = PY + (long)half*N*256;
    #pragma unroll
    for (int fi = 0; fi < 4; ++fi){
        #pragma unroll
        for (int fj = 0; fj < 4; ++fj){
            #pragma unroll
            for (int r = 0; r < 4; ++r){
                int n_ = n0 + wy*64 + fi*16 + lg*4 + r;
                int c_ = c0 + wx*64 + fj*16 + lr;
                out[(long)n_*256 + c_] = acc[fi][fj][r];
            }
        }
    }
}

// ---------------------------------------------------------------- Y = dinv[n]*(P0+P1)
__global__ void combine_kernel(const float* __restrict__ PY, const float* __restrict__ dinv,
                               float* __restrict__ Y, int N){
    long i = (long)blockIdx.x*256 + threadIdx.x;   // float4 index
    float4 a = ((const float4*)PY)[i];
    float4 b = ((const float4*)(PY + (long)N*256))[i];
    float d = dinv[i >> 6];
    float4 o; o.x = (a.x+b.x)*d; o.y = (a.y+b.y)*d; o.z = (a.z+b.z)*d; o.w = (a.w+b.w)*d;
    ((float4*)Y)[i] = o;
}

// ---------------------------------------------------------------- generic X(R,Ci) @ W(Ci,Co) + bias [relu]
__global__ __launch_bounds__(256) void gemm_XW_kernel(const float* __restrict__ X,
                                                      const float* __restrict__ W,
                                                      const float* __restrict__ bias,
                                                      float* __restrict__ out,
                                                      int R, int Ci, int Co, int relu){
    __shared__ float sa[32][65], sb[32][65];
    int tid = threadIdx.x, tx = tid & 15, ty = tid >> 4;
    int c0 = blockIdx.x * 64, r0 = blockIdx.y * 64;
    float acc[4][4] = {};
    for (int kt = 0; kt < Ci; kt += 32){
        #pragma unroll
        for (int p = 0; p < 8; ++p){
            int idx = p*256 + tid;
            int k = idx & 31, i = idx >> 5;
            int rr = r0 + i;
            sa[k][i] = (rr < R) ? X[(long)rr*Ci + kt + k] : 0.f;
            int j = idx & 63, kk = idx >> 6;
            int cc = c0 + j;
            sb[kk][j] = (cc < Co) ? W[(long)(kt+kk)*Co + cc] : 0.f;
        }
        __syncthreads();
        #pragma unroll
        for (int k = 0; k < 32; ++k){
            float a0=sa[k][ty*4+0],a1=sa[k][ty*4+1],a2=sa[k][ty*4+2],a3=sa[k][ty*4+3];
            float b0=sb[k][tx*4+0],b1=sb[k][tx*4+1],b2=sb[k][tx*4+2],b3=sb[k][tx*4+3];
            acc[0][0]+=a0*b0; acc[0][1]+=a0*b1; acc[0][2]+=a0*b2; acc[0][3]+=a0*b3;
            acc[1][0]+=a1*b0; acc[1][1]+=a1*b1; acc[1][2]+=a1*b2; acc[1][3]+=a1*b3;
            acc[2][0]+=a2*b0; acc[2][1]+=a2*b1; acc[2][2]+=a2*b2; acc[2][3]+=a2*b3;
            acc[3][0]+=a3*b0; acc[3][1]+=a3*b1; acc[3][2]+=a3*b2; acc[3][3]+=a3*b3;
        }
        __syncthreads();
    }
    #pragma unroll
    for (int r = 0; r < 4; ++r){
        #pragma unroll
        for (int c = 0; c < 4; ++c){
            int rr = r0 + ty*4 + r, cc = c0 + tx*4 + c;
            if (rr < R && cc < Co){
                float v = acc[r][c] + (bias ? bias[cc] : 0.f);
                if (relu) v = fmaxf(v, 0.f);
                out[(long)rr*Co + cc] = v;
            }
        }
    }
}

// ---------------------------------------------------------------- row softmax (K<=64), in place
__global__ void softmax_kernel(float* __restrict__ x, int Kc, float tau){
    int row = blockIdx.x, lane = threadIdx.x;
    bool act = lane < Kc;
    float v = act ? x[(long)row*Kc + lane] / tau : -1e30f;
    float mx = v;
    #pragma unroll
    for (int o = 32; o; o >>= 1) mx = fmaxf(mx, __shfl_xor(mx, o, 64));
    float e = act ? expf(v - mx) : 0.f;
    float s = e;
    #pragma unroll
    for (int o = 32; o; o >>= 1) s += __shfl_xor(s, o, 64);
    if (act) x[(long)row*Kc + lane] = e / s;
}

// ---------------------------------------------------------------- cluster xyz sums + denom (raw)
__global__ void cluster_xyz_kernel(const float* __restrict__ s, const float* __restrict__ xyz,
                                   float* __restrict__ outx, float* __restrict__ outd,
                                   int N, int Kc, int xBS, int dBS){
    __shared__ float red[256];
    int b = blockIdx.y, k = blockIdx.x, t = threadIdx.x;
    s   += (long)b*N*Kc;
    xyz += (long)b*N*3;
    float a0=0,a1=0,a2=0,ad=0;
    for (int n = t; n < N; n += 256){
        float sv = s[(long)n*Kc + k];
        ad += sv;
        a0 += sv*xyz[n*3+0]; a1 += sv*xyz[n*3+1]; a2 += sv*xyz[n*3+2];
    }
    a0 = blockReduceSum(a0, red, 256);
    a1 = blockReduceSum(a1, red, 256);
    a2 = blockReduceSum(a2, red, 256);
    ad = blockReduceSum(ad, red, 256);
    if (t == 0){
        outx[b*xBS + k*3+0] = a0;
        outx[b*xBS + k*3+1] = a1;
        outx[b*xBS + k*3+2] = a2;
        outd[b*dBS + k] = ad;
    }
}

// ---------------------------------------------------------------- part[z] = s^T @ X  (split over n, no atomics)
__global__ __launch_bounds__(256) void gemm_sTX_kernel(const float* __restrict__ s,
                                                       const float* __restrict__ X,
                                                       float* __restrict__ part,
                                                       int N, int Kc, int split,
                                                       long sBS, long xBS){
    __shared__ float sa[32][65], sb[32][65];
    int tid = threadIdx.x, tx = tid & 15, ty = tid >> 4;
    int c0 = blockIdx.x * 64;
    int b = blockIdx.z / split, chunk = blockIdx.z % split;
    int L = N / split, nst = chunk * L;
    s += b*sBS; X += b*xBS;
    float* out = part + (long)blockIdx.z * Kc * 256;
    float acc[4][4] = {};
    for (int nt = nst; nt < nst + L; nt += 32){
        #pragma unroll
        for (int p = 0; p < 8; ++p){
            int idx = p*256 + tid;
            int i = idx & 63, k = idx >> 6;
            sa[k][i] = (i < Kc) ? s[(long)(nt+k)*Kc + i] : 0.f;
            int j = idx & 63, kk = idx >> 6;
            sb[kk][j] = X[(long)(nt+kk)*256 + c0 + j];
        }
        __syncthreads();
        #pragma unroll
        for (int k = 0; k < 32; ++k){
            float a0=sa[k][ty*4+0],a1=sa[k][ty*4+1],a2=sa[k][ty*4+2],a3=sa[k][ty*4+3];
            float b0=sb[k][tx*4+0],b1=sb[k][tx*4+1],b2=sb[k][tx*4+2],b3=sb[k][tx*4+3];
            acc[0][0]+=a0*b0; acc[0][1]+=a0*b1; acc[0][2]+=a0*b2; acc[0][3]+=a0*b3;
            acc[1][0]+=a1*b0; acc[1][1]+=a1*b1; acc[1][2]+=a1*b2; acc[1][3]+=a1*b3;
            acc[2][0]+=a2*b0; acc[2][1]+=a2*b1; acc[2][2]+=a2*b2; acc[2][3]+=a2*b3;
            acc[3][0]+=a3*b0; acc[3][1]+=a3*b1; acc[3][2]+=a3*b2; acc[3][3]+=a3*b3;
        }
        __syncthreads();
    }
    #pragma unroll
    for (int r = 0; r < 4; ++r){
        int kc = ty*4 + r;
        if (kc < Kc){
            #pragma unroll
            for (int c = 0; c < 4; ++c)
                out[(long)kc*256 + c0 + tx*4 + c] = acc[r][c];
        }
    }
}

// ---------------------------------------------------------------- sum partials, divide by denom
__global__ void divide_sum_kernel(const float* __restrict__ part, const float* __restrict__ den,
                                  float* __restrict__ cfea, float* __restrict__ cxyz,
                                  int Kc, int split, int fBS, int xBS, int dBS){
    int b = blockIdx.y, k = blockIdx.x, t = threadIdx.x;
    float d = den[b*dBS + k] + EPSF;
    float s = 0.f;
    for (int q = 0; q < split; ++q)
        s += part[((long)(b*split+q)*Kc + k)*256 + t];
    cfea[(long)b*fBS + k*256 + t] = s / d;
    if (t < 3) cxyz[b*xBS + k*3 + t] /= d;
}

// ---------------------------------------------------------------- level losses: wave per point
__global__ __launch_bounds__(256) void level_loss_kernel(const float* __restrict__ s,
                                                         const float* __restrict__ pxyz,
                                                         const float* __restrict__ cxyz,
                                                         const float* __restrict__ cfea,
                                                         const float* __restrict__ nf,
                                                         float* __restrict__ scal,
                                                         int N, float inv, int ndsSlot){
    __shared__ float cx[192];
    __shared__ float partA[4], partN[4];
    int b = blockIdx.y, t = threadIdx.x, w = t >> 6, l = t & 63;
    s    += (long)b*N*64;
    pxyz += (long)b*N*3;
    nf   += (long)b*N*256;
    cxyz += (long)b*384;
    cfea += (long)b*32768;
    if (t < 192) cx[t] = cxyz[t];
    __syncthreads();
    int n = blockIdx.x*4 + w;
    float sl = s[(long)n*64 + l];
    float px = pxyz[n*3+0], py = pxyz[n*3+1], pz = pxyz[n*3+2];
    float dx = px - cx[l*3+0], dy = py - cx[l*3+1], dz = pz - cx[l*3+2];
    float d2 = dx*dx + dy*dy + dz*dz;
    float assSum = waveSum(sl*d2);
    float dmin = waveMin(d2);
    float c0=0,c1=0,c2=0,c3=0;
    #pragma unroll 8
    for (int k = 0; k < 64; ++k){
        float sk = __shfl(sl, k, 64);
        const float* row = cfea + k*256;
        c0 += sk*row[l]; c1 += sk*row[l+64]; c2 += sk*row[l+128]; c3 += sk*row[l+192];
    }
    float nrm2 = waveSum(c0*c0 + c1*c1 + c2*c2 + c3*c3);
    float inrm = 1.f / fmaxf(sqrtf(nrm2), 1e-12f);
    const float* nfr = nf + (long)n*256;
    float e0 = c0*inrm - nfr[l];
    float e1 = c1*inrm - nfr[l+64];
    float e2 = c2*inrm - nfr[l+128];
    float e3 = c3*inrm - nfr[l+192];
    float nds = waveSum(e0*e0 + e1*e1 + e2*e2 + e3*e3);
    if (l == 0){
        partA[w] = inv*(assSum + 1.f - expf(-0.5f*dmin));
        partN[w] = nds;
    }
    __syncthreads();
    if (t == 0){
        int slot = blockIdx.x & 63;
        atomicAdd(&scal[slot], partA[0]+partA[1]+partA[2]+partA[3]);
        atomicAdd(&scal[ndsSlot*64 + slot], partN[0]+partN[1]+partN[2]+partN[3]);
    }
}

// ---------------------------------------------------------------- knn affinity -> normalized adjacency (128 pts)
__global__ void knn_nac_kernel(const float* __restrict__ cxyz, float* __restrict__ nac){
    __shared__ float x[128][3];
    __shared__ float di[128];
    int b = blockIdx.x, n = threadIdx.x;
    x[n][0] = cxyz[b*384 + n*3+0];
    x[n][1] = cxyz[b*384 + n*3+1];
    x[n][2] = cxyz[b*384 + n*3+2];
    __syncthreads();
    float* Ab = nac + (long)b*16384;
    float xn0 = x[n][0], xn1 = x[n][1], xn2 = x[n][2];
    float last = -1.f;
    for (int p = 0; p < 8; ++p){
        float cur = 1e30f;
        for (int m = 0; m < 128; ++m){
            float dx = xn0-x[m][0], dy = xn1-x[m][1], dz = xn2-x[m][2];
            float d2 = dx*dx+dy*dy+dz*dz + (m==n ? 1e6f : 0.f);
            if (d2 > last && d2 < cur) cur = d2;
        }
        last = cur;
    }
    for (int m = 0; m < 128; ++m){
        float dx = xn0-x[m][0], dy = xn1-x[m][1], dz = xn2-x[m][2];
        float d2 = dx*dx+dy*dy+dz*dz;
        float v = (m != n && d2 <= last) ? expf(-d2) : 0.f;
        Ab[n*128 + m] = v;
    }
    __syncthreads();
    for (int m = 0; m < 128; ++m){
        float mx = fmaxf(Ab[n*128+m], Ab[m*128+n]);
        Ab[n*128+m] = mx;
    }
    __syncthreads();
    float deg = 0.f;
    for (int m = 0; m < 128; ++m) deg += Ab[n*128+m];
    di[n] = rsqrtf(deg + EPSF);
    __syncthreads();
    for (int m = 0; m < 128; ++m) Ab[n*128+m] *= di[n]*di[m];
}

// ---------------------------------------------------------------- Y2 = na_c @ cfea
__global__ void bmm_small_kernel(const float* __restrict__ nac, const float* __restrict__ cfea,
                                 float* __restrict__ Y2){
    __shared__ float row[128];
    int b = blockIdx.y, n = blockIdx.x, t = threadIdx.x;
    if (t < 128) row[t] = nac[(long)b*16384 + n*128 + t];
    __syncthreads();
    float acc = 0.f;
    #pragma unroll 4
    for (int k = 0; k < 128; ++k) acc += row[k]*cfea[(long)b*32768 + k*256 + t];
    Y2[(long)b*32768 + n*256 + t] = acc;
}

// ---------------------------------------------------------------- cut_loss_c
__global__ void cutc_kernel(const float* __restrict__ gs, const float* __restrict__ cxyz,
                            const float* __restrict__ cxyzg, float* __restrict__ scal, float inv){
    __shared__ float cg[48];
    __shared__ float red[128];
    int b = blockIdx.x, t = threadIdx.x;
    if (t < 48) cg[t] = cxyzg[b*48 + t];
    __syncthreads();
    float x0 = cxyz[b*384 + t*3+0], x1 = cxyz[b*384 + t*3+1], x2 = cxyz[b*384 + t*3+2];
    float acc = 0.f;
    #pragma unroll
    for (int k = 0; k < 16; ++k){
        float dx = x0-cg[k*3+0], dy = x1-cg[k*3+1], dz = x2-cg[k*3+2];
        acc += gs[b*2048 + t*16 + k]*(dx*dx+dy*dy+dz*dz);
    }
    acc = blockReduceSum(acc, red, 128);
    if (t == 0) atomicAdd(&scal[b], acc*inv);
}

// ---------------------------------------------------------------- cross attention (M=16)
__global__ __launch_bounds__(256) void attn_kernel(const float* __restrict__ q,
                                                   const float* __restrict__ kk,
                                                   const float* __restrict__ vv,
                                                   float* __restrict__ out){
    __shared__ float Ks[16][256], Vs[16][256];
    int b = blockIdx.y, n = blockIdx.x, t = threadIdx.x;
    #pragma unroll
    for (int p = 0; p < 16; ++p){
        int j = p*256 + t;
        Ks[j>>8][j&255] = kk[b*4096 + j];
        Vs[j>>8][j&255] = vv[b*4096 + j];
    }
    __syncthreads();
    float qv = q[((long)b*1024 + n)*256 + t];
    float sc[16];
    #pragma unroll
    for (int m = 0; m < 16; ++m){
        float v = qv * Ks[m][t];
        #pragma unroll
        for (int o = 32; o; o >>= 1) v += __shfl_xor(v, o, 64);
        sc[m] = v * 0.125f;
    }
    float mx = -1e30f;
    #pragma unroll
    for (int m = 0; m < 16; ++m) mx = fmaxf(mx, sc[m]);
    float sum = 0.f;
    #pragma unroll
    for (int m = 0; m < 16; ++m){ sc[m] = expf(sc[m]-mx); sum += sc[m]; }
    float o = 0.f;
    #pragma unroll
    for (int m = 0; m < 16; ++m) o += sc[m]*Vs[m][t];
    out[((long)b*1024 + n)*256 + t] = o / sum;
}

// ---------------------------------------------------------------- quad: wave per row, bf16 A (N=1024)
__global__ void quad_kernel(const unsigned short* __restrict__ A, const float* __restrict__ dinv,
                            const float* __restrict__ xyz, float* __restrict__ scal){
    __shared__ float part[4];
    int t = threadIdx.x, w = t >> 6, l = t & 63;
    int n = blockIdx.x*4 + w;
    float a0=0,a1=0,a2=0;
    #pragma unroll 4
    for (int i = 0; i < 16; ++i){
        int m = l + i*64;
        float wv = bf2f(A[(long)n*1024 + m])*dinv[m];
        a0 += wv*xyz[m*3+0]; a1 += wv*xyz[m*3+1]; a2 += wv*xyz[m*3+2];
    }
    a0 = waveSum(a0); a1 = waveSum(a1); a2 = waveSum(a2);
    if (l == 0){
        float x0 = xyz[n*3+0], x1 = xyz[n*3+1], x2 = xyz[n*3+2];
        part[w] = (x0*x0+x1*x1+x2*x2) - dinv[n]*(x0*a0+x1*a1+x2*a2);
    }
    __syncthreads();
    if (t == 0) atomicAdd(&scal[4*64 + (blockIdx.x & 63)], part[0]+part[1]+part[2]+part[3]);
}

// ---------------------------------------------------------------- g_loss per-row: wave per row
__global__ void gloss_kernel(const float* __restrict__ agg, const float* __restrict__ gfea,
                             float* __restrict__ scal){
    __shared__ float part[4];
    int t = threadIdx.x, w = t >> 6, l = t & 63;
    long r = (long)blockIdx.x*4 + w;
    const float* a = agg + r*256;
    const float* g = gfea + r*256;
    float a0=a[l],a1=a[l+64],a2=a[l+128],a3=a[l+192];
    float g0=g[l],g1=g[l+64],g2=g[l+128],g3=g[l+192];
    float na2 = waveSum(a0*a0+a1*a1+a2*a2+a3*a3);
    float ng2 = waveSum(g0*g0+g1*g1+g2*g2+g3*g3);
    float ia = 1.f/fmaxf(sqrtf(na2), 1e-12f), ig = 1.f/fmaxf(sqrtf(ng2), 1e-12f);
    float e0=a0*ia-g0*ig, e1=a1*ia-g1*ig, e2=a2*ia-g2*ig, e3=a3*ia-g3*ig;
    float d2 = waveSum(e0*e0+e1*e1+e2*e2+e3*e3);
    if (l == 0) part[w] = sqrtf(d2);
    __syncthreads();
    if (t == 0) atomicAdd(&scal[3*64 + (blockIdx.x & 63)], part[0]+part[1]+part[2]+part[3]);
}

// ---------------------------------------------------------------- finalize
__global__ void finalize_kernel(const float* __restrict__ scal, float* __restrict__ out){
    int t = threadIdx.x;
    float s[5];
    #pragma unroll
    for (int q = 0; q < 5; ++q){
        float v = scal[q*64 + t];
        #pragma unroll
        for (int o = 32; o; o >>= 1) v += __shfl_xor(v, o, 64);
        s[q] = v;
    }
    if (t == 0){
        out[524288] = s[0] + sqrtf(s[1]) + sqrtf(s[2]);
        out[524289] = s[3]*0.5f + 1e-4f*s[4]/2048.0f;
    }
}

// ================================================================ launcher
extern "C" void kernel_launch(void* const* d_in, const int* in_sizes, int n_in,
                              void* d_out, int out_size, void* d_ws, size_t ws_size,
                              hipStream_t stream){
    const float* g_fea   = (const float*)d_in[0];
    const float* g_xyz   = (const float*)d_in[1];
    const float* p_fea_0 = (const float*)d_in[2];
    const float* p_xyz_0 = (const float*)d_in[3];
    const float* p_fea_1 = (const float*)d_in[4];
    const float* p_xyz_1 = (const float*)d_in[5];
    const float* lW1 = (const float*)d_in[6];
    const float* lb1 = (const float*)d_in[7];
    const float* lW2 = (const float*)d_in[8];
    const float* lb2 = (const float*)d_in[9];
    const float* gW1 = (const float*)d_in[10];
    const float* gb1 = (const float*)d_in[11];
    const float* gW2 = (const float*)d_in[12];
    const float* gb2 = (const float*)d_in[13];
    const float* Wq = (const float*)d_in[14];
    const float* Wk = (const float*)d_in[15];
    const float* Wv = (const float*)d_in[16];
    const float* Wo = (const float*)d_in[17];
    float* out = (float*)d_out;
    float* ws_f = (float*)d_ws;

    // ---- workspace layout (float offsets)
    constexpr long O_SCALS = 0;                         // 8*64 spread slots (zeroed)
    constexpr long O_CFEA  = 512;                       // (B,128,256)
    constexpr long O_CXYZ  = O_CFEA + 2L*128*256;       // (B,128,3)
    constexpr long O_DEN   = O_CXYZ + 768;              // (B,128)
    constexpr long O_CFG   = O_DEN  + 256;              // (B,16,256)
    constexpr long O_CXG   = O_CFG  + 2L*16*256;        // (B,16,3)
    constexpr long O_DENG  = O_CXG  + 96;               // (B,16) +pad
    constexpr long O_PART  = O_DENG + 64;               // sTX partials (<= 16*64*256)
    constexpr long O_NF    = O_PART + 262144;           // f32 (2*4096,256)
    constexpr long O_NFB   = O_NF   + 2L*4096*256;      // bf16 same (as floats /2)
    constexpr long O_XST   = O_NFB  + 1048576;          // bf16 (256,N) one batch
    constexpr long O_Y     = O_XST  + 262144;           // f32 (2N,256)
    constexpr long O_H     = O_Y    + 2L*4096*256;      // (2N,128)
    constexpr long O_S     = O_H    + 2L*4096*128;      // (2N,64)
    constexpr long O_DINV  = O_S    + 2L*4096*64;       // (2*4096)
    constexpr long O_PY    = O_DINV + 8192;             // f32 partials 2*(N,256)
    constexpr long O_A     = O_PY   + 2L*4096*256;      // bf16 (4096,4096) one batch
    constexpr long O_Q     = O_A    + 8388608;
    constexpr long O_AO    = O_Q    + 524288;
    constexpr long O_KK    = O_AO   + 524288;
    constexpr long O_VV    = O_KK   + 8192;
    constexpr long O_NAC   = O_VV   + 8192;
    constexpr long O_Y2    = O_NAC  + 32768;
    constexpr long O_H2    = O_Y2   + 65536;
    constexpr long O_LG2   = O_H2   + 32768;

    hipMemsetAsync(ws_f + O_SCALS, 0, 512*sizeof(float), stream);

    float* nf   = ws_f + O_NF;
    unsigned short* nfb = (unsigned short*)(ws_f + O_NFB);
    unsigned short* xsT = (unsigned short*)(ws_f + O_XST);
    unsigned short* A   = (unsigned short*)(ws_f + O_A);
    float* Yb   = ws_f + O_Y;
    float* hb   = ws_f + O_H;
    float* sb   = ws_f + O_S;
    float* dinv = ws_f + O_DINV;
    float* PY   = ws_f + O_PY;
    float* part = ws_f + O_PART;

    struct Lvl { const float* fea; const float* xyz; int N; int k0; int ndsSlot; };
    Lvl lv[2] = {{p_fea_0, p_xyz_0, 4096, 0, 1}, {p_fea_1, p_xyz_1, 2048, 64, 2}};

    for (int L = 0; L < 2; ++L){
        int N = lv[L].N;
        const float* fea = lv[L].fea;
        const float* xyz = lv[L].xyz;
        l2norm_kernel<<<2*N, 256, 0, stream>>>(fea, nf, nfb, 2*N);
        for (int b = 0; b < 2; ++b){
            const unsigned short* nfbb = nfb + (long)b*N*256;
            const float* xyzb = xyz + (long)b*N*3;
            gram_mfma_kernel<<<dim3(N/128, N/128), 256, 0, stream>>>(nfbb, xyzb, A, N, 1.0f, 0.25f);
            rowsum_kernel<<<N, 256, 0, stream>>>(A, dinv + b*N, N);
            transpose_scale_kernel<<<dim3(N/64, 4), 256, 0, stream>>>(fea + (long)b*N*256, dinv + b*N, xsT, N);
            ax_mfma_kernel<<<dim3(2, N/128, 2), 256, 0, stream>>>(A, xsT, PY, N);
            combine_kernel<<<N/4, 256, 0, stream>>>(PY, dinv + b*N, Yb + (long)b*N*256, N);
        }
        gemm_XW_kernel<<<dim3(2, 2*N/64), 256, 0, stream>>>(Yb, lW1, lb1, hb, 2*N, 256, 128, 1);
        gemm_XW_kernel<<<dim3(1, 2*N/64), 256, 0, stream>>>(hb, lW2, lb2, sb, 2*N, 128, 64, 0);
        softmax_kernel<<<2*N, 64, 0, stream>>>(sb, 64, 0.1f);
        cluster_xyz_kernel<<<dim3(64, 2), 256, 0, stream>>>(sb, xyz, ws_f + O_CXYZ + lv[L].k0*3,
                                                            ws_f + O_DEN + lv[L].k0, N, 64, 384, 128);
        gemm_sTX_kernel<<<dim3(4, 1, 16), 256, 0, stream>>>(sb, fea, part, N, 64, 8,
                                                            (long)N*64, (long)N*256);
        divide_sum_kernel<<<dim3(64, 2), 256, 0, stream>>>(part, ws_f + O_DEN + lv[L].k0,
                                                           ws_f + O_CFEA + lv[L].k0*256,
                                                           ws_f + O_CXYZ + lv[L].k0*3,
                                                           64, 8, 128*256, 384, 128);
        level_loss_kernel<<<dim3(N/4, 2), 256, 0, stream>>>(sb, xyz, ws_f + O_CXYZ + lv[L].k0*3,
                                                            ws_f + O_CFEA + lv[L].k0*256, nf,
                                                            ws_f + O_SCALS, N, 1.0f/(2.0f*N), lv[L].ndsSlot);
    }

    // ---- global cluster stage
    knn_nac_kernel<<<2, 128, 0, stream>>>(ws_f + O_CXYZ, ws_f + O_NAC);
    bmm_small_kernel<<<dim3(128, 2), 256, 0, stream>>>(ws_f + O_NAC, ws_f + O_CFEA, ws_f + O_Y2);
    gemm_XW_kernel<<<dim3(2, 4), 256, 0, stream>>>(ws_f + O_Y2, gW1, gb1, ws_f + O_H2, 256, 256, 128, 1);
    gemm_XW_kernel<<<dim3(1, 4), 256, 0, stream>>>(ws_f + O_H2, gW2, gb2, ws_f + O_LG2, 256, 128, 16, 0);
    softmax_kernel<<<256, 64, 0, stream>>>(ws_f + O_LG2, 16, 0.1f);
    cluster_xyz_kernel<<<dim3(16, 2), 256, 0, stream>>>(ws_f + O_LG2, ws_f + O_CXYZ,
                                                        ws_f + O_CXG, ws_f + O_DENG, 128, 16, 48, 16);
    gemm_sTX_kernel<<<dim3(4, 1, 2), 256, 0, stream>>>(ws_f + O_LG2, ws_f + O_CFEA, part,
                                                       128, 16, 1, 128L*16, 128L*256);
    divide_sum_kernel<<<dim3(16, 2), 256, 0, stream>>>(part, ws_f + O_DENG, ws_f + O_CFG,
                                                       ws_f + O_CXG, 16, 1, 16*256, 48, 16);
    cutc_kernel<<<2, 128, 0, stream>>>(ws_f + O_LG2, ws_f + O_CXYZ, ws_f + O_CXG,
                                       ws_f + O_SCALS, 1.0f/256.0f);

    // ---- cross attention
    gemm_XW_kernel<<<dim3(4, 32), 256, 0, stream>>>(g_fea, Wq, nullptr, ws_f + O_Q, 2048, 256, 256, 0);
    gemm_XW_kernel<<<dim3(4, 1), 256, 0, stream>>>(ws_f + O_CFG, Wk, nullptr, ws_f + O_KK, 32, 256, 256, 0);
    gemm_XW_kernel<<<dim3(4, 1), 256, 0, stream>>>(ws_f + O_CFG, Wv, nullptr, ws_f + O_VV, 32, 256, 256, 0);
    attn_kernel<<<dim3(1024, 2), 256, 0, stream>>>(ws_f + O_Q, ws_f + O_KK, ws_f + O_VV, ws_f + O_AO);
    gemm_XW_kernel<<<dim3(4, 32), 256, 0, stream>>>(ws_f + O_AO, Wo, nullptr, out, 2048, 256, 256, 0);

    // ---- A_g stage
    l2norm_kernel<<<2048, 256, 0, stream>>>(g_fea, nf, nfb, 2048);
    for (int b = 0; b < 2; ++b){
        gram_mfma_kernel<<<dim3(8, 8), 256, 0, stream>>>(nfb + (long)b*1024*256, g_xyz + (long)b*1024*3,
                                                         A, 1024, 16.0f, 0.25f);
        rowsum_kernel<<<1024, 256, 0, stream>>>(A, dinv + b*1024, 1024);
        quad_kernel<<<256, 256, 0, stream>>>(A, dinv + b*1024, g_xyz + (long)b*1024*3, ws_f + O_SCALS);
    }

    gloss_kernel<<<512, 256, 0, stream>>>(out, g_fea, ws_f + O_SCALS);
    finalize_kernel<<<1, 64, 0, stream>>>(ws_f + O_SCALS, out);
}

// Round 4
// 906.760 us; speedup vs baseline: 2.6163x; 1.2406x over previous
//
#include <hip/hip_runtime.h>

#define EPSF 1e-4f

typedef __attribute__((ext_vector_type(8))) short bf16x8;
typedef __attribute__((ext_vector_type(4))) float f32x4;

__device__ __forceinline__ unsigned short f2bf(float f){
    unsigned int u = __float_as_uint(f);
    return (unsigned short)((u + 0x7FFF + ((u >> 16) & 1)) >> 16);
}
__device__ __forceinline__ float bf2f(unsigned short u){
    return __uint_as_float(((unsigned int)u) << 16);
}
__device__ __forceinline__ float waveSum(float v){
    #pragma unroll
    for (int o = 32; o; o >>= 1) v += __shfl_xor(v, o, 64);
    return v;
}
__device__ __forceinline__ float waveMin(float v){
    #pragma unroll
    for (int o = 32; o; o >>= 1) v = fminf(v, __shfl_xor(v, o, 64));
    return v;
}
__device__ __forceinline__ float waveMax(float v){
    #pragma unroll
    for (int o = 32; o; o >>= 1) v = fmaxf(v, __shfl_xor(v, o, 64));
    return v;
}
__device__ __forceinline__ float blockReduceSum(float v, float* red, int nthr){
    int t = threadIdx.x;
    red[t] = v; __syncthreads();
    for (int s = nthr >> 1; s > 0; s >>= 1){
        if (t < s) red[t] += red[t + s];
        __syncthreads();
    }
    float r = red[0]; __syncthreads();
    return r;
}

// ---------------------------------------------------------------- l2norm rows of 256 -> f32 + bf16
__global__ void l2norm_kernel(const float* __restrict__ x, float* __restrict__ outf,
                              unsigned short* __restrict__ outb, int rows){
    __shared__ float red[256];
    int row = blockIdx.x, t = threadIdx.x;
    float v = x[(long)row*256 + t];
    float s = blockReduceSum(v*v, red, 256);
    float nrm = fmaxf(sqrtf(s), 1e-12f);
    float r = v / nrm;
    outf[(long)row*256 + t] = r;
    outb[(long)row*256 + t] = f2bf(r);
}

// ---------------------------------------------------------------- flat f32 -> bf16
__global__ void cvt_bf16_kernel(const float* __restrict__ in, unsigned short* __restrict__ out, long n4){
    long i = (long)blockIdx.x*256 + threadIdx.x;
    if (i < n4){
        float4 v = ((const float4*)in)[i];
        unsigned int lo = f2bf(v.x) | ((unsigned int)f2bf(v.y) << 16);
        unsigned int hi = f2bf(v.z) | ((unsigned int)f2bf(v.w) << 16);
        uint2 u; u.x = lo; u.y = hi;
        ((uint2*)out)[i] = u;
    }
}

// ---------------------------------------------------------------- transpose+cvt weight: W(Rw,Cw) -> WT(Cw,Rw) bf16
__global__ void tcvt_kernel(const float* __restrict__ W, unsigned short* __restrict__ WT,
                            int Rw, int Cw){
    __shared__ float tile[64][65];
    int r0 = blockIdx.x*64, c0 = blockIdx.y*64;
    int t = threadIdx.x;
    for (int idx = t; idx < 4096; idx += 256){
        int rr = idx >> 6, cc = idx & 63;
        tile[rr][cc] = (r0+rr < Rw && c0+cc < Cw) ? W[(long)(r0+rr)*Cw + c0+cc] : 0.f;
    }
    __syncthreads();
    for (int idx = t; idx < 4096; idx += 256){
        int cc = idx >> 6, rr = idx & 63;
        if (r0+rr < Rw && c0+cc < Cw)
            WT[(long)(c0+cc)*Rw + r0+rr] = f2bf(tile[rr][cc]);
    }
}

// ---------------------------------------------------------------- MFMA gram: A = exp(scale*(2dot-2)) * mask, bf16 out
__global__ __launch_bounds__(256) void gram_mfma_kernel(const unsigned short* __restrict__ nf,
                                                        const float* __restrict__ xyz,
                                                        unsigned short* __restrict__ A,
                                                        int N, float r2, float scale){
    __shared__ short tA[128*32], tB[128*32];
    __shared__ float xa[384], xb[384];
    int tid = threadIdx.x;
    int n0 = blockIdx.y*128, m0 = blockIdx.x*128;
    for (int i = tid; i < 384; i += 256){ xa[i] = xyz[n0*3 + i]; xb[i] = xyz[m0*3 + i]; }
    int w = tid >> 6, l = tid & 63;
    int wy = w >> 1, wx = w & 1;
    int lg = l >> 4, lr = l & 15;
    int srow = tid >> 2, sc = tid & 3;
    f32x4 zero = {0.f, 0.f, 0.f, 0.f};
    f32x4 acc[4][4];
    #pragma unroll
    for (int i = 0; i < 4; ++i)
        #pragma unroll
        for (int j = 0; j < 4; ++j) acc[i][j] = zero;
    for (int kt = 0; kt < 256; kt += 32){
        __syncthreads();
        #pragma unroll
        for (int p = 0; p < 2; ++p){
            int row = srow + p*64;
            uint4 va = *(const uint4*)(nf + (long)(n0+row)*256 + kt + sc*8);
            uint4 vb = *(const uint4*)(nf + (long)(m0+row)*256 + kt + sc*8);
            *(uint4*)(tA + row*32 + sc*8) = va;
            *(uint4*)(tB + row*32 + sc*8) = vb;
        }
        __syncthreads();
        bf16x8 af[4], bfr[4];
        #pragma unroll
        for (int f = 0; f < 4; ++f){
            af[f]  = *(const bf16x8*)(tA + (wy*64 + f*16 + lr)*32 + lg*8);
            bfr[f] = *(const bf16x8*)(tB + (wx*64 + f*16 + lr)*32 + lg*8);
        }
        #pragma unroll
        for (int i = 0; i < 4; ++i)
            #pragma unroll
            for (int j = 0; j < 4; ++j)
                acc[i][j] = __builtin_amdgcn_mfma_f32_16x16x32_bf16(af[i], bfr[j], acc[i][j], 0, 0, 0);
    }
    #pragma unroll
    for (int fi = 0; fi < 4; ++fi){
        #pragma unroll
        for (int fj = 0; fj < 4; ++fj){
            #pragma unroll
            for (int r = 0; r < 4; ++r){
                int n_ = wy*64 + fi*16 + lg*4 + r;
                int m_ = wx*64 + fj*16 + lr;
                float dx = xa[n_*3+0]-xb[m_*3+0];
                float dy = xa[n_*3+1]-xb[m_*3+1];
                float dz = xa[n_*3+2]-xb[m_*3+2];
                float d2x = dx*dx + dy*dy + dz*dz;
                int gn = n0 + n_, gm = m0 + m_;
                float dot = acc[fi][fj][r];
                float val = (d2x < r2 && gn != gm) ? expf(scale*(2.f*dot - 2.f)) : 0.f;
                A[(long)gn*N + gm] = f2bf(val);
            }
        }
    }
}

// ---------------------------------------------------------------- row sums of bf16 A -> dinv
__global__ void rowsum_kernel(const unsigned short* __restrict__ A, float* __restrict__ dinv, int N){
    __shared__ float red[256];
    int n = blockIdx.x, t = threadIdx.x;
    const uint4* row = (const uint4*)(A + (long)n*N);
    float s = 0.f;
    for (int i = t; i < N/8; i += 256){
        uint4 u = row[i];
        s += __uint_as_float(u.x << 16) + __uint_as_float(u.x & 0xFFFF0000u);
        s += __uint_as_float(u.y << 16) + __uint_as_float(u.y & 0xFFFF0000u);
        s += __uint_as_float(u.z << 16) + __uint_as_float(u.z & 0xFFFF0000u);
        s += __uint_as_float(u.w << 16) + __uint_as_float(u.w & 0xFFFF0000u);
    }
    s = blockReduceSum(s, red, 256);
    if (t == 0) dinv[n] = rsqrtf(s + EPSF);
}

// ---------------------------------------------------------------- feaT[c][m] = fea[m][c] (raw) ; xsT[c][m] = fea[m][c]*dinv[m]
__global__ __launch_bounds__(256) void transpose_scale_kernel(const float* __restrict__ fea,
                                                              const float* __restrict__ dinv,
                                                              unsigned short* __restrict__ feaT,
                                                              unsigned short* __restrict__ xsT, int N){
    __shared__ float tile[64][65];
    __shared__ float dl[64];
    int m0 = blockIdx.x*64, c0 = blockIdx.y*64;
    int t = threadIdx.x;
    int lr = t >> 2, lc = (t & 3)*16;
    #pragma unroll
    for (int j = 0; j < 4; ++j){
        float4 v = *(const float4*)(fea + (long)(m0+lr)*256 + c0 + lc + j*4);
        tile[lr][lc+j*4+0] = v.x; tile[lr][lc+j*4+1] = v.y;
        tile[lr][lc+j*4+2] = v.z; tile[lr][lc+j*4+3] = v.w;
    }
    if (t < 64) dl[t] = dinv[m0+t];
    __syncthreads();
    unsigned short vr[16] __attribute__((aligned(16)));
    unsigned short vs[16] __attribute__((aligned(16)));
    #pragma unroll
    for (int j = 0; j < 16; ++j){
        float raw = tile[lc+j][lr];
        vr[j] = f2bf(raw);
        vs[j] = f2bf(raw * dl[lc+j]);
    }
    long off = (long)(c0+lr)*N + m0 + lc;
    *(uint4*)(feaT + off)     = *(uint4*)&vr[0];
    *(uint4*)(feaT + off + 8) = *(uint4*)&vr[8];
    *(uint4*)(xsT + off)      = *(uint4*)&vs[0];
    *(uint4*)(xsT + off + 8)  = *(uint4*)&vs[8];
}

// ---------------------------------------------------------------- MFMA A@XsT^T -> PY partials (split 2)
__global__ __launch_bounds__(256) void ax_mfma_kernel(const unsigned short* __restrict__ A,
                                                      const unsigned short* __restrict__ xsT,
                                                      float* __restrict__ PY, int N){
    __shared__ short tA[128*32], tB[128*32];
    int tid = threadIdx.x;
    int c0 = blockIdx.x*128, n0 = blockIdx.y*128;
    int half = blockIdx.z;
    int kbase = half*(N/2), kend = kbase + N/2;
    int w = tid >> 6, l = tid & 63;
    int wy = w >> 1, wx = w & 1;
    int lg = l >> 4, lr = l & 15;
    int srow = tid >> 2, sc = tid & 3;
    f32x4 zero = {0.f, 0.f, 0.f, 0.f};
    f32x4 acc[4][4];
    #pragma unroll
    for (int i = 0; i < 4; ++i)
        #pragma unroll
        for (int j = 0; j < 4; ++j) acc[i][j] = zero;
    for (int kt = kbase; kt < kend; kt += 32){
        __syncthreads();
        #pragma unroll
        for (int p = 0; p < 2; ++p){
            int row = srow + p*64;
            uint4 va = *(const uint4*)(A   + (long)(n0+row)*N + kt + sc*8);
            uint4 vb = *(const uint4*)(xsT + (long)(c0+row)*N + kt + sc*8);
            *(uint4*)(tA + row*32 + sc*8) = va;
            *(uint4*)(tB + row*32 + sc*8) = vb;
        }
        __syncthreads();
        bf16x8 af[4], bfr[4];
        #pragma unroll
        for (int f = 0; f < 4; ++f){
            af[f]  = *(const bf16x8*)(tA + (wy*64 + f*16 + lr)*32 + lg*8);
            bfr[f] = *(const bf16x8*)(tB + (wx*64 + f*16 + lr)*32 + lg*8);
        }
        #pragma unroll
        for (int i = 0; i < 4; ++i)
            #pragma unroll
            for (int j = 0; j < 4; ++j)
                acc[i][j] = __builtin_amdgcn_mfma_f32_16x16x32_bf16(af[i], bfr[j], acc[i][j], 0, 0, 0);
    }
    float* out = PY + (long)half*N*256;
    #pragma unroll
    for (int fi = 0; fi < 4; ++fi){
        #pragma unroll
        for (int fj = 0; fj < 4; ++fj){
            #pragma unroll
            for (int r = 0; r < 4; ++r){
                int n_ = n0 + wy*64 + fi*16 + lg*4 + r;
                int c_ = c0 + wx*64 + fj*16 + lr;
                out[(long)n_*256 + c_] = acc[fi][fj][r];
            }
        }
    }
}

// ---------------------------------------------------------------- Yb(bf16) = dinv[n]*(P0+P1)
__global__ void combine_kernel(const float* __restrict__ PY, const float* __restrict__ dinv,
                               unsigned short* __restrict__ Yb, int N){
    long i = (long)blockIdx.x*256 + threadIdx.x;  // 8 elems per thread
    long e = i*8;
    const float4* p0 = (const float4*)(PY + e);
    const float4* p1 = (const float4*)(PY + (long)N*256 + e);
    float4 a0 = p0[0], a1 = p0[1], b0 = p1[0], b1 = p1[1];
    float d = dinv[e >> 8];
    unsigned short vb[8] __attribute__((aligned(16)));
    vb[0] = f2bf((a0.x+b0.x)*d); vb[1] = f2bf((a0.y+b0.y)*d);
    vb[2] = f2bf((a0.z+b0.z)*d); vb[3] = f2bf((a0.w+b0.w)*d);
    vb[4] = f2bf((a1.x+b1.x)*d); vb[5] = f2bf((a1.y+b1.y)*d);
    vb[6] = f2bf((a1.z+b1.z)*d); vb[7] = f2bf((a1.w+b1.w)*d);
    *(uint4*)(Yb + e) = *(uint4*)vb;
}

// ---------------------------------------------------------------- MFMA X(R,Ci)bf16 @ WT(Co,Ci)bf16 + bias [relu] -> f32/bf16
__global__ __launch_bounds__(256) void gemm_XW_mfma_kernel(const unsigned short* __restrict__ X,
                                                           const unsigned short* __restrict__ WT,
                                                           const float* __restrict__ bias,
                                                           float* __restrict__ outF,
                                                           unsigned short* __restrict__ outB,
                                                           int R, int Ci, int Co, int relu){
    __shared__ short tA[128*32], tB[128*32];
    int tid = threadIdx.x;
    int c0 = blockIdx.x*128, r0 = blockIdx.y*128;
    int w = tid >> 6, l = tid & 63;
    int wy = w >> 1, wx = w & 1;
    int lg = l >> 4, lr = l & 15;
    int srow = tid >> 2, sc = tid & 3;
    f32x4 zero = {0.f, 0.f, 0.f, 0.f};
    f32x4 acc[4][4];
    #pragma unroll
    for (int i = 0; i < 4; ++i)
        #pragma unroll
        for (int j = 0; j < 4; ++j) acc[i][j] = zero;
    for (int kt = 0; kt < Ci; kt += 32){
        __syncthreads();
        #pragma unroll
        for (int p = 0; p < 2; ++p){
            int row = srow + p*64;
            uint4 va = {0,0,0,0}, vb = {0,0,0,0};
            int ar = r0 + row, br = c0 + row;
            if (ar < R)  va = *(const uint4*)(X  + (long)ar*Ci + kt + sc*8);
            if (br < Co) vb = *(const uint4*)(WT + (long)br*Ci + kt + sc*8);
            *(uint4*)(tA + row*32 + sc*8) = va;
            *(uint4*)(tB + row*32 + sc*8) = vb;
        }
        __syncthreads();
        bf16x8 af[4], bfr[4];
        #pragma unroll
        for (int f = 0; f < 4; ++f){
            af[f]  = *(const bf16x8*)(tA + (wy*64 + f*16 + lr)*32 + lg*8);
            bfr[f] = *(const bf16x8*)(tB + (wx*64 + f*16 + lr)*32 + lg*8);
        }
        #pragma unroll
        for (int i = 0; i < 4; ++i)
            #pragma unroll
            for (int j = 0; j < 4; ++j)
                acc[i][j] = __builtin_amdgcn_mfma_f32_16x16x32_bf16(af[i], bfr[j], acc[i][j], 0, 0, 0);
    }
    #pragma unroll
    for (int fi = 0; fi < 4; ++fi){
        #pragma unroll
        for (int fj = 0; fj < 4; ++fj){
            #pragma unroll
            for (int r = 0; r < 4; ++r){
                int rr = r0 + wy*64 + fi*16 + lg*4 + r;
                int cc = c0 + wx*64 + fj*16 + lr;
                if (rr < R && cc < Co){
                    float v = acc[fi][fj][r] + (bias ? bias[cc] : 0.f);
                    if (relu) v = fmaxf(v, 0.f);
                    if (outF) outF[(long)rr*Co + cc] = v;
                    if (outB) outB[(long)rr*Co + cc] = f2bf(v);
                }
            }
        }
    }
}

// ---------------------------------------------------------------- softmax rows of 64 (in place, f32) + sT bf16
__global__ __launch_bounds__(256) void softmaxT_kernel(float* __restrict__ s,
                                                       unsigned short* __restrict__ sT,
                                                       int sStride, float invtau){
    __shared__ unsigned short st[64][65];
    int blk = blockIdx.x, t = threadIdx.x, w = t >> 6, l = t & 63;
    #pragma unroll
    for (int i = 0; i < 16; ++i){
        int rloc = w + 4*i;
        long row = (long)blk*64 + rloc;
        float v = s[row*64 + l] * invtau;
        float mx = waveMax(v);
        float e = expf(v - mx);
        float sum = waveSum(e);
        float p = e / sum;
        s[row*64 + l] = p;
        st[l][rloc] = f2bf(p);
    }
    __syncthreads();
    int k = t >> 2, j = (t & 3)*16;
    unsigned short vbuf[16] __attribute__((aligned(16)));
    #pragma unroll
    for (int q = 0; q < 16; ++q) vbuf[q] = st[k][j+q];
    long off = (long)k*sStride + (long)blk*64 + j;
    *(uint4*)(sT + off)     = *(uint4*)&vbuf[0];
    *(uint4*)(sT + off + 8) = *(uint4*)&vbuf[8];
}

// ---------------------------------------------------------------- MFMA sT(64,2N) @ feaT(256,N)^T -> part (64,256) per (b,chunk)
__global__ __launch_bounds__(256) void stx_mfma_kernel(const unsigned short* __restrict__ sT,
                                                       const unsigned short* __restrict__ feaT,
                                                       float* __restrict__ part,
                                                       int N, int split, int sStride){
    __shared__ short tA[64*32], tB[256*32];
    int tid = threadIdx.x;
    int z = blockIdx.x, b = z / split, chunk = z % split;
    int L = N / split, kst = chunk * L;
    const unsigned short* sTb = sT + (long)b*N;
    const unsigned short* fT  = feaT + (long)b*256*N;
    int w = tid >> 6, l = tid & 63;
    int lg = l >> 4, lr = l & 15;
    f32x4 zero = {0.f, 0.f, 0.f, 0.f};
    f32x4 acc[4][4];
    #pragma unroll
    for (int i = 0; i < 4; ++i)
        #pragma unroll
        for (int j = 0; j < 4; ++j) acc[i][j] = zero;
    int srow = tid >> 2, koff = (tid & 3)*8;
    for (int kt = kst; kt < kst + L; kt += 32){
        __syncthreads();
        *(uint4*)(tA + srow*32 + koff) = *(const uint4*)(sTb + (long)srow*sStride + kt + koff);
        #pragma unroll
        for (int p = 0; p < 4; ++p){
            int row = srow + p*64;
            *(uint4*)(tB + row*32 + koff) = *(const uint4*)(fT + (long)row*N + kt + koff);
        }
        __syncthreads();
        bf16x8 af[4], bfr[4];
        #pragma unroll
        for (int f = 0; f < 4; ++f){
            af[f]  = *(const bf16x8*)(tA + (f*16 + lr)*32 + lg*8);
            bfr[f] = *(const bf16x8*)(tB + (w*64 + f*16 + lr)*32 + lg*8);
        }
        #pragma unroll
        for (int i = 0; i < 4; ++i)
            #pragma unroll
            for (int j = 0; j < 4; ++j)
                acc[i][j] = __builtin_amdgcn_mfma_f32_16x16x32_bf16(af[i], bfr[j], acc[i][j], 0, 0, 0);
    }
    float* outp = part + (long)z*64*256;
    #pragma unroll
    for (int fi = 0; fi < 4; ++fi){
        #pragma unroll
        for (int fj = 0; fj < 4; ++fj){
            #pragma unroll
            for (int r = 0; r < 4; ++r){
                int kc = fi*16 + lg*4 + r;
                int cc = w*64 + fj*16 + lr;
                outp[(long)kc*256 + cc] = acc[fi][fj][r];
            }
        }
    }
}

// ---------------------------------------------------------------- generic f32 X(R,Ci) @ W(Ci,Co) + bias [relu]
__global__ __launch_bounds__(256) void gemm_XW_kernel(const float* __restrict__ X,
                                                      const float* __restrict__ W,
                                                      const float* __restrict__ bias,
                                                      float* __restrict__ out,
                                                      int R, int Ci, int Co, int relu){
    __shared__ float sa[32][65], sb[32][65];
    int tid = threadIdx.x, tx = tid & 15, ty = tid >> 4;
    int c0 = blockIdx.x * 64, r0 = blockIdx.y * 64;
    float acc[4][4] = {};
    for (int kt = 0; kt < Ci; kt += 32){
        #pragma unroll
        for (int p = 0; p < 8; ++p){
            int idx = p*256 + tid;
            int k = idx & 31, i = idx >> 5;
            int rr = r0 + i;
            sa[k][i] = (rr < R) ? X[(long)rr*Ci + kt + k] : 0.f;
            int j = idx & 63, kk = idx >> 6;
            int cc = c0 + j;
            sb[kk][j] = (cc < Co) ? W[(long)(kt+kk)*Co + cc] : 0.f;
        }
        __syncthreads();
        #pragma unroll
        for (int k = 0; k < 32; ++k){
            float a0=sa[k][ty*4+0],a1=sa[k][ty*4+1],a2=sa[k][ty*4+2],a3=sa[k][ty*4+3];
            float b0=sb[k][tx*4+0],b1=sb[k][tx*4+1],b2=sb[k][tx*4+2],b3=sb[k][tx*4+3];
            acc[0][0]+=a0*b0; acc[0][1]+=a0*b1; acc[0][2]+=a0*b2; acc[0][3]+=a0*b3;
            acc[1][0]+=a1*b0; acc[1][1]+=a1*b1; acc[1][2]+=a1*b2; acc[1][3]+=a1*b3;
            acc[2][0]+=a2*b0; acc[2][1]+=a2*b1; acc[2][2]+=a2*b2; acc[2][3]+=a2*b3;
            acc[3][0]+=a3*b0; acc[3][1]+=a3*b1; acc[3][2]+=a3*b2; acc[3][3]+=a3*b3;
        }
        __syncthreads();
    }
    #pragma unroll
    for (int r = 0; r < 4; ++r){
        #pragma unroll
        for (int c = 0; c < 4; ++c){
            int rr = r0 + ty*4 + r, cc = c0 + tx*4 + c;
            if (rr < R && cc < Co){
                float v = acc[r][c] + (bias ? bias[cc] : 0.f);
                if (relu) v = fmaxf(v, 0.f);
                out[(long)rr*Co + cc] = v;
            }
        }
    }
}

// ---------------------------------------------------------------- row softmax (K<=64), in place
__global__ void softmax_kernel(float* __restrict__ x, int Kc, float tau){
    int row = blockIdx.x, lane = threadIdx.x;
    bool act = lane < Kc;
    float v = act ? x[(long)row*Kc + lane] / tau : -1e30f;
    float mx = v;
    #pragma unroll
    for (int o = 32; o; o >>= 1) mx = fmaxf(mx, __shfl_xor(mx, o, 64));
    float e = act ? expf(v - mx) : 0.f;
    float s = e;
    #pragma unroll
    for (int o = 32; o; o >>= 1) s += __shfl_xor(s, o, 64);
    if (act) x[(long)row*Kc + lane] = e / s;
}

// ---------------------------------------------------------------- cluster xyz sums + denom (raw)
__global__ void cluster_xyz_kernel(const float* __restrict__ s, const float* __restrict__ xyz,
                                   float* __restrict__ outx, float* __restrict__ outd,
                                   int N, int Kc, int xBS, int dBS){
    __shared__ float red[256];
    int b = blockIdx.y, k = blockIdx.x, t = threadIdx.x;
    s   += (long)b*N*Kc;
    xyz += (long)b*N*3;
    float a0=0,a1=0,a2=0,ad=0;
    for (int n = t; n < N; n += 256){
        float sv = s[(long)n*Kc + k];
        ad += sv;
        a0 += sv*xyz[n*3+0]; a1 += sv*xyz[n*3+1]; a2 += sv*xyz[n*3+2];
    }
    a0 = blockReduceSum(a0, red, 256);
    a1 = blockReduceSum(a1, red, 256);
    a2 = blockReduceSum(a2, red, 256);
    ad = blockReduceSum(ad, red, 256);
    if (t == 0){
        outx[b*xBS + k*3+0] = a0;
        outx[b*xBS + k*3+1] = a1;
        outx[b*xBS + k*3+2] = a2;
        outd[b*dBS + k] = ad;
    }
}

// ---------------------------------------------------------------- f32 sTX for tiny global stage
__global__ __launch_bounds__(256) void gemm_sTX_kernel(const float* __restrict__ s,
                                                       const float* __restrict__ X,
                                                       float* __restrict__ part,
                                                       int N, int Kc, int split,
                                                       long sBS, long xBS){
    __shared__ float sa[32][65], sb[32][65];
    int tid = threadIdx.x, tx = tid & 15, ty = tid >> 4;
    int c0 = blockIdx.x * 64;
    int b = blockIdx.z / split, chunk = blockIdx.z % split;
    int L = N / split, nst = chunk * L;
    s += b*sBS; X += b*xBS;
    float* out = part + (long)blockIdx.z * Kc * 256;
    float acc[4][4] = {};
    for (int nt = nst; nt < nst + L; nt += 32){
        #pragma unroll
        for (int p = 0; p < 8; ++p){
            int idx = p*256 + tid;
            int i = idx & 63, k = idx >> 6;
            sa[k][i] = (i < Kc) ? s[(long)(nt+k)*Kc + i] : 0.f;
            int j = idx & 63, kk = idx >> 6;
            sb[kk][j] = X[(long)(nt+kk)*256 + c0 + j];
        }
        __syncthreads();
        #pragma unroll
        for (int k = 0; k < 32; ++k){
            float a0=sa[k][ty*4+0],a1=sa[k][ty*4+1],a2=sa[k][ty*4+2],a3=sa[k][ty*4+3];
            float b0=sb[k][tx*4+0],b1=sb[k][tx*4+1],b2=sb[k][tx*4+2],b3=sb[k][tx*4+3];
            acc[0][0]+=a0*b0; acc[0][1]+=a0*b1; acc[0][2]+=a0*b2; acc[0][3]+=a0*b3;
            acc[1][0]+=a1*b0; acc[1][1]+=a1*b1; acc[1][2]+=a1*b2; acc[1][3]+=a1*b3;
            acc[2][0]+=a2*b0; acc[2][1]+=a2*b1; acc[2][2]+=a2*b2; acc[2][3]+=a2*b3;
            acc[3][0]+=a3*b0; acc[3][1]+=a3*b1; acc[3][2]+=a3*b2; acc[3][3]+=a3*b3;
        }
        __syncthreads();
    }
    #pragma unroll
    for (int r = 0; r < 4; ++r){
        int kc = ty*4 + r;
        if (kc < Kc){
            #pragma unroll
            for (int c = 0; c < 4; ++c)
                out[(long)kc*256 + c0 + tx*4 + c] = acc[r][c];
        }
    }
}

// ---------------------------------------------------------------- sum partials, divide by denom
__global__ void divide_sum_kernel(const float* __restrict__ part, const float* __restrict__ den,
                                  float* __restrict__ cfea, float* __restrict__ cxyz,
                                  int Kc, int split, int fBS, int xBS, int dBS){
    int b = blockIdx.y, k = blockIdx.x, t = threadIdx.x;
    float d = den[b*dBS + k] + EPSF;
    float s = 0.f;
    for (int q = 0; q < split; ++q)
        s += part[((long)(b*split+q)*Kc + k)*256 + t];
    cfea[(long)b*fBS + k*256 + t] = s / d;
    if (t < 3) cxyz[b*xBS + k*3 + t] /= d;
}

// ---------------------------------------------------------------- level losses: wave per point
__global__ __launch_bounds__(256) void level_loss_kernel(const float* __restrict__ s,
                                                         const float* __restrict__ pxyz,
                                                         const float* __restrict__ cxyz,
                                                         const float* __restrict__ cfea,
                                                         const float* __restrict__ nf,
                                                         float* __restrict__ scal,
                                                         int N, float inv, int ndsSlot){
    __shared__ float cx[192];
    __shared__ float partA[4], partN[4];
    int b = blockIdx.y, t = threadIdx.x, w = t >> 6, l = t & 63;
    s    += (long)b*N*64;
    pxyz += (long)b*N*3;
    nf   += (long)b*N*256;
    cxyz += (long)b*384;
    cfea += (long)b*32768;
    if (t < 192) cx[t] = cxyz[t];
    __syncthreads();
    int n = blockIdx.x*4 + w;
    float sl = s[(long)n*64 + l];
    float px = pxyz[n*3+0], py = pxyz[n*3+1], pz = pxyz[n*3+2];
    float dx = px - cx[l*3+0], dy = py - cx[l*3+1], dz = pz - cx[l*3+2];
    float d2 = dx*dx + dy*dy + dz*dz;
    float assSum = waveSum(sl*d2);
    float dmin = waveMin(d2);
    float c0=0,c1=0,c2=0,c3=0;
    #pragma unroll 8
    for (int k = 0; k < 64; ++k){
        float sk = __shfl(sl, k, 64);
        const float* row = cfea + k*256;
        c0 += sk*row[l]; c1 += sk*row[l+64]; c2 += sk*row[l+128]; c3 += sk*row[l+192];
    }
    float nrm2 = waveSum(c0*c0 + c1*c1 + c2*c2 + c3*c3);
    float inrm = 1.f / fmaxf(sqrtf(nrm2), 1e-12f);
    const float* nfr = nf + (long)n*256;
    float e0 = c0*inrm - nfr[l];
    float e1 = c1*inrm - nfr[l+64];
    float e2 = c2*inrm - nfr[l+128];
    float e3 = c3*inrm - nfr[l+192];
    float nds = waveSum(e0*e0 + e1*e1 + e2*e2 + e3*e3);
    if (l == 0){
        partA[w] = inv*(assSum + 1.f - expf(-0.5f*dmin));
        partN[w] = nds;
    }
    __syncthreads();
    if (t == 0){
        int slot = blockIdx.x & 63;
        atomicAdd(&scal[slot], partA[0]+partA[1]+partA[2]+partA[3]);
        atomicAdd(&scal[ndsSlot*64 + slot], partN[0]+partN[1]+partN[2]+partN[3]);
    }
}

// ---------------------------------------------------------------- knn affinity -> normalized adjacency, fully in LDS
__global__ __launch_bounds__(128) void knn_nac_kernel(const float* __restrict__ cxyz,
                                                      float* __restrict__ nac){
    __shared__ float d2s[128][129];
    __shared__ float x[128][3];
    __shared__ float di[128];
    int b = blockIdx.x, n = threadIdx.x;
    x[n][0] = cxyz[b*384 + n*3+0];
    x[n][1] = cxyz[b*384 + n*3+1];
    x[n][2] = cxyz[b*384 + n*3+2];
    __syncthreads();
    float xn0 = x[n][0], xn1 = x[n][1], xn2 = x[n][2];
    for (int m = 0; m < 128; ++m){
        float dx = xn0-x[m][0], dy = xn1-x[m][1], dz = xn2-x[m][2];
        d2s[n][m] = dx*dx+dy*dy+dz*dz + (m==n ? 1e6f : 0.f);
    }
    // kth smallest (8 distinct-value passes) over own row
    float last = -1.f;
    for (int p = 0; p < 8; ++p){
        float cur = 1e30f;
        for (int m = 0; m < 128; ++m){
            float v = d2s[n][m];
            if (v > last && v < cur) cur = v;
        }
        last = cur;
    }
    // build affinity in place
    for (int m = 0; m < 128; ++m){
        float d2 = d2s[n][m];
        d2s[n][m] = (m != n && d2 <= last) ? expf(-d2) : 0.f;
    }
    __syncthreads();
    // symmetrize (benign race, max is idempotent)
    for (int m = 0; m < 128; ++m){
        float v = fmaxf(d2s[n][m], d2s[m][n]);
        d2s[n][m] = v;
    }
    __syncthreads();
    float deg = 0.f;
    for (int m = 0; m < 128; ++m) deg += d2s[n][m];
    di[n] = rsqrtf(deg + EPSF);
    __syncthreads();
    float* Ab = nac + (long)b*16384;
    for (int c = 0; c < 128; ++c)
        Ab[c*128 + n] = d2s[c][n] * di[c] * di[n];
}

// ---------------------------------------------------------------- Y2 = na_c @ cfea
__global__ void bmm_small_kernel(const float* __restrict__ nac, const float* __restrict__ cfea,
                                 float* __restrict__ Y2){
    __shared__ float row[128];
    int b = blockIdx.y, n = blockIdx.x, t = threadIdx.x;
    if (t < 128) row[t] = nac[(long)b*16384 + n*128 + t];
    __syncthreads();
    float acc = 0.f;
    #pragma unroll 4
    for (int k = 0; k < 128; ++k) acc += row[k]*cfea[(long)b*32768 + k*256 + t];
    Y2[(long)b*32768 + n*256 + t] = acc;
}

// ---------------------------------------------------------------- cut_loss_c
__global__ void cutc_kernel(const float* __restrict__ gs, const float* __restrict__ cxyz,
                            const float* __restrict__ cxyzg, float* __restrict__ scal, float inv){
    __shared__ float cg[48];
    __shared__ float red[128];
    int b = blockIdx.x, t = threadIdx.x;
    if (t < 48) cg[t] = cxyzg[b*48 + t];
    __syncthreads();
    float x0 = cxyz[b*384 + t*3+0], x1 = cxyz[b*384 + t*3+1], x2 = cxyz[b*384 + t*3+2];
    float acc = 0.f;
    #pragma unroll
    for (int k = 0; k < 16; ++k){
        float dx = x0-cg[k*3+0], dy = x1-cg[k*3+1], dz = x2-cg[k*3+2];
        acc += gs[b*2048 + t*16 + k]*(dx*dx+dy*dy+dz*dz);
    }
    acc = blockReduceSum(acc, red, 128);
    if (t == 0) atomicAdd(&scal[b], acc*inv);
}

// ---------------------------------------------------------------- cross attention (M=16) -> AO bf16
__global__ __launch_bounds__(256) void attn_kernel(const float* __restrict__ q,
                                                   const float* __restrict__ kk,
                                                   const float* __restrict__ vv,
                                                   unsigned short* __restrict__ aob){
    __shared__ float Ks[16][256], Vs[16][256];
    int b = blockIdx.y, n = blockIdx.x, t = threadIdx.x;
    #pragma unroll
    for (int p = 0; p < 16; ++p){
        int j = p*256 + t;
        Ks[j>>8][j&255] = kk[b*4096 + j];
        Vs[j>>8][j&255] = vv[b*4096 + j];
    }
    __syncthreads();
    float qv = q[((long)b*1024 + n)*256 + t];
    float sc[16];
    #pragma unroll
    for (int m = 0; m < 16; ++m){
        float v = qv * Ks[m][t];
        #pragma unroll
        for (int o = 32; o; o >>= 1) v += __shfl_xor(v, o, 64);
        sc[m] = v * 0.125f;
    }
    float mx = -1e30f;
    #pragma unroll
    for (int m = 0; m < 16; ++m) mx = fmaxf(mx, sc[m]);
    float sum = 0.f;
    #pragma unroll
    for (int m = 0; m < 16; ++m){ sc[m] = expf(sc[m]-mx); sum += sc[m]; }
    float o = 0.f;
    #pragma unroll
    for (int m = 0; m < 16; ++m) o += sc[m]*Vs[m][t];
    aob[((long)b*1024 + n)*256 + t] = f2bf(o / sum);
}

// ---------------------------------------------------------------- quad: wave per row, bf16 A (N=1024)
__global__ void quad_kernel(const unsigned short* __restrict__ A, const float* __restrict__ dinv,
                            const float* __restrict__ xyz, float* __restrict__ scal){
    __shared__ float part[4];
    int t = threadIdx.x, w = t >> 6, l = t & 63;
    int n = blockIdx.x*4 + w;
    float a0=0,a1=0,a2=0;
    #pragma unroll 4
    for (int i = 0; i < 16; ++i){
        int m = l + i*64;
        float wv = bf2f(A[(long)n*1024 + m])*dinv[m];
        a0 += wv*xyz[m*3+0]; a1 += wv*xyz[m*3+1]; a2 += wv*xyz[m*3+2];
    }
    a0 = waveSum(a0); a1 = waveSum(a1); a2 = waveSum(a2);
    if (l == 0){
        float x0 = xyz[n*3+0], x1 = xyz[n*3+1], x2 = xyz[n*3+2];
        part[w] = (x0*x0+x1*x1+x2*x2) - dinv[n]*(x0*a0+x1*a1+x2*a2);
    }
    __syncthreads();
    if (t == 0) atomicAdd(&scal[4*64 + (blockIdx.x & 63)], part[0]+part[1]+part[2]+part[3]);
}

// ---------------------------------------------------------------- g_loss per-row: wave per row
__global__ void gloss_kernel(const float* __restrict__ agg, const float* __restrict__ gfea,
                             float* __restrict__ scal){
    __shared__ float part[4];
    int t = threadIdx.x, w = t >> 6, l = t & 63;
    long r = (long)blockIdx.x*4 + w;
    const float* a = agg + r*256;
    const float* g = gfea + r*256;
    float a0=a[l],a1=a[l+64],a2=a[l+128],a3=a[l+192];
    float g0=g[l],g1=g[l+64],g2=g[l+128],g3=g[l+192];
    float na2 = waveSum(a0*a0+a1*a1+a2*a2+a3*a3);
    float ng2 = waveSum(g0*g0+g1*g1+g2*g2+g3*g3);
    float ia = 1.f/fmaxf(sqrtf(na2), 1e-12f), ig = 1.f/fmaxf(sqrtf(ng2), 1e-12f);
    float e0=a0*ia-g0*ig, e1=a1*ia-g1*ig, e2=a2*ia-g2*ig, e3=a3*ia-g3*ig;
    float d2 = waveSum(e0*e0+e1*e1+e2*e2+e3*e3);
    if (l == 0) part[w] = sqrtf(d2);
    __syncthreads();
    if (t == 0) atomicAdd(&scal[3*64 + (blockIdx.x & 63)], part[0]+part[1]+part[2]+part[3]);
}

// ---------------------------------------------------------------- finalize
__global__ void finalize_kernel(const float* __restrict__ scal, float* __restrict__ out){
    int t = threadIdx.x;
    float s[5];
    #pragma unroll
    for (int q = 0; q < 5; ++q){
        float v = scal[q*64 + t];
        #pragma unroll
        for (int o = 32; o; o >>= 1) v += __shfl_xor(v, o, 64);
        s[q] = v;
    }
    if (t == 0){
        out[524288] = s[0] + sqrtf(s[1]) + sqrtf(s[2]);
        out[524289] = s[3]*0.5f + 1e-4f*s[4]/2048.0f;
    }
}

// ================================================================ launcher
extern "C" void kernel_launch(void* const* d_in, const int* in_sizes, int n_in,
                              void* d_out, int out_size, void* d_ws, size_t ws_size,
                              hipStream_t stream){
    const float* g_fea   = (const float*)d_in[0];
    const float* g_xyz   = (const float*)d_in[1];
    const float* p_fea_0 = (const float*)d_in[2];
    const float* p_xyz_0 = (const float*)d_in[3];
    const float* p_fea_1 = (const float*)d_in[4];
    const float* p_xyz_1 = (const float*)d_in[5];
    const float* lW1 = (const float*)d_in[6];
    const float* lb1 = (const float*)d_in[7];
    const float* lW2 = (const float*)d_in[8];
    const float* lb2 = (const float*)d_in[9];
    const float* gW1 = (const float*)d_in[10];
    const float* gb1 = (const float*)d_in[11];
    const float* gW2 = (const float*)d_in[12];
    const float* gb2 = (const float*)d_in[13];
    const float* Wq = (const float*)d_in[14];
    const float* Wk = (const float*)d_in[15];
    const float* Wv = (const float*)d_in[16];
    const float* Wo = (const float*)d_in[17];
    float* out = (float*)d_out;
    float* ws_f = (float*)d_ws;

    // ---- workspace layout (float units)
    constexpr long O_SCALS = 0;                          // 8*64 spread slots
    constexpr long O_CFEA  = 512;                        // (B,128,256) f32
    constexpr long O_CXYZ  = O_CFEA + 65536;             // (B,128,3)
    constexpr long O_DEN   = O_CXYZ + 768;               // (B,128)
    constexpr long O_CFG   = O_DEN  + 256;               // (B,16,256)
    constexpr long O_CXG   = O_CFG  + 8192;              // (B,16,3)
    constexpr long O_DENG  = O_CXG  + 96;                // (B,16)+pad
    constexpr long O_PART  = O_DENG + 64;                // 262144
    constexpr long O_NF    = O_PART + 262144;            // f32 (2*4096,256)
    constexpr long O_NFB   = O_NF   + 2097152;           // bf16 (2*4096,256)
    constexpr long O_XST   = O_NFB  + 1048576;           // bf16 (2,256,4096)
    constexpr long O_FEAT  = O_XST  + 1048576;           // bf16 (2,256,4096)
    constexpr long O_YB    = O_FEAT + 1048576;           // bf16 (2,N,256)
    constexpr long O_HB    = O_YB   + 1048576;           // bf16 (2N,128)
    constexpr long O_S     = O_HB   + 524288;            // f32 (2N,64)
    constexpr long O_ST    = O_S    + 524288;            // bf16 (64, 2*4096)
    constexpr long O_DINV  = O_ST   + 262144;            // (2*4096)
    constexpr long O_PY    = O_DINV + 8192;              // f32 2*(N,256)
    constexpr long O_A     = O_PY   + 2097152;           // bf16 (4096,4096)
    constexpr long O_Q     = O_A    + 8388608;           // f32 (2048,256)
    constexpr long O_GFB   = O_Q    + 524288;            // bf16 g_fea
    constexpr long O_AOB   = O_GFB  + 262144;            // bf16 attn-out
    constexpr long O_KK    = O_AOB  + 262144;
    constexpr long O_VV    = O_KK   + 8192;
    constexpr long O_NAC   = O_VV   + 8192;
    constexpr long O_Y2    = O_NAC  + 32768;
    constexpr long O_H2    = O_Y2   + 65536;
    constexpr long O_LG2   = O_H2   + 32768;
    constexpr long O_W1T   = O_LG2  + 4096;              // bf16 (128,256)
    constexpr long O_W2T   = O_W1T  + 16384;             // bf16 (64,128)
    constexpr long O_WQT   = O_W2T  + 4096;              // bf16 (256,256)
    constexpr long O_WOT   = O_WQT  + 32768;             // bf16 (256,256)

    hipMemsetAsync(ws_f + O_SCALS, 0, 512*sizeof(float), stream);

    float* nf   = ws_f + O_NF;
    unsigned short* nfb  = (unsigned short*)(ws_f + O_NFB);
    unsigned short* xsT  = (unsigned short*)(ws_f + O_XST);
    unsigned short* feaT = (unsigned short*)(ws_f + O_FEAT);
    unsigned short* Ybb  = (unsigned short*)(ws_f + O_YB);
    unsigned short* Hb   = (unsigned short*)(ws_f + O_HB);
    unsigned short* sTb  = (unsigned short*)(ws_f + O_ST);
    unsigned short* A    = (unsigned short*)(ws_f + O_A);
    unsigned short* gfb  = (unsigned short*)(ws_f + O_GFB);
    unsigned short* aob  = (unsigned short*)(ws_f + O_AOB);
    unsigned short* lW1T = (unsigned short*)(ws_f + O_W1T);
    unsigned short* lW2T = (unsigned short*)(ws_f + O_W2T);
    unsigned short* WqT  = (unsigned short*)(ws_f + O_WQT);
    unsigned short* WoT  = (unsigned short*)(ws_f + O_WOT);
    float* sb   = ws_f + O_S;
    float* dinv = ws_f + O_DINV;
    float* PY   = ws_f + O_PY;
    float* part = ws_f + O_PART;
    float* Qf   = ws_f + O_Q;

    // weight conversions (once per call)
    tcvt_kernel<<<dim3(4, 2), 256, 0, stream>>>(lW1, lW1T, 256, 128);
    tcvt_kernel<<<dim3(2, 1), 256, 0, stream>>>(lW2, lW2T, 128, 64);
    tcvt_kernel<<<dim3(4, 4), 256, 0, stream>>>(Wq, WqT, 256, 256);
    tcvt_kernel<<<dim3(4, 4), 256, 0, stream>>>(Wo, WoT, 256, 256);
    cvt_bf16_kernel<<<512, 256, 0, stream>>>(g_fea, gfb, 131072);

    struct Lvl { const float* fea; const float* xyz; int N; int k0; int ndsSlot; };
    Lvl lv[2] = {{p_fea_0, p_xyz_0, 4096, 0, 1}, {p_fea_1, p_xyz_1, 2048, 64, 2}};

    for (int L = 0; L < 2; ++L){
        int N = lv[L].N;
        const float* fea = lv[L].fea;
        const float* xyz = lv[L].xyz;
        l2norm_kernel<<<2*N, 256, 0, stream>>>(fea, nf, nfb, 2*N);
        for (int b = 0; b < 2; ++b){
            const unsigned short* nfbb = nfb + (long)b*N*256;
            const float* xyzb = xyz + (long)b*N*3;
            gram_mfma_kernel<<<dim3(N/128, N/128), 256, 0, stream>>>(nfbb, xyzb, A, N, 1.0f, 0.25f);
            rowsum_kernel<<<N, 256, 0, stream>>>(A, dinv + b*N, N);
            transpose_scale_kernel<<<dim3(N/64, 4), 256, 0, stream>>>(fea + (long)b*N*256, dinv + b*N,
                                                                      feaT + (long)b*256*N,
                                                                      xsT + (long)b*256*N, N);
            ax_mfma_kernel<<<dim3(2, N/128, 2), 256, 0, stream>>>(A, xsT + (long)b*256*N, PY, N);
            combine_kernel<<<N/8, 256, 0, stream>>>(PY, dinv + b*N, Ybb + (long)b*N*256, N);
        }
        // h = relu(Yb @ lW1 + b1) -> bf16 ; s = h @ lW2 + b2 -> f32
        gemm_XW_mfma_kernel<<<dim3(1, 2*N/128), 256, 0, stream>>>(Ybb, lW1T, lb1, nullptr, Hb,
                                                                  2*N, 256, 128, 1);
        gemm_XW_mfma_kernel<<<dim3(1, 2*N/128), 256, 0, stream>>>(Hb, lW2T, lb2, sb, nullptr,
                                                                  2*N, 128, 64, 0);
        softmaxT_kernel<<<2*N/64, 256, 0, stream>>>(sb, sTb, 2*N, 10.0f);
        cluster_xyz_kernel<<<dim3(64, 2), 256, 0, stream>>>(sb, xyz, ws_f + O_CXYZ + lv[L].k0*3,
                                                            ws_f + O_DEN + lv[L].k0, N, 64, 384, 128);
        stx_mfma_kernel<<<16, 256, 0, stream>>>(sTb, feaT, part, N, 8, 2*N);
        divide_sum_kernel<<<dim3(64, 2), 256, 0, stream>>>(part, ws_f + O_DEN + lv[L].k0,
                                                           ws_f + O_CFEA + lv[L].k0*256,
                                                           ws_f + O_CXYZ + lv[L].k0*3,
                                                           64, 8, 128*256, 384, 128);
        level_loss_kernel<<<dim3(N/4, 2), 256, 0, stream>>>(sb, xyz, ws_f + O_CXYZ + lv[L].k0*3,
                                                            ws_f + O_CFEA + lv[L].k0*256, nf,
                                                            ws_f + O_SCALS, N, 1.0f/(2.0f*N), lv[L].ndsSlot);
    }

    // ---- global cluster stage
    knn_nac_kernel<<<2, 128, 0, stream>>>(ws_f + O_CXYZ, ws_f + O_NAC);
    bmm_small_kernel<<<dim3(128, 2), 256, 0, stream>>>(ws_f + O_NAC, ws_f + O_CFEA, ws_f + O_Y2);
    gemm_XW_kernel<<<dim3(2, 4), 256, 0, stream>>>(ws_f + O_Y2, gW1, gb1, ws_f + O_H2, 256, 256, 128, 1);
    gemm_XW_kernel<<<dim3(1, 4), 256, 0, stream>>>(ws_f + O_H2, gW2, gb2, ws_f + O_LG2, 256, 128, 16, 0);
    softmax_kernel<<<256, 64, 0, stream>>>(ws_f + O_LG2, 16, 0.1f);
    cluster_xyz_kernel<<<dim3(16, 2), 256, 0, stream>>>(ws_f + O_LG2, ws_f + O_CXYZ,
                                                        ws_f + O_CXG, ws_f + O_DENG, 128, 16, 48, 16);
    gemm_sTX_kernel<<<dim3(4, 1, 2), 256, 0, stream>>>(ws_f + O_LG2, ws_f + O_CFEA, part,
                                                       128, 16, 1, 128L*16, 128L*256);
    divide_sum_kernel<<<dim3(16, 2), 256, 0, stream>>>(part, ws_f + O_DENG, ws_f + O_CFG,
                                                       ws_f + O_CXG, 16, 1, 16*256, 48, 16);
    cutc_kernel<<<2, 128, 0, stream>>>(ws_f + O_LG2, ws_f + O_CXYZ, ws_f + O_CXG,
                                       ws_f + O_SCALS, 1.0f/256.0f);

    // ---- cross attention (Q,Wo via MFMA; K,V tiny f32)
    gemm_XW_mfma_kernel<<<dim3(2, 16), 256, 0, stream>>>(gfb, WqT, nullptr, Qf, nullptr,
                                                         2048, 256, 256, 0);
    gemm_XW_kernel<<<dim3(4, 1), 256, 0, stream>>>(ws_f + O_CFG, Wk, nullptr, ws_f + O_KK, 32, 256, 256, 0);
    gemm_XW_kernel<<<dim3(4, 1), 256, 0, stream>>>(ws_f + O_CFG, Wv, nullptr, ws_f + O_VV, 32, 256, 256, 0);
    attn_kernel<<<dim3(1024, 2), 256, 0, stream>>>(Qf, ws_f + O_KK, ws_f + O_VV, aob);
    gemm_XW_mfma_kernel<<<dim3(2, 16), 256, 0, stream>>>(aob, WoT, nullptr, out, nullptr,
                                                         2048, 256, 256, 0);

    // ---- A_g stage
    l2norm_kernel<<<2048, 256, 0, stream>>>(g_fea, nf, nfb, 2048);
    for (int b = 0; b < 2; ++b){
        gram_mfma_kernel<<<dim3(8, 8), 256, 0, stream>>>(nfb + (long)b*1024*256, g_xyz + (long)b*1024*3,
                                                         A, 1024, 16.0f, 0.25f);
        rowsum_kernel<<<1024, 256, 0, stream>>>(A, dinv + b*1024, 1024);
        quad_kernel<<<256, 256, 0, stream>>>(A, dinv + b*1024, g_xyz + (long)b*1024*3, ws_f + O_SCALS);
    }

    gloss_kernel<<<512, 256, 0, stream>>>(out, g_fea, ws_f + O_SCALS);
    finalize_kernel<<<1, 64, 0, stream>>>(ws_f + O_SCALS, out);
}

// Round 5
// 782.877 us; speedup vs baseline: 3.0303x; 1.1582x over previous
//
#include <hip/hip_runtime.h>

#define EPSF 1e-4f

typedef __attribute__((ext_vector_type(8))) short bf16x8;
typedef __attribute__((ext_vector_type(4))) float f32x4;

__device__ __forceinline__ unsigned short f2bf(float f){
    unsigned int u = __float_as_uint(f);
    return (unsigned short)((u + 0x7FFF + ((u >> 16) & 1)) >> 16);
}
__device__ __forceinline__ float bf2f(unsigned short u){
    return __uint_as_float(((unsigned int)u) << 16);
}
__device__ __forceinline__ float waveSum(float v){
    #pragma unroll
    for (int o = 32; o; o >>= 1) v += __shfl_xor(v, o, 64);
    return v;
}
__device__ __forceinline__ float waveMin(float v){
    #pragma unroll
    for (int o = 32; o; o >>= 1) v = fminf(v, __shfl_xor(v, o, 64));
    return v;
}
__device__ __forceinline__ float waveMax(float v){
    #pragma unroll
    for (int o = 32; o; o >>= 1) v = fmaxf(v, __shfl_xor(v, o, 64));
    return v;
}
__device__ __forceinline__ float blockReduceSum(float v, float* red, int nthr){
    int t = threadIdx.x;
    red[t] = v; __syncthreads();
    for (int s = nthr >> 1; s > 0; s >>= 1){
        if (t < s) red[t] += red[t + s];
        __syncthreads();
    }
    float r = red[0]; __syncthreads();
    return r;
}

// ---------------------------------------------------------------- l2norm rows of 256 -> f32 + bf16
__global__ void l2norm_kernel(const float* __restrict__ x, float* __restrict__ outf,
                              unsigned short* __restrict__ outb, int rows){
    __shared__ float red[256];
    int row = blockIdx.x, t = threadIdx.x;
    float v = x[(long)row*256 + t];
    float s = blockReduceSum(v*v, red, 256);
    float nrm = fmaxf(sqrtf(s), 1e-12f);
    float r = v / nrm;
    outf[(long)row*256 + t] = r;
    outb[(long)row*256 + t] = f2bf(r);
}

// ---------------------------------------------------------------- flat f32 -> bf16
__global__ void cvt_bf16_kernel(const float* __restrict__ in, unsigned short* __restrict__ out, long n4){
    long i = (long)blockIdx.x*256 + threadIdx.x;
    if (i < n4){
        float4 v = ((const float4*)in)[i];
        unsigned int lo = f2bf(v.x) | ((unsigned int)f2bf(v.y) << 16);
        unsigned int hi = f2bf(v.z) | ((unsigned int)f2bf(v.w) << 16);
        uint2 u; u.x = lo; u.y = hi;
        ((uint2*)out)[i] = u;
    }
}

// ---------------------------------------------------------------- transpose+cvt weight: W(Rw,Cw) -> WT(Cw,Rw) bf16
__global__ void tcvt_kernel(const float* __restrict__ W, unsigned short* __restrict__ WT,
                            int Rw, int Cw){
    __shared__ float tile[64][65];
    int r0 = blockIdx.x*64, c0 = blockIdx.y*64;
    int t = threadIdx.x;
    for (int idx = t; idx < 4096; idx += 256){
        int rr = idx >> 6, cc = idx & 63;
        tile[rr][cc] = (r0+rr < Rw && c0+cc < Cw) ? W[(long)(r0+rr)*Cw + c0+cc] : 0.f;
    }
    __syncthreads();
    for (int idx = t; idx < 4096; idx += 256){
        int cc = idx >> 6, rr = idx & 63;
        if (r0+rr < Rw && c0+cc < Cw)
            WT[(long)(c0+cc)*Rw + r0+rr] = f2bf(tile[rr][cc]);
    }
}

// ---------------------------------------------------------------- MFMA gram: A = exp(scale*(2dot-2)) * mask, bf16 out
// also accumulates row degree sums into deg via atomics (deg pre-zeroed)
__global__ __launch_bounds__(256) void gram_mfma_kernel(const unsigned short* __restrict__ nf,
                                                        const float* __restrict__ xyz,
                                                        unsigned short* __restrict__ A,
                                                        float* __restrict__ deg,
                                                        int N, float r2, float scale){
    __shared__ short tA[128*32], tB[128*32];
    __shared__ float xa[384], xb[384];
    int tid = threadIdx.x;
    int n0 = blockIdx.y*128, m0 = blockIdx.x*128;
    for (int i = tid; i < 384; i += 256){ xa[i] = xyz[n0*3 + i]; xb[i] = xyz[m0*3 + i]; }
    int w = tid >> 6, l = tid & 63;
    int wy = w >> 1, wx = w & 1;
    int lg = l >> 4, lr = l & 15;
    int srow = tid >> 2, sc = tid & 3;
    f32x4 zero = {0.f, 0.f, 0.f, 0.f};
    f32x4 acc[4][4];
    #pragma unroll
    for (int i = 0; i < 4; ++i)
        #pragma unroll
        for (int j = 0; j < 4; ++j) acc[i][j] = zero;
    for (int kt = 0; kt < 256; kt += 32){
        __syncthreads();
        #pragma unroll
        for (int p = 0; p < 2; ++p){
            int row = srow + p*64;
            uint4 va = *(const uint4*)(nf + (long)(n0+row)*256 + kt + sc*8);
            uint4 vb = *(const uint4*)(nf + (long)(m0+row)*256 + kt + sc*8);
            *(uint4*)(tA + row*32 + sc*8) = va;
            *(uint4*)(tB + row*32 + sc*8) = vb;
        }
        __syncthreads();
        bf16x8 af[4], bfr[4];
        #pragma unroll
        for (int f = 0; f < 4; ++f){
            af[f]  = *(const bf16x8*)(tA + (wy*64 + f*16 + lr)*32 + lg*8);
            bfr[f] = *(const bf16x8*)(tB + (wx*64 + f*16 + lr)*32 + lg*8);
        }
        #pragma unroll
        for (int i = 0; i < 4; ++i)
            #pragma unroll
            for (int j = 0; j < 4; ++j)
                acc[i][j] = __builtin_amdgcn_mfma_f32_16x16x32_bf16(af[i], bfr[j], acc[i][j], 0, 0, 0);
    }
    #pragma unroll
    for (int fi = 0; fi < 4; ++fi){
        #pragma unroll
        for (int r = 0; r < 4; ++r){
            int n_ = wy*64 + fi*16 + lg*4 + r;
            int gn = n0 + n_;
            float rowacc = 0.f;
            #pragma unroll
            for (int fj = 0; fj < 4; ++fj){
                int m_ = wx*64 + fj*16 + lr;
                float dx = xa[n_*3+0]-xb[m_*3+0];
                float dy = xa[n_*3+1]-xb[m_*3+1];
                float dz = xa[n_*3+2]-xb[m_*3+2];
                float d2x = dx*dx + dy*dy + dz*dz;
                int gm = m0 + m_;
                float dot = acc[fi][fj][r];
                float val = (d2x < r2 && gn != gm) ? expf(scale*(2.f*dot - 2.f)) : 0.f;
                A[(long)gn*N + gm] = f2bf(val);
                rowacc += val;
            }
            rowacc += __shfl_xor(rowacc, 1, 64);
            rowacc += __shfl_xor(rowacc, 2, 64);
            rowacc += __shfl_xor(rowacc, 4, 64);
            rowacc += __shfl_xor(rowacc, 8, 64);
            if (lr == 0) atomicAdd(&deg[gn], rowacc);
        }
    }
}

// ---------------------------------------------------------------- feaT[c][m] = fea[m][c] (raw) ; xsT[c][m] = fea[m][c]*rsqrt(deg[m]+eps)
__global__ __launch_bounds__(256) void transpose_scale_kernel(const float* __restrict__ fea,
                                                              const float* __restrict__ deg,
                                                              unsigned short* __restrict__ feaT,
                                                              unsigned short* __restrict__ xsT, int N){
    __shared__ float tile[64][65];
    __shared__ float dl[64];
    int m0 = blockIdx.x*64, c0 = blockIdx.y*64;
    int t = threadIdx.x;
    int lr = t >> 2, lc = (t & 3)*16;
    #pragma unroll
    for (int j = 0; j < 4; ++j){
        float4 v = *(const float4*)(fea + (long)(m0+lr)*256 + c0 + lc + j*4);
        tile[lr][lc+j*4+0] = v.x; tile[lr][lc+j*4+1] = v.y;
        tile[lr][lc+j*4+2] = v.z; tile[lr][lc+j*4+3] = v.w;
    }
    if (t < 64) dl[t] = rsqrtf(deg[m0+t] + EPSF);
    __syncthreads();
    unsigned short vr[16] __attribute__((aligned(16)));
    unsigned short vs[16] __attribute__((aligned(16)));
    #pragma unroll
    for (int j = 0; j < 16; ++j){
        float raw = tile[lc+j][lr];
        vr[j] = f2bf(raw);
        vs[j] = f2bf(raw * dl[lc+j]);
    }
    long off = (long)(c0+lr)*N + m0 + lc;
    *(uint4*)(feaT + off)     = *(uint4*)&vr[0];
    *(uint4*)(feaT + off + 8) = *(uint4*)&vr[8];
    *(uint4*)(xsT + off)      = *(uint4*)&vs[0];
    *(uint4*)(xsT + off + 8)  = *(uint4*)&vs[8];
}

// ---------------------------------------------------------------- MFMA A@XsT^T -> PY partials (split 2)
__global__ __launch_bounds__(256) void ax_mfma_kernel(const unsigned short* __restrict__ A,
                                                      const unsigned short* __restrict__ xsT,
                                                      float* __restrict__ PY, int N){
    __shared__ short tA[128*32], tB[128*32];
    int tid = threadIdx.x;
    int c0 = blockIdx.x*128, n0 = blockIdx.y*128;
    int half = blockIdx.z;
    int kbase = half*(N/2), kend = kbase + N/2;
    int w = tid >> 6, l = tid & 63;
    int wy = w >> 1, wx = w & 1;
    int lg = l >> 4, lr = l & 15;
    int srow = tid >> 2, sc = tid & 3;
    f32x4 zero = {0.f, 0.f, 0.f, 0.f};
    f32x4 acc[4][4];
    #pragma unroll
    for (int i = 0; i < 4; ++i)
        #pragma unroll
        for (int j = 0; j < 4; ++j) acc[i][j] = zero;
    for (int kt = kbase; kt < kend; kt += 32){
        __syncthreads();
        #pragma unroll
        for (int p = 0; p < 2; ++p){
            int row = srow + p*64;
            uint4 va = *(const uint4*)(A   + (long)(n0+row)*N + kt + sc*8);
            uint4 vb = *(const uint4*)(xsT + (long)(c0+row)*N + kt + sc*8);
            *(uint4*)(tA + row*32 + sc*8) = va;
            *(uint4*)(tB + row*32 + sc*8) = vb;
        }
        __syncthreads();
        bf16x8 af[4], bfr[4];
        #pragma unroll
        for (int f = 0; f < 4; ++f){
            af[f]  = *(const bf16x8*)(tA + (wy*64 + f*16 + lr)*32 + lg*8);
            bfr[f] = *(const bf16x8*)(tB + (wx*64 + f*16 + lr)*32 + lg*8);
        }
        #pragma unroll
        for (int i = 0; i < 4; ++i)
            #pragma unroll
            for (int j = 0; j < 4; ++j)
                acc[i][j] = __builtin_amdgcn_mfma_f32_16x16x32_bf16(af[i], bfr[j], acc[i][j], 0, 0, 0);
    }
    float* out = PY + (long)half*N*256;
    #pragma unroll
    for (int fi = 0; fi < 4; ++fi){
        #pragma unroll
        for (int fj = 0; fj < 4; ++fj){
            #pragma unroll
            for (int r = 0; r < 4; ++r){
                int n_ = n0 + wy*64 + fi*16 + lg*4 + r;
                int c_ = c0 + wx*64 + fj*16 + lr;
                out[(long)n_*256 + c_] = acc[fi][fj][r];
            }
        }
    }
}

// ---------------------------------------------------------------- Yb(bf16) = rsqrt(deg[n])*(P0+P1)
__global__ void combine_kernel(const float* __restrict__ PY, const float* __restrict__ deg,
                               unsigned short* __restrict__ Yb, int N){
    long i = (long)blockIdx.x*256 + threadIdx.x;  // 8 elems per thread
    long e = i*8;
    const float4* p0 = (const float4*)(PY + e);
    const float4* p1 = (const float4*)(PY + (long)N*256 + e);
    float4 a0 = p0[0], a1 = p0[1], b0 = p1[0], b1 = p1[1];
    float d = rsqrtf(deg[e >> 8] + EPSF);
    unsigned short vb[8] __attribute__((aligned(16)));
    vb[0] = f2bf((a0.x+b0.x)*d); vb[1] = f2bf((a0.y+b0.y)*d);
    vb[2] = f2bf((a0.z+b0.z)*d); vb[3] = f2bf((a0.w+b0.w)*d);
    vb[4] = f2bf((a1.x+b1.x)*d); vb[5] = f2bf((a1.y+b1.y)*d);
    vb[6] = f2bf((a1.z+b1.z)*d); vb[7] = f2bf((a1.w+b1.w)*d);
    *(uint4*)(Yb + e) = *(uint4*)vb;
}

// ---------------------------------------------------------------- MFMA X(R,Ci)bf16 @ WT(Co,Ci)bf16 + bias [relu] -> f32/bf16
__global__ __launch_bounds__(256) void gemm_XW_mfma_kernel(const unsigned short* __restrict__ X,
                                                           const unsigned short* __restrict__ WT,
                                                           const float* __restrict__ bias,
                                                           float* __restrict__ outF,
                                                           unsigned short* __restrict__ outB,
                                                           int R, int Ci, int Co, int relu){
    __shared__ short tA[128*32], tB[128*32];
    int tid = threadIdx.x;
    int c0 = blockIdx.x*128, r0 = blockIdx.y*128;
    int w = tid >> 6, l = tid & 63;
    int wy = w >> 1, wx = w & 1;
    int lg = l >> 4, lr = l & 15;
    int srow = tid >> 2, sc = tid & 3;
    f32x4 zero = {0.f, 0.f, 0.f, 0.f};
    f32x4 acc[4][4];
    #pragma unroll
    for (int i = 0; i < 4; ++i)
        #pragma unroll
        for (int j = 0; j < 4; ++j) acc[i][j] = zero;
    for (int kt = 0; kt < Ci; kt += 32){
        __syncthreads();
        #pragma unroll
        for (int p = 0; p < 2; ++p){
            int row = srow + p*64;
            uint4 va = {0,0,0,0}, vb = {0,0,0,0};
            int ar = r0 + row, br = c0 + row;
            if (ar < R)  va = *(const uint4*)(X  + (long)ar*Ci + kt + sc*8);
            if (br < Co) vb = *(const uint4*)(WT + (long)br*Ci + kt + sc*8);
            *(uint4*)(tA + row*32 + sc*8) = va;
            *(uint4*)(tB + row*32 + sc*8) = vb;
        }
        __syncthreads();
        bf16x8 af[4], bfr[4];
        #pragma unroll
        for (int f = 0; f < 4; ++f){
            af[f]  = *(const bf16x8*)(tA + (wy*64 + f*16 + lr)*32 + lg*8);
            bfr[f] = *(const bf16x8*)(tB + (wx*64 + f*16 + lr)*32 + lg*8);
        }
        #pragma unroll
        for (int i = 0; i < 4; ++i)
            #pragma unroll
            for (int j = 0; j < 4; ++j)
                acc[i][j] = __builtin_amdgcn_mfma_f32_16x16x32_bf16(af[i], bfr[j], acc[i][j], 0, 0, 0);
    }
    #pragma unroll
    for (int fi = 0; fi < 4; ++fi){
        #pragma unroll
        for (int fj = 0; fj < 4; ++fj){
            #pragma unroll
            for (int r = 0; r < 4; ++r){
                int rr = r0 + wy*64 + fi*16 + lg*4 + r;
                int cc = c0 + wx*64 + fj*16 + lr;
                if (rr < R && cc < Co){
                    float v = acc[fi][fj][r] + (bias ? bias[cc] : 0.f);
                    if (relu) v = fmaxf(v, 0.f);
                    if (outF) outF[(long)rr*Co + cc] = v;
                    if (outB) outB[(long)rr*Co + cc] = f2bf(v);
                }
            }
        }
    }
}

// ---------------------------------------------------------------- split-K f32 GEMM -> partials (latency-parallel small gemms)
// z = blockIdx.z ; mat = z/Ks picks W0/W1 ; k-chunk = Ci/Ks
__global__ __launch_bounds__(256) void gemm_splitk_kernel(const float* __restrict__ X,
                                                          const float* __restrict__ W0,
                                                          const float* __restrict__ W1,
                                                          float* __restrict__ part,
                                                          int R, int Ci, int Co, int Ks){
    __shared__ float sa[32][65], sb[32][65];
    int tid = threadIdx.x, tx = tid & 15, ty = tid >> 4;
    int c0 = blockIdx.x * 64, r0 = blockIdx.y * 64;
    int z = blockIdx.z;
    const float* W = (z / Ks) ? W1 : W0;
    int kchunk = Ci / Ks, kst = (z % Ks) * kchunk;
    float acc[4][4] = {};
    for (int kt = kst; kt < kst + kchunk; kt += 32){
        #pragma unroll
        for (int p = 0; p < 8; ++p){
            int idx = p*256 + tid;
            int k = idx & 31, i = idx >> 5;
            int rr = r0 + i;
            sa[k][i] = (rr < R) ? X[(long)rr*Ci + kt + k] : 0.f;
            int j = idx & 63, kk = idx >> 6;
            int cc = c0 + j;
            sb[kk][j] = (cc < Co) ? W[(long)(kt+kk)*Co + cc] : 0.f;
        }
        __syncthreads();
        #pragma unroll
        for (int k = 0; k < 32; ++k){
            float a0=sa[k][ty*4+0],a1=sa[k][ty*4+1],a2=sa[k][ty*4+2],a3=sa[k][ty*4+3];
            float b0=sb[k][tx*4+0],b1=sb[k][tx*4+1],b2=sb[k][tx*4+2],b3=sb[k][tx*4+3];
            acc[0][0]+=a0*b0; acc[0][1]+=a0*b1; acc[0][2]+=a0*b2; acc[0][3]+=a0*b3;
            acc[1][0]+=a1*b0; acc[1][1]+=a1*b1; acc[1][2]+=a1*b2; acc[1][3]+=a1*b3;
            acc[2][0]+=a2*b0; acc[2][1]+=a2*b1; acc[2][2]+=a2*b2; acc[2][3]+=a2*b3;
            acc[3][0]+=a3*b0; acc[3][1]+=a3*b1; acc[3][2]+=a3*b2; acc[3][3]+=a3*b3;
        }
        __syncthreads();
    }
    float* outp = part + (long)z*R*Co;
    #pragma unroll
    for (int r = 0; r < 4; ++r){
        #pragma unroll
        for (int c = 0; c < 4; ++c){
            int rr = r0 + ty*4 + r, cc = c0 + tx*4 + c;
            if (rr < R && cc < Co) outp[(long)rr*Co + cc] = acc[r][c];
        }
    }
}

// ---------------------------------------------------------------- sum split-K partials + bias [+relu]
__global__ void combine_bias_kernel(const float* __restrict__ part, const float* __restrict__ bias,
                                    float* __restrict__ out, int R, int Co, int Ks, int relu){
    long i = (long)blockIdx.x*256 + threadIdx.x;
    if (i < (long)R*Co){
        long zs = (long)R*Co;
        float s = 0.f;
        for (int q = 0; q < Ks; ++q) s += part[q*zs + i];
        float v = s + (bias ? bias[i % Co] : 0.f);
        if (relu) v = fmaxf(v, 0.f);
        out[i] = v;
    }
}

// ---------------------------------------------------------------- softmax rows of 64 (in place, f32) + sT bf16
__global__ __launch_bounds__(256) void softmaxT_kernel(float* __restrict__ s,
                                                       unsigned short* __restrict__ sT,
                                                       int sStride, float invtau){
    __shared__ unsigned short st[64][65];
    int blk = blockIdx.x, t = threadIdx.x, w = t >> 6, l = t & 63;
    #pragma unroll
    for (int i = 0; i < 16; ++i){
        int rloc = w + 4*i;
        long row = (long)blk*64 + rloc;
        float v = s[row*64 + l] * invtau;
        float mx = waveMax(v);
        float e = expf(v - mx);
        float sum = waveSum(e);
        float p = e / sum;
        s[row*64 + l] = p;
        st[l][rloc] = f2bf(p);
    }
    __syncthreads();
    int k = t >> 2, j = (t & 3)*16;
    unsigned short vbuf[16] __attribute__((aligned(16)));
    #pragma unroll
    for (int q = 0; q < 16; ++q) vbuf[q] = st[k][j+q];
    long off = (long)k*sStride + (long)blk*64 + j;
    *(uint4*)(sT + off)     = *(uint4*)&vbuf[0];
    *(uint4*)(sT + off + 8) = *(uint4*)&vbuf[8];
}

// ---------------------------------------------------------------- MFMA sT(64,2N) @ feaT(256,N)^T -> part per (b,chunk)
__global__ __launch_bounds__(256) void stx_mfma_kernel(const unsigned short* __restrict__ sT,
                                                       const unsigned short* __restrict__ feaT,
                                                       float* __restrict__ part,
                                                       int N, int split, int sStride){
    __shared__ short tA[64*32], tB[256*32];
    int tid = threadIdx.x;
    int z = blockIdx.x, b = z / split, chunk = z % split;
    int L = N / split, kst = chunk * L;
    const unsigned short* sTb = sT + (long)b*N;
    const unsigned short* fT  = feaT + (long)b*256*N;
    int w = tid >> 6, l = tid & 63;
    int lg = l >> 4, lr = l & 15;
    f32x4 zero = {0.f, 0.f, 0.f, 0.f};
    f32x4 acc[4][4];
    #pragma unroll
    for (int i = 0; i < 4; ++i)
        #pragma unroll
        for (int j = 0; j < 4; ++j) acc[i][j] = zero;
    int srow = tid >> 2, koff = (tid & 3)*8;
    for (int kt = kst; kt < kst + L; kt += 32){
        __syncthreads();
        *(uint4*)(tA + srow*32 + koff) = *(const uint4*)(sTb + (long)srow*sStride + kt + koff);
        #pragma unroll
        for (int p = 0; p < 4; ++p){
            int row = srow + p*64;
            *(uint4*)(tB + row*32 + koff) = *(const uint4*)(fT + (long)row*N + kt + koff);
        }
        __syncthreads();
        bf16x8 af[4], bfr[4];
        #pragma unroll
        for (int f = 0; f < 4; ++f){
            af[f]  = *(const bf16x8*)(tA + (f*16 + lr)*32 + lg*8);
            bfr[f] = *(const bf16x8*)(tB + (w*64 + f*16 + lr)*32 + lg*8);
        }
        #pragma unroll
        for (int i = 0; i < 4; ++i)
            #pragma unroll
            for (int j = 0; j < 4; ++j)
                acc[i][j] = __builtin_amdgcn_mfma_f32_16x16x32_bf16(af[i], bfr[j], acc[i][j], 0, 0, 0);
    }
    float* outp = part + (long)z*64*256;
    #pragma unroll
    for (int fi = 0; fi < 4; ++fi){
        #pragma unroll
        for (int fj = 0; fj < 4; ++fj){
            #pragma unroll
            for (int r = 0; r < 4; ++r){
                int kc = fi*16 + lg*4 + r;
                int cc = w*64 + fj*16 + lr;
                outp[(long)kc*256 + cc] = acc[fi][fj][r];
            }
        }
    }
}

// ---------------------------------------------------------------- row softmax (K<=64), in place
__global__ void softmax_kernel(float* __restrict__ x, int Kc, float tau){
    int row = blockIdx.x, lane = threadIdx.x;
    bool act = lane < Kc;
    float v = act ? x[(long)row*Kc + lane] / tau : -1e30f;
    float mx = v;
    #pragma unroll
    for (int o = 32; o; o >>= 1) mx = fmaxf(mx, __shfl_xor(mx, o, 64));
    float e = act ? expf(v - mx) : 0.f;
    float s = e;
    #pragma unroll
    for (int o = 32; o; o >>= 1) s += __shfl_xor(s, o, 64);
    if (act) x[(long)row*Kc + lane] = e / s;
}

// ---------------------------------------------------------------- cluster xyz sums + denom (raw)
__global__ void cluster_xyz_kernel(const float* __restrict__ s, const float* __restrict__ xyz,
                                   float* __restrict__ outx, float* __restrict__ outd,
                                   int N, int Kc, int xBS, int dBS){
    __shared__ float red[256];
    int b = blockIdx.y, k = blockIdx.x, t = threadIdx.x;
    s   += (long)b*N*Kc;
    xyz += (long)b*N*3;
    float a0=0,a1=0,a2=0,ad=0;
    for (int n = t; n < N; n += 256){
        float sv = s[(long)n*Kc + k];
        ad += sv;
        a0 += sv*xyz[n*3+0]; a1 += sv*xyz[n*3+1]; a2 += sv*xyz[n*3+2];
    }
    a0 = blockReduceSum(a0, red, 256);
    a1 = blockReduceSum(a1, red, 256);
    a2 = blockReduceSum(a2, red, 256);
    ad = blockReduceSum(ad, red, 256);
    if (t == 0){
        outx[b*xBS + k*3+0] = a0;
        outx[b*xBS + k*3+1] = a1;
        outx[b*xBS + k*3+2] = a2;
        outd[b*dBS + k] = ad;
    }
}

// ---------------------------------------------------------------- f32 sTX for tiny global stage (split over n)
__global__ __launch_bounds__(256) void gemm_sTX_kernel(const float* __restrict__ s,
                                                       const float* __restrict__ X,
                                                       float* __restrict__ part,
                                                       int N, int Kc, int split,
                                                       long sBS, long xBS){
    __shared__ float sa[32][65], sb[32][65];
    int tid = threadIdx.x, tx = tid & 15, ty = tid >> 4;
    int c0 = blockIdx.x * 64;
    int b = blockIdx.z / split, chunk = blockIdx.z % split;
    int L = N / split, nst = chunk * L;
    s += b*sBS; X += b*xBS;
    float* out = part + (long)blockIdx.z * Kc * 256;
    float acc[4][4] = {};
    for (int nt = nst; nt < nst + L; nt += 32){
        #pragma unroll
        for (int p = 0; p < 8; ++p){
            int idx = p*256 + tid;
            int i = idx & 63, k = idx >> 6;
            sa[k][i] = (i < Kc) ? s[(long)(nt+k)*Kc + i] : 0.f;
            int j = idx & 63, kk = idx >> 6;
            sb[kk][j] = X[(long)(nt+kk)*256 + c0 + j];
        }
        __syncthreads();
        #pragma unroll
        for (int k = 0; k < 32; ++k){
            float a0=sa[k][ty*4+0],a1=sa[k][ty*4+1],a2=sa[k][ty*4+2],a3=sa[k][ty*4+3];
            float b0=sb[k][tx*4+0],b1=sb[k][tx*4+1],b2=sb[k][tx*4+2],b3=sb[k][tx*4+3];
            acc[0][0]+=a0*b0; acc[0][1]+=a0*b1; acc[0][2]+=a0*b2; acc[0][3]+=a0*b3;
            acc[1][0]+=a1*b0; acc[1][1]+=a1*b1; acc[1][2]+=a1*b2; acc[1][3]+=a1*b3;
            acc[2][0]+=a2*b0; acc[2][1]+=a2*b1; acc[2][2]+=a2*b2; acc[2][3]+=a2*b3;
            acc[3][0]+=a3*b0; acc[3][1]+=a3*b1; acc[3][2]+=a3*b2; acc[3][3]+=a3*b3;
        }
        __syncthreads();
    }
    #pragma unroll
    for (int r = 0; r < 4; ++r){
        int kc = ty*4 + r;
        if (kc < Kc){
            #pragma unroll
            for (int c = 0; c < 4; ++c)
                out[(long)kc*256 + c0 + tx*4 + c] = acc[r][c];
        }
    }
}

// ---------------------------------------------------------------- sum partials, divide by denom
__global__ void divide_sum_kernel(const float* __restrict__ part, const float* __restrict__ den,
                                  float* __restrict__ cfea, float* __restrict__ cxyz,
                                  int Kc, int split, int fBS, int xBS, int dBS){
    int b = blockIdx.y, k = blockIdx.x, t = threadIdx.x;
    float d = den[b*dBS + k] + EPSF;
    float s = 0.f;
    for (int q = 0; q < split; ++q)
        s += part[((long)(b*split+q)*Kc + k)*256 + t];
    cfea[(long)b*fBS + k*256 + t] = s / d;
    if (t < 3) cxyz[b*xBS + k*3 + t] /= d;
}

// ---------------------------------------------------------------- level losses: wave per point
__global__ __launch_bounds__(256) void level_loss_kernel(const float* __restrict__ s,
                                                         const float* __restrict__ pxyz,
                                                         const float* __restrict__ cxyz,
                                                         const float* __restrict__ cfea,
                                                         const float* __restrict__ nf,
                                                         float* __restrict__ scal,
                                                         int N, float inv, int ndsSlot){
    __shared__ float cx[192];
    __shared__ float partA[4], partN[4];
    int b = blockIdx.y, t = threadIdx.x, w = t >> 6, l = t & 63;
    s    += (long)b*N*64;
    pxyz += (long)b*N*3;
    nf   += (long)b*N*256;
    cxyz += (long)b*384;
    cfea += (long)b*32768;
    if (t < 192) cx[t] = cxyz[t];
    __syncthreads();
    int n = blockIdx.x*4 + w;
    float sl = s[(long)n*64 + l];
    float px = pxyz[n*3+0], py = pxyz[n*3+1], pz = pxyz[n*3+2];
    float dx = px - cx[l*3+0], dy = py - cx[l*3+1], dz = pz - cx[l*3+2];
    float d2 = dx*dx + dy*dy + dz*dz;
    float assSum = waveSum(sl*d2);
    float dmin = waveMin(d2);
    float c0=0,c1=0,c2=0,c3=0;
    #pragma unroll 8
    for (int k = 0; k < 64; ++k){
        float sk = __shfl(sl, k, 64);
        const float* row = cfea + k*256;
        c0 += sk*row[l]; c1 += sk*row[l+64]; c2 += sk*row[l+128]; c3 += sk*row[l+192];
    }
    float nrm2 = waveSum(c0*c0 + c1*c1 + c2*c2 + c3*c3);
    float inrm = 1.f / fmaxf(sqrtf(nrm2), 1e-12f);
    const float* nfr = nf + (long)n*256;
    float e0 = c0*inrm - nfr[l];
    float e1 = c1*inrm - nfr[l+64];
    float e2 = c2*inrm - nfr[l+128];
    float e3 = c3*inrm - nfr[l+192];
    float nds = waveSum(e0*e0 + e1*e1 + e2*e2 + e3*e3);
    if (l == 0){
        partA[w] = inv*(assSum + 1.f - expf(-0.5f*dmin));
        partN[w] = nds;
    }
    __syncthreads();
    if (t == 0){
        int slot = blockIdx.x & 63;
        atomicAdd(&scal[slot], partA[0]+partA[1]+partA[2]+partA[3]);
        atomicAdd(&scal[ndsSlot*64 + slot], partN[0]+partN[1]+partN[2]+partN[3]);
    }
}

// ---------------------------------------------------------------- knn affinity -> normalized adjacency, fully in LDS
__global__ __launch_bounds__(128) void knn_nac_kernel(const float* __restrict__ cxyz,
                                                      float* __restrict__ nac){
    __shared__ float d2s[128][129];
    __shared__ float x[128][3];
    __shared__ float di[128];
    int b = blockIdx.x, n = threadIdx.x;
    x[n][0] = cxyz[b*384 + n*3+0];
    x[n][1] = cxyz[b*384 + n*3+1];
    x[n][2] = cxyz[b*384 + n*3+2];
    __syncthreads();
    float xn0 = x[n][0], xn1 = x[n][1], xn2 = x[n][2];
    for (int m = 0; m < 128; ++m){
        float dx = xn0-x[m][0], dy = xn1-x[m][1], dz = xn2-x[m][2];
        d2s[n][m] = dx*dx+dy*dy+dz*dz + (m==n ? 1e6f : 0.f);
    }
    float last = -1.f;
    for (int p = 0; p < 8; ++p){
        float cur = 1e30f;
        for (int m = 0; m < 128; ++m){
            float v = d2s[n][m];
            if (v > last && v < cur) cur = v;
        }
        last = cur;
    }
    for (int m = 0; m < 128; ++m){
        float d2 = d2s[n][m];
        d2s[n][m] = (m != n && d2 <= last) ? expf(-d2) : 0.f;
    }
    __syncthreads();
    for (int m = 0; m < 128; ++m){
        float v = fmaxf(d2s[n][m], d2s[m][n]);
        d2s[n][m] = v;
    }
    __syncthreads();
    float deg = 0.f;
    for (int m = 0; m < 128; ++m) deg += d2s[n][m];
    di[n] = rsqrtf(deg + EPSF);
    __syncthreads();
    float* Ab = nac + (long)b*16384;
    for (int c = 0; c < 128; ++c)
        Ab[c*128 + n] = d2s[c][n] * di[c] * di[n];
}

// ---------------------------------------------------------------- Y2 = na_c @ cfea
__global__ void bmm_small_kernel(const float* __restrict__ nac, const float* __restrict__ cfea,
                                 float* __restrict__ Y2){
    __shared__ float row[128];
    int b = blockIdx.y, n = blockIdx.x, t = threadIdx.x;
    if (t < 128) row[t] = nac[(long)b*16384 + n*128 + t];
    __syncthreads();
    float acc = 0.f;
    #pragma unroll 4
    for (int k = 0; k < 128; ++k) acc += row[k]*cfea[(long)b*32768 + k*256 + t];
    Y2[(long)b*32768 + n*256 + t] = acc;
}

// ---------------------------------------------------------------- cut_loss_c
__global__ void cutc_kernel(const float* __restrict__ gs, const float* __restrict__ cxyz,
                            const float* __restrict__ cxyzg, float* __restrict__ scal, float inv){
    __shared__ float cg[48];
    __shared__ float red[128];
    int b = blockIdx.x, t = threadIdx.x;
    if (t < 48) cg[t] = cxyzg[b*48 + t];
    __syncthreads();
    float x0 = cxyz[b*384 + t*3+0], x1 = cxyz[b*384 + t*3+1], x2 = cxyz[b*384 + t*3+2];
    float acc = 0.f;
    #pragma unroll
    for (int k = 0; k < 16; ++k){
        float dx = x0-cg[k*3+0], dy = x1-cg[k*3+1], dz = x2-cg[k*3+2];
        acc += gs[b*2048 + t*16 + k]*(dx*dx+dy*dy+dz*dz);
    }
    acc = blockReduceSum(acc, red, 128);
    if (t == 0) atomicAdd(&scal[b], acc*inv);
}

// ---------------------------------------------------------------- cross attention (M=16) -> AO bf16
__global__ __launch_bounds__(256) void attn_kernel(const float* __restrict__ q,
                                                   const float* __restrict__ kk,
                                                   const float* __restrict__ vv,
                                                   unsigned short* __restrict__ aob){
    __shared__ float Ks[16][256], Vs[16][256];
    int b = blockIdx.y, n = blockIdx.x, t = threadIdx.x;
    #pragma unroll
    for (int p = 0; p < 16; ++p){
        int j = p*256 + t;
        Ks[j>>8][j&255] = kk[b*4096 + j];
        Vs[j>>8][j&255] = vv[b*4096 + j];
    }
    __syncthreads();
    float qv = q[((long)b*1024 + n)*256 + t];
    float sc[16];
    #pragma unroll
    for (int m = 0; m < 16; ++m){
        float v = qv * Ks[m][t];
        #pragma unroll
        for (int o = 32; o; o >>= 1) v += __shfl_xor(v, o, 64);
        sc[m] = v * 0.125f;
    }
    float mx = -1e30f;
    #pragma unroll
    for (int m = 0; m < 16; ++m) mx = fmaxf(mx, sc[m]);
    float sum = 0.f;
    #pragma unroll
    for (int m = 0; m < 16; ++m){ sc[m] = expf(sc[m]-mx); sum += sc[m]; }
    float o = 0.f;
    #pragma unroll
    for (int m = 0; m < 16; ++m) o += sc[m]*Vs[m][t];
    aob[((long)b*1024 + n)*256 + t] = f2bf(o / sum);
}

// ---------------------------------------------------------------- quad: wave per row, bf16 A (N=1024), deg-based
__global__ void quad_kernel(const unsigned short* __restrict__ A, const float* __restrict__ deg,
                            const float* __restrict__ xyz, float* __restrict__ scal){
    __shared__ float part[4];
    int t = threadIdx.x, w = t >> 6, l = t & 63;
    int n = blockIdx.x*4 + w;
    float a0=0,a1=0,a2=0;
    #pragma unroll 4
    for (int i = 0; i < 16; ++i){
        int m = l + i*64;
        float wv = bf2f(A[(long)n*1024 + m])*rsqrtf(deg[m] + EPSF);
        a0 += wv*xyz[m*3+0]; a1 += wv*xyz[m*3+1]; a2 += wv*xyz[m*3+2];
    }
    a0 = waveSum(a0); a1 = waveSum(a1); a2 = waveSum(a2);
    if (l == 0){
        float x0 = xyz[n*3+0], x1 = xyz[n*3+1], x2 = xyz[n*3+2];
        float dn = rsqrtf(deg[n] + EPSF);
        part[w] = (x0*x0+x1*x1+x2*x2) - dn*(x0*a0+x1*a1+x2*a2);
    }
    __syncthreads();
    if (t == 0) atomicAdd(&scal[4*64 + (blockIdx.x & 63)], part[0]+part[1]+part[2]+part[3]);
}

// ---------------------------------------------------------------- g_loss per-row: wave per row
__global__ void gloss_kernel(const float* __restrict__ agg, const float* __restrict__ gfea,
                             float* __restrict__ scal){
    __shared__ float part[4];
    int t = threadIdx.x, w = t >> 6, l = t & 63;
    long r = (long)blockIdx.x*4 + w;
    const float* a = agg + r*256;
    const float* g = gfea + r*256;
    float a0=a[l],a1=a[l+64],a2=a[l+128],a3=a[l+192];
    float g0=g[l],g1=g[l+64],g2=g[l+128],g3=g[l+192];
    float na2 = waveSum(a0*a0+a1*a1+a2*a2+a3*a3);
    float ng2 = waveSum(g0*g0+g1*g1+g2*g2+g3*g3);
    float ia = 1.f/fmaxf(sqrtf(na2), 1e-12f), ig = 1.f/fmaxf(sqrtf(ng2), 1e-12f);
    float e0=a0*ia-g0*ig, e1=a1*ia-g1*ig, e2=a2*ia-g2*ig, e3=a3*ia-g3*ig;
    float d2 = waveSum(e0*e0+e1*e1+e2*e2+e3*e3);
    if (l == 0) part[w] = sqrtf(d2);
    __syncthreads();
    if (t == 0) atomicAdd(&scal[3*64 + (blockIdx.x & 63)], part[0]+part[1]+part[2]+part[3]);
}

// ---------------------------------------------------------------- finalize
__global__ void finalize_kernel(const float* __restrict__ scal, float* __restrict__ out){
    int t = threadIdx.x;
    float s[5];
    #pragma unroll
    for (int q = 0; q < 5; ++q){
        float v = scal[q*64 + t];
        #pragma unroll
        for (int o = 32; o; o >>= 1) v += __shfl_xor(v, o, 64);
        s[q] = v;
    }
    if (t == 0){
        out[524288] = s[0] + sqrtf(s[1]) + sqrtf(s[2]);
        out[524289] = s[3]*0.5f + 1e-4f*s[4]/2048.0f;
    }
}

// ================================================================ launcher
extern "C" void kernel_launch(void* const* d_in, const int* in_sizes, int n_in,
                              void* d_out, int out_size, void* d_ws, size_t ws_size,
                              hipStream_t stream){
    const float* g_fea   = (const float*)d_in[0];
    const float* g_xyz   = (const float*)d_in[1];
    const float* p_fea_0 = (const float*)d_in[2];
    const float* p_xyz_0 = (const float*)d_in[3];
    const float* p_fea_1 = (const float*)d_in[4];
    const float* p_xyz_1 = (const float*)d_in[5];
    const float* lW1 = (const float*)d_in[6];
    const float* lb1 = (const float*)d_in[7];
    const float* lW2 = (const float*)d_in[8];
    const float* lb2 = (const float*)d_in[9];
    const float* gW1 = (const float*)d_in[10];
    const float* gb1 = (const float*)d_in[11];
    const float* gW2 = (const float*)d_in[12];
    const float* gb2 = (const float*)d_in[13];
    const float* Wq = (const float*)d_in[14];
    const float* Wk = (const float*)d_in[15];
    const float* Wv = (const float*)d_in[16];
    const float* Wo = (const float*)d_in[17];
    float* out = (float*)d_out;
    float* ws_f = (float*)d_ws;

    // ---- workspace layout (float units, chained)
    constexpr long O_SCALS = 0;                      // 512 spread slots
    constexpr long O_DEG   = O_SCALS + 512;          // 14336 degree sums (zeroed with scals)
    constexpr long O_CFEA  = 16384;                  // (B,128,256) f32
    constexpr long O_CXYZ  = O_CFEA + 65536;
    constexpr long O_DEN   = O_CXYZ + 768;
    constexpr long O_CFG   = O_DEN  + 256;
    constexpr long O_CXG   = O_CFG  + 8192;
    constexpr long O_DENG  = O_CXG  + 96;
    constexpr long O_PART  = O_DENG + 64;            // 524288 partials
    constexpr long O_NF    = O_PART + 524288;        // f32 (2*4096,256)
    constexpr long O_NFB   = O_NF   + 2097152;       // bf16
    constexpr long O_XST   = O_NFB  + 1048576;       // bf16 (2,256,4096)
    constexpr long O_FEAT  = O_XST  + 1048576;       // bf16 (2,256,4096)
    constexpr long O_YB    = O_FEAT + 1048576;       // bf16 (2,N,256)
    constexpr long O_HB    = O_YB   + 1048576;       // bf16 (2N,128)
    constexpr long O_S     = O_HB   + 524288;        // f32 (2N,64)
    constexpr long O_ST    = O_S    + 524288;        // bf16 (64, 2*4096)
    constexpr long O_PY    = O_ST   + 262144;        // f32 2*(N,256)
    constexpr long O_A     = O_PY   + 2097152;       // bf16 (4096,4096)
    constexpr long O_Q     = O_A    + 8388608;       // f32 (2048,256)
    constexpr long O_GFB   = O_Q    + 524288;        // bf16 g_fea
    constexpr long O_AOB   = O_GFB  + 262144;        // bf16 attn-out
    constexpr long O_KK    = O_AOB  + 262144;
    constexpr long O_VV    = O_KK   + 8192;
    constexpr long O_NAC   = O_VV   + 8192;
    constexpr long O_Y2    = O_NAC  + 32768;
    constexpr long O_H2    = O_Y2   + 65536;
    constexpr long O_LG2   = O_H2   + 32768;
    constexpr long O_W1T   = O_LG2  + 4096;
    constexpr long O_W2T   = O_W1T  + 16384;
    constexpr long O_WQT   = O_W2T  + 4096;
    constexpr long O_WOT   = O_WQT  + 32768;

    hipMemsetAsync(ws_f + O_SCALS, 0, (512 + 14336)*sizeof(float), stream);

    float* nf   = ws_f + O_NF;
    unsigned short* nfb  = (unsigned short*)(ws_f + O_NFB);
    unsigned short* xsT  = (unsigned short*)(ws_f + O_XST);
    unsigned short* feaT = (unsigned short*)(ws_f + O_FEAT);
    unsigned short* Ybb  = (unsigned short*)(ws_f + O_YB);
    unsigned short* Hb   = (unsigned short*)(ws_f + O_HB);
    unsigned short* sTb  = (unsigned short*)(ws_f + O_ST);
    unsigned short* A    = (unsigned short*)(ws_f + O_A);
    unsigned short* gfb  = (unsigned short*)(ws_f + O_GFB);
    unsigned short* aob  = (unsigned short*)(ws_f + O_AOB);
    unsigned short* lW1T = (unsigned short*)(ws_f + O_W1T);
    unsigned short* lW2T = (unsigned short*)(ws_f + O_W2T);
    unsigned short* WqT  = (unsigned short*)(ws_f + O_WQT);
    unsigned short* WoT  = (unsigned short*)(ws_f + O_WOT);
    float* sb   = ws_f + O_S;
    float* degA = ws_f + O_DEG;
    float* PY   = ws_f + O_PY;
    float* part = ws_f + O_PART;
    float* Qf   = ws_f + O_Q;

    // weight conversions
    tcvt_kernel<<<dim3(4, 2), 256, 0, stream>>>(lW1, lW1T, 256, 128);
    tcvt_kernel<<<dim3(2, 1), 256, 0, stream>>>(lW2, lW2T, 128, 64);
    tcvt_kernel<<<dim3(4, 4), 256, 0, stream>>>(Wq, WqT, 256, 256);
    tcvt_kernel<<<dim3(4, 4), 256, 0, stream>>>(Wo, WoT, 256, 256);
    cvt_bf16_kernel<<<512, 256, 0, stream>>>(g_fea, gfb, 131072);

    struct Lvl { const float* fea; const float* xyz; int N; int k0; int ndsSlot; long degBase; };
    Lvl lv[2] = {{p_fea_0, p_xyz_0, 4096, 0, 1, 0}, {p_fea_1, p_xyz_1, 2048, 64, 2, 8192}};

    for (int L = 0; L < 2; ++L){
        int N = lv[L].N;
        const float* fea = lv[L].fea;
        const float* xyz = lv[L].xyz;
        l2norm_kernel<<<2*N, 256, 0, stream>>>(fea, nf, nfb, 2*N);
        for (int b = 0; b < 2; ++b){
            float* degb = degA + lv[L].degBase + (long)b*N;
            gram_mfma_kernel<<<dim3(N/128, N/128), 256, 0, stream>>>(nfb + (long)b*N*256,
                                                                     xyz + (long)b*N*3, A, degb,
                                                                     N, 1.0f, 0.25f);
            transpose_scale_kernel<<<dim3(N/64, 4), 256, 0, stream>>>(fea + (long)b*N*256, degb,
                                                                      feaT + (long)b*256*N,
                                                                      xsT + (long)b*256*N, N);
            ax_mfma_kernel<<<dim3(2, N/128, 2), 256, 0, stream>>>(A, xsT + (long)b*256*N, PY, N);
            combine_kernel<<<N/8, 256, 0, stream>>>(PY, degb, Ybb + (long)b*N*256, N);
        }
        gemm_XW_mfma_kernel<<<dim3(1, 2*N/128), 256, 0, stream>>>(Ybb, lW1T, lb1, nullptr, Hb,
                                                                  2*N, 256, 128, 1);
        gemm_XW_mfma_kernel<<<dim3(1, 2*N/128), 256, 0, stream>>>(Hb, lW2T, lb2, sb, nullptr,
                                                                  2*N, 128, 64, 0);
        softmaxT_kernel<<<2*N/64, 256, 0, stream>>>(sb, sTb, 2*N, 10.0f);
        cluster_xyz_kernel<<<dim3(64, 2), 256, 0, stream>>>(sb, xyz, ws_f + O_CXYZ + lv[L].k0*3,
                                                            ws_f + O_DEN + lv[L].k0, N, 64, 384, 128);
        stx_mfma_kernel<<<32, 256, 0, stream>>>(sTb, feaT, part, N, 16, 2*N);
        divide_sum_kernel<<<dim3(64, 2), 256, 0, stream>>>(part, ws_f + O_DEN + lv[L].k0,
                                                           ws_f + O_CFEA + lv[L].k0*256,
                                                           ws_f + O_CXYZ + lv[L].k0*3,
                                                           64, 16, 128*256, 384, 128);
        level_loss_kernel<<<dim3(N/4, 2), 256, 0, stream>>>(sb, xyz, ws_f + O_CXYZ + lv[L].k0*3,
                                                            ws_f + O_CFEA + lv[L].k0*256, nf,
                                                            ws_f + O_SCALS, N, 1.0f/(2.0f*N), lv[L].ndsSlot);
    }

    // ---- global cluster stage
    knn_nac_kernel<<<2, 128, 0, stream>>>(ws_f + O_CXYZ, ws_f + O_NAC);
    bmm_small_kernel<<<dim3(128, 2), 256, 0, stream>>>(ws_f + O_NAC, ws_f + O_CFEA, ws_f + O_Y2);
    // H2 = relu(Y2 @ gW1 + gb1)  (split-K parallel)
    gemm_splitk_kernel<<<dim3(2, 4, 4), 256, 0, stream>>>(ws_f + O_Y2, gW1, nullptr, part,
                                                          256, 256, 128, 4);
    combine_bias_kernel<<<128, 256, 0, stream>>>(part, gb1, ws_f + O_H2, 256, 128, 4, 1);
    // LG2 = H2 @ gW2 + gb2
    gemm_splitk_kernel<<<dim3(1, 4, 4), 256, 0, stream>>>(ws_f + O_H2, gW2, nullptr, part,
                                                          256, 128, 16, 4);
    combine_bias_kernel<<<16, 256, 0, stream>>>(part, gb2, ws_f + O_LG2, 256, 16, 4, 0);
    softmax_kernel<<<256, 64, 0, stream>>>(ws_f + O_LG2, 16, 0.1f);
    cluster_xyz_kernel<<<dim3(16, 2), 256, 0, stream>>>(ws_f + O_LG2, ws_f + O_CXYZ,
                                                        ws_f + O_CXG, ws_f + O_DENG, 128, 16, 48, 16);
    gemm_sTX_kernel<<<dim3(4, 1, 8), 256, 0, stream>>>(ws_f + O_LG2, ws_f + O_CFEA, part,
                                                       128, 16, 4, 128L*16, 128L*256);
    divide_sum_kernel<<<dim3(16, 2), 256, 0, stream>>>(part, ws_f + O_DENG, ws_f + O_CFG,
                                                       ws_f + O_CXG, 16, 4, 16*256, 48, 16);
    cutc_kernel<<<2, 128, 0, stream>>>(ws_f + O_LG2, ws_f + O_CXYZ, ws_f + O_CXG,
                                       ws_f + O_SCALS, 1.0f/256.0f);

    // ---- cross attention
    gemm_XW_mfma_kernel<<<dim3(2, 16), 256, 0, stream>>>(gfb, WqT, nullptr, Qf, nullptr,
                                                         2048, 256, 256, 0);
    // K,V = cfg @ {Wk,Wv}  fused split-K (64 blocks)
    gemm_splitk_kernel<<<dim3(4, 1, 16), 256, 0, stream>>>(ws_f + O_CFG, Wk, Wv, part,
                                                           32, 256, 256, 8);
    combine_bias_kernel<<<32, 256, 0, stream>>>(part, nullptr, ws_f + O_KK, 32, 256, 8, 0);
    combine_bias_kernel<<<32, 256, 0, stream>>>(part + 8L*32*256, nullptr, ws_f + O_VV, 32, 256, 8, 0);
    attn_kernel<<<dim3(1024, 2), 256, 0, stream>>>(Qf, ws_f + O_KK, ws_f + O_VV, aob);
    gemm_XW_mfma_kernel<<<dim3(2, 16), 256, 0, stream>>>(aob, WoT, nullptr, out, nullptr,
                                                         2048, 256, 256, 0);

    // ---- A_g stage
    l2norm_kernel<<<2048, 256, 0, stream>>>(g_fea, nf, nfb, 2048);
    for (int b = 0; b < 2; ++b){
        float* degb = degA + 12288 + (long)b*1024;
        gram_mfma_kernel<<<dim3(8, 8), 256, 0, stream>>>(nfb + (long)b*1024*256, g_xyz + (long)b*1024*3,
                                                         A, degb, 1024, 16.0f, 0.25f);
        quad_kernel<<<256, 256, 0, stream>>>(A, degb, g_xyz + (long)b*1024*3, ws_f + O_SCALS);
    }

    gloss_kernel<<<512, 256, 0, stream>>>(out, g_fea, ws_f + O_SCALS);
    finalize_kernel<<<1, 64, 0, stream>>>(ws_f + O_SCALS, out);
}

// Round 6
// 770.045 us; speedup vs baseline: 3.0808x; 1.0167x over previous
//
#include <hip/hip_runtime.h>

#define EPSF 1e-4f

typedef __attribute__((ext_vector_type(8))) short bf16x8;
typedef __attribute__((ext_vector_type(4))) float f32x4;

__device__ __forceinline__ unsigned short f2bf(float f){
    unsigned int u = __float_as_uint(f);
    return (unsigned short)((u + 0x7FFF + ((u >> 16) & 1)) >> 16);
}
__device__ __forceinline__ float bf2f(unsigned short u){
    return __uint_as_float(((unsigned int)u) << 16);
}
__device__ __forceinline__ float waveSum(float v){
    #pragma unroll
    for (int o = 32; o; o >>= 1) v += __shfl_xor(v, o, 64);
    return v;
}
__device__ __forceinline__ float waveMin(float v){
    #pragma unroll
    for (int o = 32; o; o >>= 1) v = fminf(v, __shfl_xor(v, o, 64));
    return v;
}
__device__ __forceinline__ float waveMax(float v){
    #pragma unroll
    for (int o = 32; o; o >>= 1) v = fmaxf(v, __shfl_xor(v, o, 64));
    return v;
}
__device__ __forceinline__ float blockReduceSum(float v, float* red, int nthr){
    int t = threadIdx.x;
    red[t] = v; __syncthreads();
    for (int s = nthr >> 1; s > 0; s >>= 1){
        if (t < s) red[t] += red[t + s];
        __syncthreads();
    }
    float r = red[0]; __syncthreads();
    return r;
}

// ---------------------------------------------------------------- l2norm rows of 256 -> bf16
__global__ void l2norm_kernel(const float* __restrict__ x, unsigned short* __restrict__ outb, int rows){
    __shared__ float red[256];
    int row = blockIdx.x, t = threadIdx.x;
    float v = x[(long)row*256 + t];
    float s = blockReduceSum(v*v, red, 256);
    float nrm = fmaxf(sqrtf(s), 1e-12f);
    outb[(long)row*256 + t] = f2bf(v / nrm);
}

// ---------------------------------------------------------------- flat f32 -> bf16
__global__ void cvt_bf16_kernel(const float* __restrict__ in, unsigned short* __restrict__ out, long n4){
    long i = (long)blockIdx.x*256 + threadIdx.x;
    if (i < n4){
        float4 v = ((const float4*)in)[i];
        unsigned int lo = f2bf(v.x) | ((unsigned int)f2bf(v.y) << 16);
        unsigned int hi = f2bf(v.z) | ((unsigned int)f2bf(v.w) << 16);
        uint2 u; u.x = lo; u.y = hi;
        ((uint2*)out)[i] = u;
    }
}

// ---------------------------------------------------------------- transpose+cvt weight: W(Rw,Cw) -> WT(Cw,Rw) bf16
__global__ void tcvt_kernel(const float* __restrict__ W, unsigned short* __restrict__ WT,
                            int Rw, int Cw){
    __shared__ float tile[64][65];
    int r0 = blockIdx.x*64, c0 = blockIdx.y*64;
    int t = threadIdx.x;
    for (int idx = t; idx < 4096; idx += 256){
        int rr = idx >> 6, cc = idx & 63;
        tile[rr][cc] = (r0+rr < Rw && c0+cc < Cw) ? W[(long)(r0+rr)*Cw + c0+cc] : 0.f;
    }
    __syncthreads();
    for (int idx = t; idx < 4096; idx += 256){
        int cc = idx >> 6, rr = idx & 63;
        if (r0+rr < Rw && c0+cc < Cw)
            WT[(long)(c0+cc)*Rw + r0+rr] = f2bf(tile[rr][cc]);
    }
}

// ---------------------------------------------------------------- MFMA gram: A = exp(scale*(2dot-2)) * mask, bf16 out
// also accumulates row degree sums into deg via atomics (deg pre-zeroed)
__global__ __launch_bounds__(256) void gram_mfma_kernel(const unsigned short* __restrict__ nf,
                                                        const float* __restrict__ xyz,
                                                        unsigned short* __restrict__ A,
                                                        float* __restrict__ deg,
                                                        int N, float r2, float scale){
    __shared__ short tA[128*32], tB[128*32];
    __shared__ float xa[384], xb[384];
    int tid = threadIdx.x;
    int n0 = blockIdx.y*128, m0 = blockIdx.x*128;
    for (int i = tid; i < 384; i += 256){ xa[i] = xyz[n0*3 + i]; xb[i] = xyz[m0*3 + i]; }
    int w = tid >> 6, l = tid & 63;
    int wy = w >> 1, wx = w & 1;
    int lg = l >> 4, lr = l & 15;
    int srow = tid >> 2, sc = tid & 3;
    f32x4 zero = {0.f, 0.f, 0.f, 0.f};
    f32x4 acc[4][4];
    #pragma unroll
    for (int i = 0; i < 4; ++i)
        #pragma unroll
        for (int j = 0; j < 4; ++j) acc[i][j] = zero;
    for (int kt = 0; kt < 256; kt += 32){
        __syncthreads();
        #pragma unroll
        for (int p = 0; p < 2; ++p){
            int row = srow + p*64;
            uint4 va = *(const uint4*)(nf + (long)(n0+row)*256 + kt + sc*8);
            uint4 vb = *(const uint4*)(nf + (long)(m0+row)*256 + kt + sc*8);
            *(uint4*)(tA + row*32 + sc*8) = va;
            *(uint4*)(tB + row*32 + sc*8) = vb;
        }
        __syncthreads();
        bf16x8 af[4], bfr[4];
        #pragma unroll
        for (int f = 0; f < 4; ++f){
            af[f]  = *(const bf16x8*)(tA + (wy*64 + f*16 + lr)*32 + lg*8);
            bfr[f] = *(const bf16x8*)(tB + (wx*64 + f*16 + lr)*32 + lg*8);
        }
        #pragma unroll
        for (int i = 0; i < 4; ++i)
            #pragma unroll
            for (int j = 0; j < 4; ++j)
                acc[i][j] = __builtin_amdgcn_mfma_f32_16x16x32_bf16(af[i], bfr[j], acc[i][j], 0, 0, 0);
    }
    #pragma unroll
    for (int fi = 0; fi < 4; ++fi){
        #pragma unroll
        for (int r = 0; r < 4; ++r){
            int n_ = wy*64 + fi*16 + lg*4 + r;
            int gn = n0 + n_;
            float rowacc = 0.f;
            #pragma unroll
            for (int fj = 0; fj < 4; ++fj){
                int m_ = wx*64 + fj*16 + lr;
                float dx = xa[n_*3+0]-xb[m_*3+0];
                float dy = xa[n_*3+1]-xb[m_*3+1];
                float dz = xa[n_*3+2]-xb[m_*3+2];
                float d2x = dx*dx + dy*dy + dz*dz;
                int gm = m0 + m_;
                float dot = acc[fi][fj][r];
                float val = (d2x < r2 && gn != gm) ? expf(scale*(2.f*dot - 2.f)) : 0.f;
                A[(long)gn*N + gm] = f2bf(val);
                rowacc += val;
            }
            rowacc += __shfl_xor(rowacc, 1, 64);
            rowacc += __shfl_xor(rowacc, 2, 64);
            rowacc += __shfl_xor(rowacc, 4, 64);
            rowacc += __shfl_xor(rowacc, 8, 64);
            if (lr == 0) atomicAdd(&deg[gn], rowacc);
        }
    }
}

// ---------------------------------------------------------------- feaT[c][m] = fea[m][c] (raw) ; xsT[c][m] = fea[m][c]*rsqrt(deg[m]+eps)
__global__ __launch_bounds__(256) void transpose_scale_kernel(const float* __restrict__ fea,
                                                              const float* __restrict__ deg,
                                                              unsigned short* __restrict__ feaT,
                                                              unsigned short* __restrict__ xsT, int N){
    __shared__ float tile[64][65];
    __shared__ float dl[64];
    int m0 = blockIdx.x*64, c0 = blockIdx.y*64;
    int t = threadIdx.x;
    int lr = t >> 2, lc = (t & 3)*16;
    #pragma unroll
    for (int j = 0; j < 4; ++j){
        float4 v = *(const float4*)(fea + (long)(m0+lr)*256 + c0 + lc + j*4);
        tile[lr][lc+j*4+0] = v.x; tile[lr][lc+j*4+1] = v.y;
        tile[lr][lc+j*4+2] = v.z; tile[lr][lc+j*4+3] = v.w;
    }
    if (t < 64) dl[t] = rsqrtf(deg[m0+t] + EPSF);
    __syncthreads();
    unsigned short vr[16] __attribute__((aligned(16)));
    unsigned short vs[16] __attribute__((aligned(16)));
    #pragma unroll
    for (int j = 0; j < 16; ++j){
        float raw = tile[lc+j][lr];
        vr[j] = f2bf(raw);
        vs[j] = f2bf(raw * dl[lc+j]);
    }
    long off = (long)(c0+lr)*N + m0 + lc;
    *(uint4*)(feaT + off)     = *(uint4*)&vr[0];
    *(uint4*)(feaT + off + 8) = *(uint4*)&vr[8];
    *(uint4*)(xsT + off)      = *(uint4*)&vs[0];
    *(uint4*)(xsT + off + 8)  = *(uint4*)&vs[8];
}

// ---------------------------------------------------------------- MFMA A@XsT^T -> PY partials (split-K, register dbuf prefetch)
__global__ __launch_bounds__(256) void ax_mfma_kernel(const unsigned short* __restrict__ A,
                                                      const unsigned short* __restrict__ xsT,
                                                      float* __restrict__ PY, int N, int split){
    __shared__ short tA[128*32], tB[128*32];
    int tid = threadIdx.x;
    int c0 = blockIdx.x*128, n0 = blockIdx.y*128;
    int chunk = blockIdx.z;
    int L = N/split, kbase = chunk*L, kend = kbase + L;
    int w = tid >> 6, l = tid & 63;
    int wy = w >> 1, wx = w & 1;
    int lg = l >> 4, lr = l & 15;
    int srow = tid >> 2, sc = tid & 3;
    f32x4 zero = {0.f, 0.f, 0.f, 0.f};
    f32x4 acc[4][4];
    #pragma unroll
    for (int i = 0; i < 4; ++i)
        #pragma unroll
        for (int j = 0; j < 4; ++j) acc[i][j] = zero;
    uint4 pva[2], pvb[2];
    #pragma unroll
    for (int p = 0; p < 2; ++p){
        int row = srow + p*64;
        pva[p] = *(const uint4*)(A   + (long)(n0+row)*N + kbase + sc*8);
        pvb[p] = *(const uint4*)(xsT + (long)(c0+row)*N + kbase + sc*8);
    }
    for (int kt = kbase; kt < kend; kt += 32){
        __syncthreads();
        #pragma unroll
        for (int p = 0; p < 2; ++p){
            int row = srow + p*64;
            *(uint4*)(tA + row*32 + sc*8) = pva[p];
            *(uint4*)(tB + row*32 + sc*8) = pvb[p];
        }
        __syncthreads();
        if (kt + 32 < kend){
            #pragma unroll
            for (int p = 0; p < 2; ++p){
                int row = srow + p*64;
                pva[p] = *(const uint4*)(A   + (long)(n0+row)*N + kt + 32 + sc*8);
                pvb[p] = *(const uint4*)(xsT + (long)(c0+row)*N + kt + 32 + sc*8);
            }
        }
        bf16x8 af[4], bfr[4];
        #pragma unroll
        for (int f = 0; f < 4; ++f){
            af[f]  = *(const bf16x8*)(tA + (wy*64 + f*16 + lr)*32 + lg*8);
            bfr[f] = *(const bf16x8*)(tB + (wx*64 + f*16 + lr)*32 + lg*8);
        }
        #pragma unroll
        for (int i = 0; i < 4; ++i)
            #pragma unroll
            for (int j = 0; j < 4; ++j)
                acc[i][j] = __builtin_amdgcn_mfma_f32_16x16x32_bf16(af[i], bfr[j], acc[i][j], 0, 0, 0);
    }
    float* out = PY + (long)chunk*N*256;
    #pragma unroll
    for (int fi = 0; fi < 4; ++fi){
        #pragma unroll
        for (int fj = 0; fj < 4; ++fj){
            #pragma unroll
            for (int r = 0; r < 4; ++r){
                int n_ = n0 + wy*64 + fi*16 + lg*4 + r;
                int c_ = c0 + wx*64 + fj*16 + lr;
                out[(long)n_*256 + c_] = acc[fi][fj][r];
            }
        }
    }
}

// ---------------------------------------------------------------- Yb(bf16) = rsqrt(deg[n])*sum_split(PY)
__global__ void combine_kernel(const float* __restrict__ PY, const float* __restrict__ deg,
                               unsigned short* __restrict__ Yb, int N, int split){
    long i = (long)blockIdx.x*256 + threadIdx.x;  // 8 elems per thread
    long e = i*8;
    float4 s0 = {0,0,0,0}, s1 = {0,0,0,0};
    for (int q = 0; q < split; ++q){
        const float4* p = (const float4*)(PY + (long)q*N*256 + e);
        float4 a = p[0], b = p[1];
        s0.x += a.x; s0.y += a.y; s0.z += a.z; s0.w += a.w;
        s1.x += b.x; s1.y += b.y; s1.z += b.z; s1.w += b.w;
    }
    float d = rsqrtf(deg[e >> 8] + EPSF);
    unsigned short vb[8] __attribute__((aligned(16)));
    vb[0] = f2bf(s0.x*d); vb[1] = f2bf(s0.y*d);
    vb[2] = f2bf(s0.z*d); vb[3] = f2bf(s0.w*d);
    vb[4] = f2bf(s1.x*d); vb[5] = f2bf(s1.y*d);
    vb[6] = f2bf(s1.z*d); vb[7] = f2bf(s1.w*d);
    *(uint4*)(Yb + e) = *(uint4*)vb;
}

// ---------------------------------------------------------------- MFMA X(R,Ci)bf16 @ WT(Co,Ci)bf16 + bias [relu] -> f32/bf16 (prefetch)
__global__ __launch_bounds__(256) void gemm_XW_mfma_kernel(const unsigned short* __restrict__ X,
                                                           const unsigned short* __restrict__ WT,
                                                           const float* __restrict__ bias,
                                                           float* __restrict__ outF,
                                                           unsigned short* __restrict__ outB,
                                                           int R, int Ci, int Co, int relu){
    __shared__ short tA[128*32], tB[128*32];
    int tid = threadIdx.x;
    int c0 = blockIdx.x*128, r0 = blockIdx.y*128;
    int w = tid >> 6, l = tid & 63;
    int wy = w >> 1, wx = w & 1;
    int lg = l >> 4, lr = l & 15;
    int srow = tid >> 2, sc = tid & 3;
    f32x4 zero = {0.f, 0.f, 0.f, 0.f};
    f32x4 acc[4][4];
    #pragma unroll
    for (int i = 0; i < 4; ++i)
        #pragma unroll
        for (int j = 0; j < 4; ++j) acc[i][j] = zero;
    uint4 pva[2], pvb[2];
    #pragma unroll
    for (int p = 0; p < 2; ++p){
        int row = srow + p*64;
        int ar = r0 + row, br = c0 + row;
        pva[p] = (ar < R)  ? *(const uint4*)(X  + (long)ar*Ci + sc*8) : (uint4){0,0,0,0};
        pvb[p] = (br < Co) ? *(const uint4*)(WT + (long)br*Ci + sc*8) : (uint4){0,0,0,0};
    }
    for (int kt = 0; kt < Ci; kt += 32){
        __syncthreads();
        #pragma unroll
        for (int p = 0; p < 2; ++p){
            int row = srow + p*64;
            *(uint4*)(tA + row*32 + sc*8) = pva[p];
            *(uint4*)(tB + row*32 + sc*8) = pvb[p];
        }
        __syncthreads();
        if (kt + 32 < Ci){
            #pragma unroll
            for (int p = 0; p < 2; ++p){
                int row = srow + p*64;
                int ar = r0 + row, br = c0 + row;
                pva[p] = (ar < R)  ? *(const uint4*)(X  + (long)ar*Ci + kt + 32 + sc*8) : (uint4){0,0,0,0};
                pvb[p] = (br < Co) ? *(const uint4*)(WT + (long)br*Ci + kt + 32 + sc*8) : (uint4){0,0,0,0};
            }
        }
        bf16x8 af[4], bfr[4];
        #pragma unroll
        for (int f = 0; f < 4; ++f){
            af[f]  = *(const bf16x8*)(tA + (wy*64 + f*16 + lr)*32 + lg*8);
            bfr[f] = *(const bf16x8*)(tB + (wx*64 + f*16 + lr)*32 + lg*8);
        }
        #pragma unroll
        for (int i = 0; i < 4; ++i)
            #pragma unroll
            for (int j = 0; j < 4; ++j)
                acc[i][j] = __builtin_amdgcn_mfma_f32_16x16x32_bf16(af[i], bfr[j], acc[i][j], 0, 0, 0);
    }
    #pragma unroll
    for (int fi = 0; fi < 4; ++fi){
        #pragma unroll
        for (int fj = 0; fj < 4; ++fj){
            #pragma unroll
            for (int r = 0; r < 4; ++r){
                int rr = r0 + wy*64 + fi*16 + lg*4 + r;
                int cc = c0 + wx*64 + fj*16 + lr;
                if (rr < R && cc < Co){
                    float v = acc[fi][fj][r] + (bias ? bias[cc] : 0.f);
                    if (relu) v = fmaxf(v, 0.f);
                    if (outF) outF[(long)rr*Co + cc] = v;
                    if (outB) outB[(long)rr*Co + cc] = f2bf(v);
                }
            }
        }
    }
}

// ---------------------------------------------------------------- split-K f32 GEMM -> partials
__global__ __launch_bounds__(256) void gemm_splitk_kernel(const float* __restrict__ X,
                                                          const float* __restrict__ W0,
                                                          const float* __restrict__ W1,
                                                          float* __restrict__ part,
                                                          int R, int Ci, int Co, int Ks){
    __shared__ float sa[32][65], sb[32][65];
    int tid = threadIdx.x, tx = tid & 15, ty = tid >> 4;
    int c0 = blockIdx.x * 64, r0 = blockIdx.y * 64;
    int z = blockIdx.z;
    const float* W = (z / Ks) ? W1 : W0;
    int kchunk = Ci / Ks, kst = (z % Ks) * kchunk;
    float acc[4][4] = {};
    for (int kt = kst; kt < kst + kchunk; kt += 32){
        #pragma unroll
        for (int p = 0; p < 8; ++p){
            int idx = p*256 + tid;
            int k = idx & 31, i = idx >> 5;
            int rr = r0 + i;
            sa[k][i] = (rr < R) ? X[(long)rr*Ci + kt + k] : 0.f;
            int j = idx & 63, kk = idx >> 6;
            int cc = c0 + j;
            sb[kk][j] = (cc < Co) ? W[(long)(kt+kk)*Co + cc] : 0.f;
        }
        __syncthreads();
        #pragma unroll
        for (int k = 0; k < 32; ++k){
            float a0=sa[k][ty*4+0],a1=sa[k][ty*4+1],a2=sa[k][ty*4+2],a3=sa[k][ty*4+3];
            float b0=sb[k][tx*4+0],b1=sb[k][tx*4+1],b2=sb[k][tx*4+2],b3=sb[k][tx*4+3];
            acc[0][0]+=a0*b0; acc[0][1]+=a0*b1; acc[0][2]+=a0*b2; acc[0][3]+=a0*b3;
            acc[1][0]+=a1*b0; acc[1][1]+=a1*b1; acc[1][2]+=a1*b2; acc[1][3]+=a1*b3;
            acc[2][0]+=a2*b0; acc[2][1]+=a2*b1; acc[2][2]+=a2*b2; acc[2][3]+=a2*b3;
            acc[3][0]+=a3*b0; acc[3][1]+=a3*b1; acc[3][2]+=a3*b2; acc[3][3]+=a3*b3;
        }
        __syncthreads();
    }
    float* outp = part + (long)z*R*Co;
    #pragma unroll
    for (int r = 0; r < 4; ++r){
        #pragma unroll
        for (int c = 0; c < 4; ++c){
            int rr = r0 + ty*4 + r, cc = c0 + tx*4 + c;
            if (rr < R && cc < Co) outp[(long)rr*Co + cc] = acc[r][c];
        }
    }
}

// ---------------------------------------------------------------- sum split-K partials + bias [+relu]
__global__ void combine_bias_kernel(const float* __restrict__ part, const float* __restrict__ bias,
                                    float* __restrict__ out, int R, int Co, int Ks, int relu){
    long i = (long)blockIdx.x*256 + threadIdx.x;
    if (i < (long)R*Co){
        long zs = (long)R*Co;
        float s = 0.f;
        for (int q = 0; q < Ks; ++q) s += part[q*zs + i];
        float v = s + (bias ? bias[i % Co] : 0.f);
        if (relu) v = fmaxf(v, 0.f);
        out[i] = v;
    }
}

// ---------------------------------------------------------------- softmax rows of 64 (in place, f32) + sT bf16
__global__ __launch_bounds__(256) void softmaxT_kernel(float* __restrict__ s,
                                                       unsigned short* __restrict__ sT,
                                                       int sStride, float invtau){
    __shared__ unsigned short st[64][65];
    int blk = blockIdx.x, t = threadIdx.x, w = t >> 6, l = t & 63;
    #pragma unroll
    for (int i = 0; i < 16; ++i){
        int rloc = w + 4*i;
        long row = (long)blk*64 + rloc;
        float v = s[row*64 + l] * invtau;
        float mx = waveMax(v);
        float e = expf(v - mx);
        float sum = waveSum(e);
        float p = e / sum;
        s[row*64 + l] = p;
        st[l][rloc] = f2bf(p);
    }
    __syncthreads();
    int k = t >> 2, j = (t & 3)*16;
    unsigned short vbuf[16] __attribute__((aligned(16)));
    #pragma unroll
    for (int q = 0; q < 16; ++q) vbuf[q] = st[k][j+q];
    long off = (long)k*sStride + (long)blk*64 + j;
    *(uint4*)(sT + off)     = *(uint4*)&vbuf[0];
    *(uint4*)(sT + off + 8) = *(uint4*)&vbuf[8];
}

// ---------------------------------------------------------------- MFMA sT(64,2N) @ feaT(256,N)^T -> part per (b,chunk)
__global__ __launch_bounds__(256) void stx_mfma_kernel(const unsigned short* __restrict__ sT,
                                                       const unsigned short* __restrict__ feaT,
                                                       float* __restrict__ part,
                                                       int N, int split, int sStride){
    __shared__ short tA[64*32], tB[256*32];
    int tid = threadIdx.x;
    int z = blockIdx.x, b = z / split, chunk = z % split;
    int L = N / split, kst = chunk * L;
    const unsigned short* sTb = sT + (long)b*N;
    const unsigned short* fT  = feaT + (long)b*256*N;
    int w = tid >> 6, l = tid & 63;
    int lg = l >> 4, lr = l & 15;
    f32x4 zero = {0.f, 0.f, 0.f, 0.f};
    f32x4 acc[4][4];
    #pragma unroll
    for (int i = 0; i < 4; ++i)
        #pragma unroll
        for (int j = 0; j < 4; ++j) acc[i][j] = zero;
    int srow = tid >> 2, koff = (tid & 3)*8;
    for (int kt = kst; kt < kst + L; kt += 32){
        __syncthreads();
        *(uint4*)(tA + srow*32 + koff) = *(const uint4*)(sTb + (long)srow*sStride + kt + koff);
        #pragma unroll
        for (int p = 0; p < 4; ++p){
            int row = srow + p*64;
            *(uint4*)(tB + row*32 + koff) = *(const uint4*)(fT + (long)row*N + kt + koff);
        }
        __syncthreads();
        bf16x8 af[4], bfr[4];
        #pragma unroll
        for (int f = 0; f < 4; ++f){
            af[f]  = *(const bf16x8*)(tA + (f*16 + lr)*32 + lg*8);
            bfr[f] = *(const bf16x8*)(tB + (w*64 + f*16 + lr)*32 + lg*8);
        }
        #pragma unroll
        for (int i = 0; i < 4; ++i)
            #pragma unroll
            for (int j = 0; j < 4; ++j)
                acc[i][j] = __builtin_amdgcn_mfma_f32_16x16x32_bf16(af[i], bfr[j], acc[i][j], 0, 0, 0);
    }
    float* outp = part + (long)z*64*256;
    #pragma unroll
    for (int fi = 0; fi < 4; ++fi){
        #pragma unroll
        for (int fj = 0; fj < 4; ++fj){
            #pragma unroll
            for (int r = 0; r < 4; ++r){
                int kc = fi*16 + lg*4 + r;
                int cc = w*64 + fj*16 + lr;
                outp[(long)kc*256 + cc] = acc[fi][fj][r];
            }
        }
    }
}

// ---------------------------------------------------------------- row softmax (K<=64), in place
__global__ void softmax_kernel(float* __restrict__ x, int Kc, float tau){
    int row = blockIdx.x, lane = threadIdx.x;
    bool act = lane < Kc;
    float v = act ? x[(long)row*Kc + lane] / tau : -1e30f;
    float mx = v;
    #pragma unroll
    for (int o = 32; o; o >>= 1) mx = fmaxf(mx, __shfl_xor(mx, o, 64));
    float e = act ? expf(v - mx) : 0.f;
    float s = e;
    #pragma unroll
    for (int o = 32; o; o >>= 1) s += __shfl_xor(s, o, 64);
    if (act) x[(long)row*Kc + lane] = e / s;
}

// ---------------------------------------------------------------- cluster xyz sums + denom (raw)
__global__ void cluster_xyz_kernel(const float* __restrict__ s, const float* __restrict__ xyz,
                                   float* __restrict__ outx, float* __restrict__ outd,
                                   int N, int Kc, int xBS, int dBS){
    __shared__ float red[256];
    int b = blockIdx.y, k = blockIdx.x, t = threadIdx.x;
    s   += (long)b*N*Kc;
    xyz += (long)b*N*3;
    float a0=0,a1=0,a2=0,ad=0;
    for (int n = t; n < N; n += 256){
        float sv = s[(long)n*Kc + k];
        ad += sv;
        a0 += sv*xyz[n*3+0]; a1 += sv*xyz[n*3+1]; a2 += sv*xyz[n*3+2];
    }
    a0 = blockReduceSum(a0, red, 256);
    a1 = blockReduceSum(a1, red, 256);
    a2 = blockReduceSum(a2, red, 256);
    ad = blockReduceSum(ad, red, 256);
    if (t == 0){
        outx[b*xBS + k*3+0] = a0;
        outx[b*xBS + k*3+1] = a1;
        outx[b*xBS + k*3+2] = a2;
        outd[b*dBS + k] = ad;
    }
}

// ---------------------------------------------------------------- f32 sTX for tiny global stage (split over n)
__global__ __launch_bounds__(256) void gemm_sTX_kernel(const float* __restrict__ s,
                                                       const float* __restrict__ X,
                                                       float* __restrict__ part,
                                                       int N, int Kc, int split,
                                                       long sBS, long xBS){
    __shared__ float sa[32][65], sb[32][65];
    int tid = threadIdx.x, tx = tid & 15, ty = tid >> 4;
    int c0 = blockIdx.x * 64;
    int b = blockIdx.z / split, chunk = blockIdx.z % split;
    int L = N / split, nst = chunk * L;
    s += b*sBS; X += b*xBS;
    float* out = part + (long)blockIdx.z * Kc * 256;
    float acc[4][4] = {};
    for (int nt = nst; nt < nst + L; nt += 32){
        #pragma unroll
        for (int p = 0; p < 8; ++p){
            int idx = p*256 + tid;
            int i = idx & 63, k = idx >> 6;
            sa[k][i] = (i < Kc) ? s[(long)(nt+k)*Kc + i] : 0.f;
            int j = idx & 63, kk = idx >> 6;
            sb[kk][j] = X[(long)(nt+kk)*256 + c0 + j];
        }
        __syncthreads();
        #pragma unroll
        for (int k = 0; k < 32; ++k){
            float a0=sa[k][ty*4+0],a1=sa[k][ty*4+1],a2=sa[k][ty*4+2],a3=sa[k][ty*4+3];
            float b0=sb[k][tx*4+0],b1=sb[k][tx*4+1],b2=sb[k][tx*4+2],b3=sb[k][tx*4+3];
            acc[0][0]+=a0*b0; acc[0][1]+=a0*b1; acc[0][2]+=a0*b2; acc[0][3]+=a0*b3;
            acc[1][0]+=a1*b0; acc[1][1]+=a1*b1; acc[1][2]+=a1*b2; acc[1][3]+=a1*b3;
            acc[2][0]+=a2*b0; acc[2][1]+=a2*b1; acc[2][2]+=a2*b2; acc[2][3]+=a2*b3;
            acc[3][0]+=a3*b0; acc[3][1]+=a3*b1; acc[3][2]+=a3*b2; acc[3][3]+=a3*b3;
        }
        __syncthreads();
    }
    #pragma unroll
    for (int r = 0; r < 4; ++r){
        int kc = ty*4 + r;
        if (kc < Kc){
            #pragma unroll
            for (int c = 0; c < 4; ++c)
                out[(long)kc*256 + c0 + tx*4 + c] = acc[r][c];
        }
    }
}

// ---------------------------------------------------------------- sum partials, divide by denom
__global__ void divide_sum_kernel(const float* __restrict__ part, const float* __restrict__ den,
                                  float* __restrict__ cfea, float* __restrict__ cxyz,
                                  int Kc, int split, int fBS, int xBS, int dBS){
    int b = blockIdx.y, k = blockIdx.x, t = threadIdx.x;
    float d = den[b*dBS + k] + EPSF;
    float s = 0.f;
    for (int q = 0; q < split; ++q)
        s += part[((long)(b*split+q)*Kc + k)*256 + t];
    cfea[(long)b*fBS + k*256 + t] = s / d;
    if (t < 3) cxyz[b*xBS + k*3 + t] /= d;
}

// ---------------------------------------------------------------- level losses: wave per point, cfea staged in LDS
__global__ __launch_bounds__(256) void level_loss_kernel(const float* __restrict__ s,
                                                         const float* __restrict__ pxyz,
                                                         const float* __restrict__ cxyz,
                                                         const float* __restrict__ cfea,
                                                         const unsigned short* __restrict__ nfb,
                                                         float* __restrict__ scal,
                                                         int N, float inv, int ndsSlot){
    __shared__ float cf[64*256];
    __shared__ float cx[192];
    __shared__ float partA[4], partN[4];
    int b = blockIdx.y, t = threadIdx.x, w = t >> 6, l = t & 63;
    s    += (long)b*N*64;
    pxyz += (long)b*N*3;
    nfb  += (long)b*N*256;
    cxyz += (long)b*384;
    cfea += (long)b*32768;
    for (int i = t; i < 4096; i += 256)
        ((float4*)cf)[i] = ((const float4*)cfea)[i];
    if (t < 192) cx[t] = cxyz[t];
    __syncthreads();
    int n = blockIdx.x*4 + w;
    float sl = s[(long)n*64 + l];
    float px = pxyz[n*3+0], py = pxyz[n*3+1], pz = pxyz[n*3+2];
    float dx = px - cx[l*3+0], dy = py - cx[l*3+1], dz = pz - cx[l*3+2];
    float d2 = dx*dx + dy*dy + dz*dz;
    float assSum = waveSum(sl*d2);
    float dmin = waveMin(d2);
    float c0=0,c1=0,c2=0,c3=0;
    #pragma unroll 8
    for (int k = 0; k < 64; ++k){
        float sk = __shfl(sl, k, 64);
        const float* row = cf + k*256;
        c0 += sk*row[l]; c1 += sk*row[l+64]; c2 += sk*row[l+128]; c3 += sk*row[l+192];
    }
    float nrm2 = waveSum(c0*c0 + c1*c1 + c2*c2 + c3*c3);
    float inrm = 1.f / fmaxf(sqrtf(nrm2), 1e-12f);
    const unsigned short* nfr = nfb + (long)n*256;
    float e0 = c0*inrm - bf2f(nfr[l]);
    float e1 = c1*inrm - bf2f(nfr[l+64]);
    float e2 = c2*inrm - bf2f(nfr[l+128]);
    float e3 = c3*inrm - bf2f(nfr[l+192]);
    float nds = waveSum(e0*e0 + e1*e1 + e2*e2 + e3*e3);
    if (l == 0){
        partA[w] = inv*(assSum + 1.f - expf(-0.5f*dmin));
        partN[w] = nds;
    }
    __syncthreads();
    if (t == 0){
        int slot = blockIdx.x & 63;
        atomicAdd(&scal[slot], partA[0]+partA[1]+partA[2]+partA[3]);
        atomicAdd(&scal[ndsSlot*64 + slot], partN[0]+partN[1]+partN[2]+partN[3]);
    }
}

// ---------------------------------------------------------------- knn affinity -> normalized adjacency, fully in LDS
__global__ __launch_bounds__(128) void knn_nac_kernel(const float* __restrict__ cxyz,
                                                      float* __restrict__ nac){
    __shared__ float d2s[128][129];
    __shared__ float x[128][3];
    __shared__ float di[128];
    int b = blockIdx.x, n = threadIdx.x;
    x[n][0] = cxyz[b*384 + n*3+0];
    x[n][1] = cxyz[b*384 + n*3+1];
    x[n][2] = cxyz[b*384 + n*3+2];
    __syncthreads();
    float xn0 = x[n][0], xn1 = x[n][1], xn2 = x[n][2];
    for (int m = 0; m < 128; ++m){
        float dx = xn0-x[m][0], dy = xn1-x[m][1], dz = xn2-x[m][2];
        d2s[n][m] = dx*dx+dy*dy+dz*dz + (m==n ? 1e6f : 0.f);
    }
    float last = -1.f;
    for (int p = 0; p < 8; ++p){
        float cur = 1e30f;
        for (int m = 0; m < 128; ++m){
            float v = d2s[n][m];
            if (v > last && v < cur) cur = v;
        }
        last = cur;
    }
    for (int m = 0; m < 128; ++m){
        float d2 = d2s[n][m];
        d2s[n][m] = (m != n && d2 <= last) ? expf(-d2) : 0.f;
    }
    __syncthreads();
    for (int m = 0; m < 128; ++m){
        float v = fmaxf(d2s[n][m], d2s[m][n]);
        d2s[n][m] = v;
    }
    __syncthreads();
    float deg = 0.f;
    for (int m = 0; m < 128; ++m) deg += d2s[n][m];
    di[n] = rsqrtf(deg + EPSF);
    __syncthreads();
    float* Ab = nac + (long)b*16384;
    for (int c = 0; c < 128; ++c)
        Ab[c*128 + n] = d2s[c][n] * di[c] * di[n];
}

// ---------------------------------------------------------------- Y2 = na_c @ cfea
__global__ void bmm_small_kernel(const float* __restrict__ nac, const float* __restrict__ cfea,
                                 float* __restrict__ Y2){
    __shared__ float row[128];
    int b = blockIdx.y, n = blockIdx.x, t = threadIdx.x;
    if (t < 128) row[t] = nac[(long)b*16384 + n*128 + t];
    __syncthreads();
    float acc = 0.f;
    #pragma unroll 4
    for (int k = 0; k < 128; ++k) acc += row[k]*cfea[(long)b*32768 + k*256 + t];
    Y2[(long)b*32768 + n*256 + t] = acc;
}

// ---------------------------------------------------------------- cut_loss_c
__global__ void cutc_kernel(const float* __restrict__ gs, const float* __restrict__ cxyz,
                            const float* __restrict__ cxyzg, float* __restrict__ scal, float inv){
    __shared__ float cg[48];
    __shared__ float red[128];
    int b = blockIdx.x, t = threadIdx.x;
    if (t < 48) cg[t] = cxyzg[b*48 + t];
    __syncthreads();
    float x0 = cxyz[b*384 + t*3+0], x1 = cxyz[b*384 + t*3+1], x2 = cxyz[b*384 + t*3+2];
    float acc = 0.f;
    #pragma unroll
    for (int k = 0; k < 16; ++k){
        float dx = x0-cg[k*3+0], dy = x1-cg[k*3+1], dz = x2-cg[k*3+2];
        acc += gs[b*2048 + t*16 + k]*(dx*dx+dy*dy+dz*dz);
    }
    acc = blockReduceSum(acc, red, 128);
    if (t == 0) atomicAdd(&scal[b], acc*inv);
}

// ---------------------------------------------------------------- cross attention (M=16) -> AO bf16
__global__ __launch_bounds__(256) void attn_kernel(const float* __restrict__ q,
                                                   const float* __restrict__ kk,
                                                   const float* __restrict__ vv,
                                                   unsigned short* __restrict__ aob){
    __shared__ float Ks[16][256], Vs[16][256];
    int b = blockIdx.y, n = blockIdx.x, t = threadIdx.x;
    #pragma unroll
    for (int p = 0; p < 16; ++p){
        int j = p*256 + t;
        Ks[j>>8][j&255] = kk[b*4096 + j];
        Vs[j>>8][j&255] = vv[b*4096 + j];
    }
    __syncthreads();
    float qv = q[((long)b*1024 + n)*256 + t];
    float sc[16];
    #pragma unroll
    for (int m = 0; m < 16; ++m){
        float v = qv * Ks[m][t];
        #pragma unroll
        for (int o = 32; o; o >>= 1) v += __shfl_xor(v, o, 64);
        sc[m] = v * 0.125f;
    }
    float mx = -1e30f;
    #pragma unroll
    for (int m = 0; m < 16; ++m) mx = fmaxf(mx, sc[m]);
    float sum = 0.f;
    #pragma unroll
    for (int m = 0; m < 16; ++m){ sc[m] = expf(sc[m]-mx); sum += sc[m]; }
    float o = 0.f;
    #pragma unroll
    for (int m = 0; m < 16; ++m) o += sc[m]*Vs[m][t];
    aob[((long)b*1024 + n)*256 + t] = f2bf(o / sum);
}

// ---------------------------------------------------------------- quad: wave per row, bf16 A (N=1024), deg-based
__global__ void quad_kernel(const unsigned short* __restrict__ A, const float* __restrict__ deg,
                            const float* __restrict__ xyz, float* __restrict__ scal){
    __shared__ float part[4];
    int t = threadIdx.x, w = t >> 6, l = t & 63;
    int n = blockIdx.x*4 + w;
    float a0=0,a1=0,a2=0;
    #pragma unroll 4
    for (int i = 0; i < 16; ++i){
        int m = l + i*64;
        float wv = bf2f(A[(long)n*1024 + m])*rsqrtf(deg[m] + EPSF);
        a0 += wv*xyz[m*3+0]; a1 += wv*xyz[m*3+1]; a2 += wv*xyz[m*3+2];
    }
    a0 = waveSum(a0); a1 = waveSum(a1); a2 = waveSum(a2);
    if (l == 0){
        float x0 = xyz[n*3+0], x1 = xyz[n*3+1], x2 = xyz[n*3+2];
        float dn = rsqrtf(deg[n] + EPSF);
        part[w] = (x0*x0+x1*x1+x2*x2) - dn*(x0*a0+x1*a1+x2*a2);
    }
    __syncthreads();
    if (t == 0) atomicAdd(&scal[4*64 + (blockIdx.x & 63)], part[0]+part[1]+part[2]+part[3]);
}

// ---------------------------------------------------------------- g_loss per-row: wave per row
__global__ void gloss_kernel(const float* __restrict__ agg, const float* __restrict__ gfea,
                             float* __restrict__ scal){
    __shared__ float part[4];
    int t = threadIdx.x, w = t >> 6, l = t & 63;
    long r = (long)blockIdx.x*4 + w;
    const float* a = agg + r*256;
    const float* g = gfea + r*256;
    float a0=a[l],a1=a[l+64],a2=a[l+128],a3=a[l+192];
    float g0=g[l],g1=g[l+64],g2=g[l+128],g3=g[l+192];
    float na2 = waveSum(a0*a0+a1*a1+a2*a2+a3*a3);
    float ng2 = waveSum(g0*g0+g1*g1+g2*g2+g3*g3);
    float ia = 1.f/fmaxf(sqrtf(na2), 1e-12f), ig = 1.f/fmaxf(sqrtf(ng2), 1e-12f);
    float e0=a0*ia-g0*ig, e1=a1*ia-g1*ig, e2=a2*ia-g2*ig, e3=a3*ia-g3*ig;
    float d2 = waveSum(e0*e0+e1*e1+e2*e2+e3*e3);
    if (l == 0) part[w] = sqrtf(d2);
    __syncthreads();
    if (t == 0) atomicAdd(&scal[3*64 + (blockIdx.x & 63)], part[0]+part[1]+part[2]+part[3]);
}

// ---------------------------------------------------------------- finalize
__global__ void finalize_kernel(const float* __restrict__ scal, float* __restrict__ out){
    int t = threadIdx.x;
    float s[5];
    #pragma unroll
    for (int q = 0; q < 5; ++q){
        float v = scal[q*64 + t];
        #pragma unroll
        for (int o = 32; o; o >>= 1) v += __shfl_xor(v, o, 64);
        s[q] = v;
    }
    if (t == 0){
        out[524288] = s[0] + sqrtf(s[1]) + sqrtf(s[2]);
        out[524289] = s[3]*0.5f + 1e-4f*s[4]/2048.0f;
    }
}

// ================================================================ launcher
extern "C" void kernel_launch(void* const* d_in, const int* in_sizes, int n_in,
                              void* d_out, int out_size, void* d_ws, size_t ws_size,
                              hipStream_t stream){
    const float* g_fea   = (const float*)d_in[0];
    const float* g_xyz   = (const float*)d_in[1];
    const float* p_fea_0 = (const float*)d_in[2];
    const float* p_xyz_0 = (const float*)d_in[3];
    const float* p_fea_1 = (const float*)d_in[4];
    const float* p_xyz_1 = (const float*)d_in[5];
    const float* lW1 = (const float*)d_in[6];
    const float* lb1 = (const float*)d_in[7];
    const float* lW2 = (const float*)d_in[8];
    const float* lb2 = (const float*)d_in[9];
    const float* gW1 = (const float*)d_in[10];
    const float* gb1 = (const float*)d_in[11];
    const float* gW2 = (const float*)d_in[12];
    const float* gb2 = (const float*)d_in[13];
    const float* Wq = (const float*)d_in[14];
    const float* Wk = (const float*)d_in[15];
    const float* Wv = (const float*)d_in[16];
    const float* Wo = (const float*)d_in[17];
    float* out = (float*)d_out;
    float* ws_f = (float*)d_ws;

    // ---- workspace layout (float units)
    constexpr long O_SCALS = 0;                      // 512 spread slots
    constexpr long O_DEG   = 512;                    // 14336 degree sums
    constexpr long O_CFEA  = 16384;                  // (B,128,256) f32
    constexpr long O_CXYZ  = O_CFEA + 65536;
    constexpr long O_DEN   = O_CXYZ + 768;
    constexpr long O_CFG   = O_DEN  + 256;
    constexpr long O_CXG   = O_CFG  + 8192;
    constexpr long O_DENG  = O_CXG  + 96;
    constexpr long O_PART  = O_DENG + 64;            // 524288 partials
    constexpr long O_NFB   = O_PART + 524288;        // bf16 (2*4096,256)
    constexpr long O_XST   = O_NFB  + 1048576;       // bf16 (2,256,4096)
    constexpr long O_FEAT  = O_XST  + 1048576;       // bf16 (2,256,4096)
    constexpr long O_YB    = O_FEAT + 1048576;       // bf16 (2,N,256)
    constexpr long O_HB    = O_YB   + 1048576;       // bf16 (2N,128)
    constexpr long O_S     = O_HB   + 524288;        // f32 (2N,64)
    constexpr long O_ST    = O_S    + 524288;        // bf16 (64, 2*4096)
    constexpr long O_PY    = O_ST   + 262144;        // f32 8*(N,256)
    constexpr long O_A     = O_PY   + 8388608;       // bf16 (4096,4096)
    constexpr long O_Q     = O_A    + 8388608;       // f32 (2048,256)
    constexpr long O_GFB   = O_Q    + 524288;        // bf16 g_fea
    constexpr long O_AOB   = O_GFB  + 262144;        // bf16 attn-out
    constexpr long O_KK    = O_AOB  + 262144;
    constexpr long O_VV    = O_KK   + 8192;
    constexpr long O_NAC   = O_VV   + 8192;
    constexpr long O_Y2    = O_NAC  + 32768;
    constexpr long O_H2    = O_Y2   + 65536;
    constexpr long O_LG2   = O_H2   + 32768;
    constexpr long O_W1T   = O_LG2  + 4096;
    constexpr long O_W2T   = O_W1T  + 16384;
    constexpr long O_WQT   = O_W2T  + 4096;
    constexpr long O_WOT   = O_WQT  + 32768;

    hipMemsetAsync(ws_f + O_SCALS, 0, (512 + 14336)*sizeof(float), stream);

    unsigned short* nfb  = (unsigned short*)(ws_f + O_NFB);
    unsigned short* xsT  = (unsigned short*)(ws_f + O_XST);
    unsigned short* feaT = (unsigned short*)(ws_f + O_FEAT);
    unsigned short* Ybb  = (unsigned short*)(ws_f + O_YB);
    unsigned short* Hb   = (unsigned short*)(ws_f + O_HB);
    unsigned short* sTb  = (unsigned short*)(ws_f + O_ST);
    unsigned short* A    = (unsigned short*)(ws_f + O_A);
    unsigned short* gfb  = (unsigned short*)(ws_f + O_GFB);
    unsigned short* aob  = (unsigned short*)(ws_f + O_AOB);
    unsigned short* lW1T = (unsigned short*)(ws_f + O_W1T);
    unsigned short* lW2T = (unsigned short*)(ws_f + O_W2T);
    unsigned short* WqT  = (unsigned short*)(ws_f + O_WQT);
    unsigned short* WoT  = (unsigned short*)(ws_f + O_WOT);
    float* sb   = ws_f + O_S;
    float* degA = ws_f + O_DEG;
    float* PY   = ws_f + O_PY;
    float* part = ws_f + O_PART;
    float* Qf   = ws_f + O_Q;

    // weight conversions
    tcvt_kernel<<<dim3(4, 2), 256, 0, stream>>>(lW1, lW1T, 256, 128);
    tcvt_kernel<<<dim3(2, 1), 256, 0, stream>>>(lW2, lW2T, 128, 64);
    tcvt_kernel<<<dim3(4, 4), 256, 0, stream>>>(Wq, WqT, 256, 256);
    tcvt_kernel<<<dim3(4, 4), 256, 0, stream>>>(Wo, WoT, 256, 256);
    cvt_bf16_kernel<<<512, 256, 0, stream>>>(g_fea, gfb, 131072);

    struct Lvl { const float* fea; const float* xyz; int N; int k0; int ndsSlot; long degBase; };
    Lvl lv[2] = {{p_fea_0, p_xyz_0, 4096, 0, 1, 0}, {p_fea_1, p_xyz_1, 2048, 64, 2, 8192}};

    for (int L = 0; L < 2; ++L){
        int N = lv[L].N;
        const float* fea = lv[L].fea;
        const float* xyz = lv[L].xyz;
        l2norm_kernel<<<2*N, 256, 0, stream>>>(fea, nfb, 2*N);
        for (int b = 0; b < 2; ++b){
            float* degb = degA + lv[L].degBase + (long)b*N;
            gram_mfma_kernel<<<dim3(N/128, N/128), 256, 0, stream>>>(nfb + (long)b*N*256,
                                                                     xyz + (long)b*N*3, A, degb,
                                                                     N, 1.0f, 0.25f);
            transpose_scale_kernel<<<dim3(N/64, 4), 256, 0, stream>>>(fea + (long)b*N*256, degb,
                                                                      feaT + (long)b*256*N,
                                                                      xsT + (long)b*256*N, N);
            ax_mfma_kernel<<<dim3(2, N/128, 8), 256, 0, stream>>>(A, xsT + (long)b*256*N, PY, N, 8);
            combine_kernel<<<N/8, 256, 0, stream>>>(PY, degb, Ybb + (long)b*N*256, N, 8);
        }
        gemm_XW_mfma_kernel<<<dim3(1, 2*N/128), 256, 0, stream>>>(Ybb, lW1T, lb1, nullptr, Hb,
                                                                  2*N, 256, 128, 1);
        gemm_XW_mfma_kernel<<<dim3(1, 2*N/128), 256, 0, stream>>>(Hb, lW2T, lb2, sb, nullptr,
                                                                  2*N, 128, 64, 0);
        softmaxT_kernel<<<2*N/64, 256, 0, stream>>>(sb, sTb, 2*N, 10.0f);
        cluster_xyz_kernel<<<dim3(64, 2), 256, 0, stream>>>(sb, xyz, ws_f + O_CXYZ + lv[L].k0*3,
                                                            ws_f + O_DEN + lv[L].k0, N, 64, 384, 128);
        stx_mfma_kernel<<<32, 256, 0, stream>>>(sTb, feaT, part, N, 16, 2*N);
        divide_sum_kernel<<<dim3(64, 2), 256, 0, stream>>>(part, ws_f + O_DEN + lv[L].k0,
                                                           ws_f + O_CFEA + lv[L].k0*256,
                                                           ws_f + O_CXYZ + lv[L].k0*3,
                                                           64, 16, 128*256, 384, 128);
        level_loss_kernel<<<dim3(N/4, 2), 256, 0, stream>>>(sb, xyz, ws_f + O_CXYZ + lv[L].k0*3,
                                                            ws_f + O_CFEA + lv[L].k0*256, nfb,
                                                            ws_f + O_SCALS, N, 1.0f/(2.0f*N), lv[L].ndsSlot);
    }

    // ---- global cluster stage
    knn_nac_kernel<<<2, 128, 0, stream>>>(ws_f + O_CXYZ, ws_f + O_NAC);
    bmm_small_kernel<<<dim3(128, 2), 256, 0, stream>>>(ws_f + O_NAC, ws_f + O_CFEA, ws_f + O_Y2);
    gemm_splitk_kernel<<<dim3(2, 4, 4), 256, 0, stream>>>(ws_f + O_Y2, gW1, nullptr, part,
                                                          256, 256, 128, 4);
    combine_bias_kernel<<<128, 256, 0, stream>>>(part, gb1, ws_f + O_H2, 256, 128, 4, 1);
    gemm_splitk_kernel<<<dim3(1, 4, 4), 256, 0, stream>>>(ws_f + O_H2, gW2, nullptr, part,
                                                          256, 128, 16, 4);
    combine_bias_kernel<<<16, 256, 0, stream>>>(part, gb2, ws_f + O_LG2, 256, 16, 4, 0);
    softmax_kernel<<<256, 64, 0, stream>>>(ws_f + O_LG2, 16, 0.1f);
    cluster_xyz_kernel<<<dim3(16, 2), 256, 0, stream>>>(ws_f + O_LG2, ws_f + O_CXYZ,
                                                        ws_f + O_CXG, ws_f + O_DENG, 128, 16, 48, 16);
    gemm_sTX_kernel<<<dim3(4, 1, 8), 256, 0, stream>>>(ws_f + O_LG2, ws_f + O_CFEA, part,
                                                       128, 16, 4, 128L*16, 128L*256);
    divide_sum_kernel<<<dim3(16, 2), 256, 0, stream>>>(part, ws_f + O_DENG, ws_f + O_CFG,
                                                       ws_f + O_CXG, 16, 4, 16*256, 48, 16);
    cutc_kernel<<<2, 128, 0, stream>>>(ws_f + O_LG2, ws_f + O_CXYZ, ws_f + O_CXG,
                                       ws_f + O_SCALS, 1.0f/256.0f);

    // ---- cross attention
    gemm_XW_mfma_kernel<<<dim3(2, 16), 256, 0, stream>>>(gfb, WqT, nullptr, Qf, nullptr,
                                                         2048, 256, 256, 0);
    gemm_splitk_kernel<<<dim3(4, 1, 16), 256, 0, stream>>>(ws_f + O_CFG, Wk, Wv, part,
                                                           32, 256, 256, 8);
    combine_bias_kernel<<<32, 256, 0, stream>>>(part, nullptr, ws_f + O_KK, 32, 256, 8, 0);
    combine_bias_kernel<<<32, 256, 0, stream>>>(part + 8L*32*256, nullptr, ws_f + O_VV, 32, 256, 8, 0);
    attn_kernel<<<dim3(1024, 2), 256, 0, stream>>>(Qf, ws_f + O_KK, ws_f + O_VV, aob);
    gemm_XW_mfma_kernel<<<dim3(2, 16), 256, 0, stream>>>(aob, WoT, nullptr, out, nullptr,
                                                         2048, 256, 256, 0);

    // ---- A_g stage
    l2norm_kernel<<<2048, 256, 0, stream>>>(g_fea, nfb, 2048);
    for (int b = 0; b < 2; ++b){
        float* degb = degA + 12288 + (long)b*1024;
        gram_mfma_kernel<<<dim3(8, 8), 256, 0, stream>>>(nfb + (long)b*1024*256, g_xyz + (long)b*1024*3,
                                                         A, degb, 1024, 16.0f, 0.25f);
        quad_kernel<<<256, 256, 0, stream>>>(A, degb, g_xyz + (long)b*1024*3, ws_f + O_SCALS);
    }

    gloss_kernel<<<512, 256, 0, stream>>>(out, g_fea, ws_f + O_SCALS);
    finalize_kernel<<<1, 64, 0, stream>>>(ws_f + O_SCALS, out);
}

// Round 7
// 756.813 us; speedup vs baseline: 3.1347x; 1.0175x over previous
//
#include <hip/hip_runtime.h>

#define EPSF 1e-4f

typedef __attribute__((ext_vector_type(8))) short bf16x8;
typedef __attribute__((ext_vector_type(4))) float f32x4;

__device__ __forceinline__ unsigned short f2bf(float f){
    unsigned int u = __float_as_uint(f);
    return (unsigned short)((u + 0x7FFF + ((u >> 16) & 1)) >> 16);
}
__device__ __forceinline__ float bf2f(unsigned short u){
    return __uint_as_float(((unsigned int)u) << 16);
}
__device__ __forceinline__ float waveSum(float v){
    #pragma unroll
    for (int o = 32; o; o >>= 1) v += __shfl_xor(v, o, 64);
    return v;
}
__device__ __forceinline__ float waveMin(float v){
    #pragma unroll
    for (int o = 32; o; o >>= 1) v = fminf(v, __shfl_xor(v, o, 64));
    return v;
}
__device__ __forceinline__ float waveMax(float v){
    #pragma unroll
    for (int o = 32; o; o >>= 1) v = fmaxf(v, __shfl_xor(v, o, 64));
    return v;
}
__device__ __forceinline__ float blockReduceSum(float v, float* red, int nthr){
    int t = threadIdx.x;
    red[t] = v; __syncthreads();
    for (int s = nthr >> 1; s > 0; s >>= 1){
        if (t < s) red[t] += red[t + s];
        __syncthreads();
    }
    float r = red[0]; __syncthreads();
    return r;
}

// ---------------------------------------------------------------- l2norm rows of 256 -> bf16
__global__ void l2norm_kernel(const float* __restrict__ x, unsigned short* __restrict__ outb, int rows){
    __shared__ float red[256];
    int row = blockIdx.x, t = threadIdx.x;
    float v = x[(long)row*256 + t];
    float s = blockReduceSum(v*v, red, 256);
    float nrm = fmaxf(sqrtf(s), 1e-12f);
    outb[(long)row*256 + t] = f2bf(v / nrm);
}

// ---------------------------------------------------------------- flat f32 -> bf16
__global__ void cvt_bf16_kernel(const float* __restrict__ in, unsigned short* __restrict__ out, long n4){
    long i = (long)blockIdx.x*256 + threadIdx.x;
    if (i < n4){
        float4 v = ((const float4*)in)[i];
        unsigned int lo = f2bf(v.x) | ((unsigned int)f2bf(v.y) << 16);
        unsigned int hi = f2bf(v.z) | ((unsigned int)f2bf(v.w) << 16);
        uint2 u; u.x = lo; u.y = hi;
        ((uint2*)out)[i] = u;
    }
}

// ---------------------------------------------------------------- transpose+cvt weight: W(Rw,Cw) -> WT(Cw,Rw) bf16
__global__ void tcvt_kernel(const float* __restrict__ W, unsigned short* __restrict__ WT,
                            int Rw, int Cw){
    __shared__ float tile[64][65];
    int r0 = blockIdx.x*64, c0 = blockIdx.y*64;
    int t = threadIdx.x;
    for (int idx = t; idx < 4096; idx += 256){
        int rr = idx >> 6, cc = idx & 63;
        tile[rr][cc] = (r0+rr < Rw && c0+cc < Cw) ? W[(long)(r0+rr)*Cw + c0+cc] : 0.f;
    }
    __syncthreads();
    for (int idx = t; idx < 4096; idx += 256){
        int cc = idx >> 6, rr = idx & 63;
        if (r0+rr < Rw && c0+cc < Cw)
            WT[(long)(c0+cc)*Rw + r0+rr] = f2bf(tile[rr][cc]);
    }
}

// ---------------------------------------------------------------- MFMA gram (pad-40 LDS): A + fused degree sums
__global__ __launch_bounds__(256) void gram_mfma_kernel(const unsigned short* __restrict__ nf,
                                                        const float* __restrict__ xyz,
                                                        unsigned short* __restrict__ A,
                                                        float* __restrict__ deg,
                                                        int N, float r2, float scale){
    __shared__ short tA[128*40], tB[128*40];
    __shared__ float xa[384], xb[384];
    int tid = threadIdx.x;
    int n0 = blockIdx.y*128, m0 = blockIdx.x*128;
    for (int i = tid; i < 384; i += 256){ xa[i] = xyz[n0*3 + i]; xb[i] = xyz[m0*3 + i]; }
    int w = tid >> 6, l = tid & 63;
    int wy = w >> 1, wx = w & 1;
    int lg = l >> 4, lr = l & 15;
    int srow = tid >> 2, sc = tid & 3;
    f32x4 zero = {0.f, 0.f, 0.f, 0.f};
    f32x4 acc[4][4];
    #pragma unroll
    for (int i = 0; i < 4; ++i)
        #pragma unroll
        for (int j = 0; j < 4; ++j) acc[i][j] = zero;
    for (int kt = 0; kt < 256; kt += 32){
        __syncthreads();
        #pragma unroll
        for (int p = 0; p < 2; ++p){
            int row = srow + p*64;
            uint4 va = *(const uint4*)(nf + (long)(n0+row)*256 + kt + sc*8);
            uint4 vb = *(const uint4*)(nf + (long)(m0+row)*256 + kt + sc*8);
            *(uint4*)(tA + row*40 + sc*8) = va;
            *(uint4*)(tB + row*40 + sc*8) = vb;
        }
        __syncthreads();
        bf16x8 af[4], bfr[4];
        #pragma unroll
        for (int f = 0; f < 4; ++f){
            af[f]  = *(const bf16x8*)(tA + (wy*64 + f*16 + lr)*40 + lg*8);
            bfr[f] = *(const bf16x8*)(tB + (wx*64 + f*16 + lr)*40 + lg*8);
        }
        #pragma unroll
        for (int i = 0; i < 4; ++i)
            #pragma unroll
            for (int j = 0; j < 4; ++j)
                acc[i][j] = __builtin_amdgcn_mfma_f32_16x16x32_bf16(af[i], bfr[j], acc[i][j], 0, 0, 0);
    }
    #pragma unroll
    for (int fi = 0; fi < 4; ++fi){
        #pragma unroll
        for (int r = 0; r < 4; ++r){
            int n_ = wy*64 + fi*16 + lg*4 + r;
            int gn = n0 + n_;
            float rowacc = 0.f;
            #pragma unroll
            for (int fj = 0; fj < 4; ++fj){
                int m_ = wx*64 + fj*16 + lr;
                float dx = xa[n_*3+0]-xb[m_*3+0];
                float dy = xa[n_*3+1]-xb[m_*3+1];
                float dz = xa[n_*3+2]-xb[m_*3+2];
                float d2x = dx*dx + dy*dy + dz*dz;
                int gm = m0 + m_;
                float dot = acc[fi][fj][r];
                float val = (d2x < r2 && gn != gm) ? expf(scale*(2.f*dot - 2.f)) : 0.f;
                A[(long)gn*N + gm] = f2bf(val);
                rowacc += val;
            }
            rowacc += __shfl_xor(rowacc, 1, 64);
            rowacc += __shfl_xor(rowacc, 2, 64);
            rowacc += __shfl_xor(rowacc, 4, 64);
            rowacc += __shfl_xor(rowacc, 8, 64);
            if (lr == 0) atomicAdd(&deg[gn], rowacc);
        }
    }
}

// ---------------------------------------------------------------- feaT / xsT transpose+scale
__global__ __launch_bounds__(256) void transpose_scale_kernel(const float* __restrict__ fea,
                                                              const float* __restrict__ deg,
                                                              unsigned short* __restrict__ feaT,
                                                              unsigned short* __restrict__ xsT, int N){
    __shared__ float tile[64][65];
    __shared__ float dl[64];
    int m0 = blockIdx.x*64, c0 = blockIdx.y*64;
    int t = threadIdx.x;
    int lr = t >> 2, lc = (t & 3)*16;
    #pragma unroll
    for (int j = 0; j < 4; ++j){
        float4 v = *(const float4*)(fea + (long)(m0+lr)*256 + c0 + lc + j*4);
        tile[lr][lc+j*4+0] = v.x; tile[lr][lc+j*4+1] = v.y;
        tile[lr][lc+j*4+2] = v.z; tile[lr][lc+j*4+3] = v.w;
    }
    if (t < 64) dl[t] = rsqrtf(deg[m0+t] + EPSF);
    __syncthreads();
    unsigned short vr[16] __attribute__((aligned(16)));
    unsigned short vs[16] __attribute__((aligned(16)));
    #pragma unroll
    for (int j = 0; j < 16; ++j){
        float raw = tile[lc+j][lr];
        vr[j] = f2bf(raw);
        vs[j] = f2bf(raw * dl[lc+j]);
    }
    long off = (long)(c0+lr)*N + m0 + lc;
    *(uint4*)(feaT + off)     = *(uint4*)&vr[0];
    *(uint4*)(feaT + off + 8) = *(uint4*)&vr[8];
    *(uint4*)(xsT + off)      = *(uint4*)&vs[0];
    *(uint4*)(xsT + off + 8)  = *(uint4*)&vs[8];
}

// ---------------------------------------------------------------- MFMA A@XsT^T -> PY partials
// 128x64 tiles, grid (4, N/128, split), pad-40 LDS, reg prefetch
__global__ __launch_bounds__(256) void ax_mfma_kernel(const unsigned short* __restrict__ A,
                                                      const unsigned short* __restrict__ xsT,
                                                      float* __restrict__ PY, int N, int split){
    __shared__ short tA[128*40], tB[64*40];
    int tid = threadIdx.x;
    int c0 = blockIdx.x*64, n0 = blockIdx.y*128;
    int chunk = blockIdx.z;
    int L = N/split, kbase = chunk*L, kend = kbase + L;
    int w = tid >> 6, l = tid & 63;
    int wy = w >> 1, wx = w & 1;
    int lg = l >> 4, lr = l & 15;
    int srow = tid >> 2, sc = tid & 3;
    f32x4 zero = {0.f, 0.f, 0.f, 0.f};
    f32x4 acc[4][2];
    #pragma unroll
    for (int i = 0; i < 4; ++i)
        #pragma unroll
        for (int j = 0; j < 2; ++j) acc[i][j] = zero;
    uint4 pva[2], pvb;
    #pragma unroll
    for (int p = 0; p < 2; ++p)
        pva[p] = *(const uint4*)(A + (long)(n0+srow+p*64)*N + kbase + sc*8);
    pvb = *(const uint4*)(xsT + (long)(c0+srow)*N + kbase + sc*8);
    for (int kt = kbase; kt < kend; kt += 32){
        __syncthreads();
        #pragma unroll
        for (int p = 0; p < 2; ++p)
            *(uint4*)(tA + (srow+p*64)*40 + sc*8) = pva[p];
        *(uint4*)(tB + srow*40 + sc*8) = pvb;
        __syncthreads();
        if (kt + 32 < kend){
            #pragma unroll
            for (int p = 0; p < 2; ++p)
                pva[p] = *(const uint4*)(A + (long)(n0+srow+p*64)*N + kt + 32 + sc*8);
            pvb = *(const uint4*)(xsT + (long)(c0+srow)*N + kt + 32 + sc*8);
        }
        bf16x8 af[4], bfr[2];
        #pragma unroll
        for (int f = 0; f < 4; ++f)
            af[f] = *(const bf16x8*)(tA + (wy*64 + f*16 + lr)*40 + lg*8);
        #pragma unroll
        for (int f = 0; f < 2; ++f)
            bfr[f] = *(const bf16x8*)(tB + (wx*32 + f*16 + lr)*40 + lg*8);
        #pragma unroll
        for (int i = 0; i < 4; ++i)
            #pragma unroll
            for (int j = 0; j < 2; ++j)
                acc[i][j] = __builtin_amdgcn_mfma_f32_16x16x32_bf16(af[i], bfr[j], acc[i][j], 0, 0, 0);
    }
    float* out = PY + (long)chunk*N*256;
    #pragma unroll
    for (int fi = 0; fi < 4; ++fi){
        #pragma unroll
        for (int fj = 0; fj < 2; ++fj){
            #pragma unroll
            for (int r = 0; r < 4; ++r){
                int n_ = n0 + wy*64 + fi*16 + lg*4 + r;
                int c_ = c0 + wx*32 + fj*16 + lr;
                out[(long)n_*256 + c_] = acc[fi][fj][r];
            }
        }
    }
}

// ---------------------------------------------------------------- Yb(bf16) = rsqrt(deg[n])*sum_split(PY)
__global__ void combine_kernel(const float* __restrict__ PY, const float* __restrict__ deg,
                               unsigned short* __restrict__ Yb, int N, int split){
    long i = (long)blockIdx.x*256 + threadIdx.x;
    long e = i*8;
    float4 s0 = {0,0,0,0}, s1 = {0,0,0,0};
    for (int q = 0; q < split; ++q){
        const float4* p = (const float4*)(PY + (long)q*N*256 + e);
        float4 a = p[0], b = p[1];
        s0.x += a.x; s0.y += a.y; s0.z += a.z; s0.w += a.w;
        s1.x += b.x; s1.y += b.y; s1.z += b.z; s1.w += b.w;
    }
    float d = rsqrtf(deg[e >> 8] + EPSF);
    unsigned short vb[8] __attribute__((aligned(16)));
    vb[0] = f2bf(s0.x*d); vb[1] = f2bf(s0.y*d);
    vb[2] = f2bf(s0.z*d); vb[3] = f2bf(s0.w*d);
    vb[4] = f2bf(s1.x*d); vb[5] = f2bf(s1.y*d);
    vb[6] = f2bf(s1.z*d); vb[7] = f2bf(s1.w*d);
    *(uint4*)(Yb + e) = *(uint4*)vb;
}

// ---------------------------------------------------------------- MFMA X @ WT + bias [relu] (pad-40, prefetch)
__global__ __launch_bounds__(256) void gemm_XW_mfma_kernel(const unsigned short* __restrict__ X,
                                                           const unsigned short* __restrict__ WT,
                                                           const float* __restrict__ bias,
                                                           float* __restrict__ outF,
                                                           unsigned short* __restrict__ outB,
                                                           int R, int Ci, int Co, int relu){
    __shared__ short tA[128*40], tB[128*40];
    int tid = threadIdx.x;
    int c0 = blockIdx.x*128, r0 = blockIdx.y*128;
    int w = tid >> 6, l = tid & 63;
    int wy = w >> 1, wx = w & 1;
    int lg = l >> 4, lr = l & 15;
    int srow = tid >> 2, sc = tid & 3;
    f32x4 zero = {0.f, 0.f, 0.f, 0.f};
    f32x4 acc[4][4];
    #pragma unroll
    for (int i = 0; i < 4; ++i)
        #pragma unroll
        for (int j = 0; j < 4; ++j) acc[i][j] = zero;
    uint4 pva[2], pvb[2];
    #pragma unroll
    for (int p = 0; p < 2; ++p){
        int row = srow + p*64;
        int ar = r0 + row, br = c0 + row;
        pva[p] = (ar < R)  ? *(const uint4*)(X  + (long)ar*Ci + sc*8) : (uint4){0,0,0,0};
        pvb[p] = (br < Co) ? *(const uint4*)(WT + (long)br*Ci + sc*8) : (uint4){0,0,0,0};
    }
    for (int kt = 0; kt < Ci; kt += 32){
        __syncthreads();
        #pragma unroll
        for (int p = 0; p < 2; ++p){
            int row = srow + p*64;
            *(uint4*)(tA + row*40 + sc*8) = pva[p];
            *(uint4*)(tB + row*40 + sc*8) = pvb[p];
        }
        __syncthreads();
        if (kt + 32 < Ci){
            #pragma unroll
            for (int p = 0; p < 2; ++p){
                int row = srow + p*64;
                int ar = r0 + row, br = c0 + row;
                pva[p] = (ar < R)  ? *(const uint4*)(X  + (long)ar*Ci + kt + 32 + sc*8) : (uint4){0,0,0,0};
                pvb[p] = (br < Co) ? *(const uint4*)(WT + (long)br*Ci + kt + 32 + sc*8) : (uint4){0,0,0,0};
            }
        }
        bf16x8 af[4], bfr[4];
        #pragma unroll
        for (int f = 0; f < 4; ++f){
            af[f]  = *(const bf16x8*)(tA + (wy*64 + f*16 + lr)*40 + lg*8);
            bfr[f] = *(const bf16x8*)(tB + (wx*64 + f*16 + lr)*40 + lg*8);
        }
        #pragma unroll
        for (int i = 0; i < 4; ++i)
            #pragma unroll
            for (int j = 0; j < 4; ++j)
                acc[i][j] = __builtin_amdgcn_mfma_f32_16x16x32_bf16(af[i], bfr[j], acc[i][j], 0, 0, 0);
    }
    #pragma unroll
    for (int fi = 0; fi < 4; ++fi){
        #pragma unroll
        for (int fj = 0; fj < 4; ++fj){
            #pragma unroll
            for (int r = 0; r < 4; ++r){
                int rr = r0 + wy*64 + fi*16 + lg*4 + r;
                int cc = c0 + wx*64 + fj*16 + lr;
                if (rr < R && cc < Co){
                    float v = acc[fi][fj][r] + (bias ? bias[cc] : 0.f);
                    if (relu) v = fmaxf(v, 0.f);
                    if (outF) outF[(long)rr*Co + cc] = v;
                    if (outB) outB[(long)rr*Co + cc] = f2bf(v);
                }
            }
        }
    }
}

// ---------------------------------------------------------------- split-K f32 GEMM -> partials
__global__ __launch_bounds__(256) void gemm_splitk_kernel(const float* __restrict__ X,
                                                          const float* __restrict__ W0,
                                                          const float* __restrict__ W1,
                                                          float* __restrict__ part,
                                                          int R, int Ci, int Co, int Ks){
    __shared__ float sa[32][65], sb[32][65];
    int tid = threadIdx.x, tx = tid & 15, ty = tid >> 4;
    int c0 = blockIdx.x * 64, r0 = blockIdx.y * 64;
    int z = blockIdx.z;
    const float* W = (z / Ks) ? W1 : W0;
    int kchunk = Ci / Ks, kst = (z % Ks) * kchunk;
    float acc[4][4] = {};
    for (int kt = kst; kt < kst + kchunk; kt += 32){
        #pragma unroll
        for (int p = 0; p < 8; ++p){
            int idx = p*256 + tid;
            int k = idx & 31, i = idx >> 5;
            int rr = r0 + i;
            sa[k][i] = (rr < R) ? X[(long)rr*Ci + kt + k] : 0.f;
            int j = idx & 63, kk = idx >> 6;
            int cc = c0 + j;
            sb[kk][j] = (cc < Co) ? W[(long)(kt+kk)*Co + cc] : 0.f;
        }
        __syncthreads();
        #pragma unroll
        for (int k = 0; k < 32; ++k){
            float a0=sa[k][ty*4+0],a1=sa[k][ty*4+1],a2=sa[k][ty*4+2],a3=sa[k][ty*4+3];
            float b0=sb[k][tx*4+0],b1=sb[k][tx*4+1],b2=sb[k][tx*4+2],b3=sb[k][tx*4+3];
            acc[0][0]+=a0*b0; acc[0][1]+=a0*b1; acc[0][2]+=a0*b2; acc[0][3]+=a0*b3;
            acc[1][0]+=a1*b0; acc[1][1]+=a1*b1; acc[1][2]+=a1*b2; acc[1][3]+=a1*b3;
            acc[2][0]+=a2*b0; acc[2][1]+=a2*b1; acc[2][2]+=a2*b2; acc[2][3]+=a2*b3;
            acc[3][0]+=a3*b0; acc[3][1]+=a3*b1; acc[3][2]+=a3*b2; acc[3][3]+=a3*b3;
        }
        __syncthreads();
    }
    float* outp = part + (long)z*R*Co;
    #pragma unroll
    for (int r = 0; r < 4; ++r){
        #pragma unroll
        for (int c = 0; c < 4; ++c){
            int rr = r0 + ty*4 + r, cc = c0 + tx*4 + c;
            if (rr < R && cc < Co) outp[(long)rr*Co + cc] = acc[r][c];
        }
    }
}

// ---------------------------------------------------------------- sum split-K partials + bias [+relu]
__global__ void combine_bias_kernel(const float* __restrict__ part, const float* __restrict__ bias,
                                    float* __restrict__ out, int R, int Co, int Ks, int relu){
    long i = (long)blockIdx.x*256 + threadIdx.x;
    if (i < (long)R*Co){
        long zs = (long)R*Co;
        float s = 0.f;
        for (int q = 0; q < Ks; ++q) s += part[q*zs + i];
        float v = s + (bias ? bias[i % Co] : 0.f);
        if (relu) v = fmaxf(v, 0.f);
        out[i] = v;
    }
}

// ---------------------------------------------------------------- softmax rows of 64 + sT bf16
__global__ __launch_bounds__(256) void softmaxT_kernel(float* __restrict__ s,
                                                       unsigned short* __restrict__ sT,
                                                       int sStride, float invtau){
    __shared__ unsigned short st[64][65];
    int blk = blockIdx.x, t = threadIdx.x, w = t >> 6, l = t & 63;
    #pragma unroll
    for (int i = 0; i < 16; ++i){
        int rloc = w + 4*i;
        long row = (long)blk*64 + rloc;
        float v = s[row*64 + l] * invtau;
        float mx = waveMax(v);
        float e = expf(v - mx);
        float sum = waveSum(e);
        float p = e / sum;
        s[row*64 + l] = p;
        st[l][rloc] = f2bf(p);
    }
    __syncthreads();
    int k = t >> 2, j = (t & 3)*16;
    unsigned short vbuf[16] __attribute__((aligned(16)));
    #pragma unroll
    for (int q = 0; q < 16; ++q) vbuf[q] = st[k][j+q];
    long off = (long)k*sStride + (long)blk*64 + j;
    *(uint4*)(sT + off)     = *(uint4*)&vbuf[0];
    *(uint4*)(sT + off + 8) = *(uint4*)&vbuf[8];
}

// ---------------------------------------------------------------- MFMA sT @ feaT^T -> part per (b,chunk) (pad-40)
__global__ __launch_bounds__(256) void stx_mfma_kernel(const unsigned short* __restrict__ sT,
                                                       const unsigned short* __restrict__ feaT,
                                                       float* __restrict__ part,
                                                       int N, int split, int sStride){
    __shared__ short tA[64*40], tB[256*40];
    int tid = threadIdx.x;
    int z = blockIdx.x, b = z / split, chunk = z % split;
    int L = N / split, kst = chunk * L;
    const unsigned short* sTb = sT + (long)b*N;
    const unsigned short* fT  = feaT + (long)b*256*N;
    int w = tid >> 6, l = tid & 63;
    int lg = l >> 4, lr = l & 15;
    f32x4 zero = {0.f, 0.f, 0.f, 0.f};
    f32x4 acc[4][4];
    #pragma unroll
    for (int i = 0; i < 4; ++i)
        #pragma unroll
        for (int j = 0; j < 4; ++j) acc[i][j] = zero;
    int srow = tid >> 2, koff = (tid & 3)*8;
    for (int kt = kst; kt < kst + L; kt += 32){
        __syncthreads();
        *(uint4*)(tA + srow*40 + koff) = *(const uint4*)(sTb + (long)srow*sStride + kt + koff);
        #pragma unroll
        for (int p = 0; p < 4; ++p){
            int row = srow + p*64;
            *(uint4*)(tB + row*40 + koff) = *(const uint4*)(fT + (long)row*N + kt + koff);
        }
        __syncthreads();
        bf16x8 af[4], bfr[4];
        #pragma unroll
        for (int f = 0; f < 4; ++f){
            af[f]  = *(const bf16x8*)(tA + (f*16 + lr)*40 + lg*8);
            bfr[f] = *(const bf16x8*)(tB + (w*64 + f*16 + lr)*40 + lg*8);
        }
        #pragma unroll
        for (int i = 0; i < 4; ++i)
            #pragma unroll
            for (int j = 0; j < 4; ++j)
                acc[i][j] = __builtin_amdgcn_mfma_f32_16x16x32_bf16(af[i], bfr[j], acc[i][j], 0, 0, 0);
    }
    float* outp = part + (long)z*64*256;
    #pragma unroll
    for (int fi = 0; fi < 4; ++fi){
        #pragma unroll
        for (int fj = 0; fj < 4; ++fj){
            #pragma unroll
            for (int r = 0; r < 4; ++r){
                int kc = fi*16 + lg*4 + r;
                int cc = w*64 + fj*16 + lr;
                outp[(long)kc*256 + cc] = acc[fi][fj][r];
            }
        }
    }
}

// ---------------------------------------------------------------- row softmax (K<=64), in place
__global__ void softmax_kernel(float* __restrict__ x, int Kc, float tau){
    int row = blockIdx.x, lane = threadIdx.x;
    bool act = lane < Kc;
    float v = act ? x[(long)row*Kc + lane] / tau : -1e30f;
    float mx = v;
    #pragma unroll
    for (int o = 32; o; o >>= 1) mx = fmaxf(mx, __shfl_xor(mx, o, 64));
    float e = act ? expf(v - mx) : 0.f;
    float s = e;
    #pragma unroll
    for (int o = 32; o; o >>= 1) s += __shfl_xor(s, o, 64);
    if (act) x[(long)row*Kc + lane] = e / s;
}

// ---------------------------------------------------------------- cluster xyz sums + denom (raw)
__global__ void cluster_xyz_kernel(const float* __restrict__ s, const float* __restrict__ xyz,
                                   float* __restrict__ outx, float* __restrict__ outd,
                                   int N, int Kc, int xBS, int dBS){
    __shared__ float red[256];
    int b = blockIdx.y, k = blockIdx.x, t = threadIdx.x;
    s   += (long)b*N*Kc;
    xyz += (long)b*N*3;
    float a0=0,a1=0,a2=0,ad=0;
    for (int n = t; n < N; n += 256){
        float sv = s[(long)n*Kc + k];
        ad += sv;
        a0 += sv*xyz[n*3+0]; a1 += sv*xyz[n*3+1]; a2 += sv*xyz[n*3+2];
    }
    a0 = blockReduceSum(a0, red, 256);
    a1 = blockReduceSum(a1, red, 256);
    a2 = blockReduceSum(a2, red, 256);
    ad = blockReduceSum(ad, red, 256);
    if (t == 0){
        outx[b*xBS + k*3+0] = a0;
        outx[b*xBS + k*3+1] = a1;
        outx[b*xBS + k*3+2] = a2;
        outd[b*dBS + k] = ad;
    }
}

// ---------------------------------------------------------------- f32 sTX for tiny global stage (split over n)
__global__ __launch_bounds__(256) void gemm_sTX_kernel(const float* __restrict__ s,
                                                       const float* __restrict__ X,
                                                       float* __restrict__ part,
                                                       int N, int Kc, int split,
                                                       long sBS, long xBS){
    __shared__ float sa[32][65], sb[32][65];
    int tid = threadIdx.x, tx = tid & 15, ty = tid >> 4;
    int c0 = blockIdx.x * 64;
    int b = blockIdx.z / split, chunk = blockIdx.z % split;
    int L = N / split, nst = chunk * L;
    s += b*sBS; X += b*xBS;
    float* out = part + (long)blockIdx.z * Kc * 256;
    float acc[4][4] = {};
    for (int nt = nst; nt < nst + L; nt += 32){
        #pragma unroll
        for (int p = 0; p < 8; ++p){
            int idx = p*256 + tid;
            int i = idx & 63, k = idx >> 6;
            sa[k][i] = (i < Kc) ? s[(long)(nt+k)*Kc + i] : 0.f;
            int j = idx & 63, kk = idx >> 6;
            sb[kk][j] = X[(long)(nt+kk)*256 + c0 + j];
        }
        __syncthreads();
        #pragma unroll
        for (int k = 0; k < 32; ++k){
            float a0=sa[k][ty*4+0],a1=sa[k][ty*4+1],a2=sa[k][ty*4+2],a3=sa[k][ty*4+3];
            float b0=sb[k][tx*4+0],b1=sb[k][tx*4+1],b2=sb[k][tx*4+2],b3=sb[k][tx*4+3];
            acc[0][0]+=a0*b0; acc[0][1]+=a0*b1; acc[0][2]+=a0*b2; acc[0][3]+=a0*b3;
            acc[1][0]+=a1*b0; acc[1][1]+=a1*b1; acc[1][2]+=a1*b2; acc[1][3]+=a1*b3;
            acc[2][0]+=a2*b0; acc[2][1]+=a2*b1; acc[2][2]+=a2*b2; acc[2][3]+=a2*b3;
            acc[3][0]+=a3*b0; acc[3][1]+=a3*b1; acc[3][2]+=a3*b2; acc[3][3]+=a3*b3;
        }
        __syncthreads();
    }
    #pragma unroll
    for (int r = 0; r < 4; ++r){
        int kc = ty*4 + r;
        if (kc < Kc){
            #pragma unroll
            for (int c = 0; c < 4; ++c)
                out[(long)kc*256 + c0 + tx*4 + c] = acc[r][c];
        }
    }
}

// ---------------------------------------------------------------- sum partials, divide by denom
__global__ void divide_sum_kernel(const float* __restrict__ part, const float* __restrict__ den,
                                  float* __restrict__ cfea, float* __restrict__ cxyz,
                                  int Kc, int split, int fBS, int xBS, int dBS){
    int b = blockIdx.y, k = blockIdx.x, t = threadIdx.x;
    float d = den[b*dBS + k] + EPSF;
    float s = 0.f;
    for (int q = 0; q < split; ++q)
        s += part[((long)(b*split+q)*Kc + k)*256 + t];
    cfea[(long)b*fBS + k*256 + t] = s / d;
    if (t < 3) cxyz[b*xBS + k*3 + t] /= d;
}

// ---------------------------------------------------------------- level losses: wave per point, cfea staged in LDS
__global__ __launch_bounds__(256) void level_loss_kernel(const float* __restrict__ s,
                                                         const float* __restrict__ pxyz,
                                                         const float* __restrict__ cxyz,
                                                         const float* __restrict__ cfea,
                                                         const unsigned short* __restrict__ nfb,
                                                         float* __restrict__ scal,
                                                         int N, float inv, int ndsSlot){
    __shared__ float cf[64*256];
    __shared__ float cx[192];
    __shared__ float partA[4], partN[4];
    int b = blockIdx.y, t = threadIdx.x, w = t >> 6, l = t & 63;
    s    += (long)b*N*64;
    pxyz += (long)b*N*3;
    nfb  += (long)b*N*256;
    cxyz += (long)b*384;
    cfea += (long)b*32768;
    for (int i = t; i < 4096; i += 256)
        ((float4*)cf)[i] = ((const float4*)cfea)[i];
    if (t < 192) cx[t] = cxyz[t];
    __syncthreads();
    int n = blockIdx.x*4 + w;
    float sl = s[(long)n*64 + l];
    float px = pxyz[n*3+0], py = pxyz[n*3+1], pz = pxyz[n*3+2];
    float dx = px - cx[l*3+0], dy = py - cx[l*3+1], dz = pz - cx[l*3+2];
    float d2 = dx*dx + dy*dy + dz*dz;
    float assSum = waveSum(sl*d2);
    float dmin = waveMin(d2);
    float c0=0,c1=0,c2=0,c3=0;
    #pragma unroll 8
    for (int k = 0; k < 64; ++k){
        float sk = __shfl(sl, k, 64);
        const float* row = cf + k*256;
        c0 += sk*row[l]; c1 += sk*row[l+64]; c2 += sk*row[l+128]; c3 += sk*row[l+192];
    }
    float nrm2 = waveSum(c0*c0 + c1*c1 + c2*c2 + c3*c3);
    float inrm = 1.f / fmaxf(sqrtf(nrm2), 1e-12f);
    const unsigned short* nfr = nfb + (long)n*256;
    float e0 = c0*inrm - bf2f(nfr[l]);
    float e1 = c1*inrm - bf2f(nfr[l+64]);
    float e2 = c2*inrm - bf2f(nfr[l+128]);
    float e3 = c3*inrm - bf2f(nfr[l+192]);
    float nds = waveSum(e0*e0 + e1*e1 + e2*e2 + e3*e3);
    if (l == 0){
        partA[w] = inv*(assSum + 1.f - expf(-0.5f*dmin));
        partN[w] = nds;
    }
    __syncthreads();
    if (t == 0){
        int slot = blockIdx.x & 63;
        atomicAdd(&scal[slot], partA[0]+partA[1]+partA[2]+partA[3]);
        atomicAdd(&scal[ndsSlot*64 + slot], partN[0]+partN[1]+partN[2]+partN[3]);
    }
}

// ---------------------------------------------------------------- knn affinity -> normalized adjacency, fully in LDS
__global__ __launch_bounds__(128) void knn_nac_kernel(const float* __restrict__ cxyz,
                                                      float* __restrict__ nac){
    __shared__ float d2s[128][129];
    __shared__ float x[128][3];
    __shared__ float di[128];
    int b = blockIdx.x, n = threadIdx.x;
    x[n][0] = cxyz[b*384 + n*3+0];
    x[n][1] = cxyz[b*384 + n*3+1];
    x[n][2] = cxyz[b*384 + n*3+2];
    __syncthreads();
    float xn0 = x[n][0], xn1 = x[n][1], xn2 = x[n][2];
    for (int m = 0; m < 128; ++m){
        float dx = xn0-x[m][0], dy = xn1-x[m][1], dz = xn2-x[m][2];
        d2s[n][m] = dx*dx+dy*dy+dz*dz + (m==n ? 1e6f : 0.f);
    }
    float last = -1.f;
    for (int p = 0; p < 8; ++p){
        float cur = 1e30f;
        for (int m = 0; m < 128; ++m){
            float v = d2s[n][m];
            if (v > last && v < cur) cur = v;
        }
        last = cur;
    }
    for (int m = 0; m < 128; ++m){
        float d2 = d2s[n][m];
        d2s[n][m] = (m != n && d2 <= last) ? expf(-d2) : 0.f;
    }
    __syncthreads();
    for (int m = 0; m < 128; ++m){
        float v = fmaxf(d2s[n][m], d2s[m][n]);
        d2s[n][m] = v;
    }
    __syncthreads();
    float deg = 0.f;
    for (int m = 0; m < 128; ++m) deg += d2s[n][m];
    di[n] = rsqrtf(deg + EPSF);
    __syncthreads();
    float* Ab = nac + (long)b*16384;
    for (int c = 0; c < 128; ++c)
        Ab[c*128 + n] = d2s[c][n] * di[c] * di[n];
}

// ---------------------------------------------------------------- Y2 = na_c @ cfea
__global__ void bmm_small_kernel(const float* __restrict__ nac, const float* __restrict__ cfea,
                                 float* __restrict__ Y2){
    __shared__ float row[128];
    int b = blockIdx.y, n = blockIdx.x, t = threadIdx.x;
    if (t < 128) row[t] = nac[(long)b*16384 + n*128 + t];
    __syncthreads();
    float acc = 0.f;
    #pragma unroll 4
    for (int k = 0; k < 128; ++k) acc += row[k]*cfea[(long)b*32768 + k*256 + t];
    Y2[(long)b*32768 + n*256 + t] = acc;
}

// ---------------------------------------------------------------- cut_loss_c
__global__ void cutc_kernel(const float* __restrict__ gs, const float* __restrict__ cxyz,
                            const float* __restrict__ cxyzg, float* __restrict__ scal, float inv){
    __shared__ float cg[48];
    __shared__ float red[128];
    int b = blockIdx.x, t = threadIdx.x;
    if (t < 48) cg[t] = cxyzg[b*48 + t];
    __syncthreads();
    float x0 = cxyz[b*384 + t*3+0], x1 = cxyz[b*384 + t*3+1], x2 = cxyz[b*384 + t*3+2];
    float acc = 0.f;
    #pragma unroll
    for (int k = 0; k < 16; ++k){
        float dx = x0-cg[k*3+0], dy = x1-cg[k*3+1], dz = x2-cg[k*3+2];
        acc += gs[b*2048 + t*16 + k]*(dx*dx+dy*dy+dz*dz);
    }
    acc = blockReduceSum(acc, red, 128);
    if (t == 0) atomicAdd(&scal[b], acc*inv);
}

// ---------------------------------------------------------------- cross attention (M=16) -> AO bf16
__global__ __launch_bounds__(256) void attn_kernel(const float* __restrict__ q,
                                                   const float* __restrict__ kk,
                                                   const float* __restrict__ vv,
                                                   unsigned short* __restrict__ aob){
    __shared__ float Ks[16][256], Vs[16][256];
    int b = blockIdx.y, n = blockIdx.x, t = threadIdx.x;
    #pragma unroll
    for (int p = 0; p < 16; ++p){
        int j = p*256 + t;
        Ks[j>>8][j&255] = kk[b*4096 + j];
        Vs[j>>8][j&255] = vv[b*4096 + j];
    }
    __syncthreads();
    float qv = q[((long)b*1024 + n)*256 + t];
    float sc[16];
    #pragma unroll
    for (int m = 0; m < 16; ++m){
        float v = qv * Ks[m][t];
        #pragma unroll
        for (int o = 32; o; o >>= 1) v += __shfl_xor(v, o, 64);
        sc[m] = v * 0.125f;
    }
    float mx = -1e30f;
    #pragma unroll
    for (int m = 0; m < 16; ++m) mx = fmaxf(mx, sc[m]);
    float sum = 0.f;
    #pragma unroll
    for (int m = 0; m < 16; ++m){ sc[m] = expf(sc[m]-mx); sum += sc[m]; }
    float o = 0.f;
    #pragma unroll
    for (int m = 0; m < 16; ++m) o += sc[m]*Vs[m][t];
    aob[((long)b*1024 + n)*256 + t] = f2bf(o / sum);
}

// ---------------------------------------------------------------- quad: wave per row, bf16 A (N=1024), deg-based
__global__ void quad_kernel(const unsigned short* __restrict__ A, const float* __restrict__ deg,
                            const float* __restrict__ xyz, float* __restrict__ scal){
    __shared__ float part[4];
    int t = threadIdx.x, w = t >> 6, l = t & 63;
    int n = blockIdx.x*4 + w;
    float a0=0,a1=0,a2=0;
    #pragma unroll 4
    for (int i = 0; i < 16; ++i){
        int m = l + i*64;
        float wv = bf2f(A[(long)n*1024 + m])*rsqrtf(deg[m] + EPSF);
        a0 += wv*xyz[m*3+0]; a1 += wv*xyz[m*3+1]; a2 += wv*xyz[m*3+2];
    }
    a0 = waveSum(a0); a1 = waveSum(a1); a2 = waveSum(a2);
    if (l == 0){
        float x0 = xyz[n*3+0], x1 = xyz[n*3+1], x2 = xyz[n*3+2];
        float dn = rsqrtf(deg[n] + EPSF);
        part[w] = (x0*x0+x1*x1+x2*x2) - dn*(x0*a0+x1*a1+x2*a2);
    }
    __syncthreads();
    if (t == 0) atomicAdd(&scal[4*64 + (blockIdx.x & 63)], part[0]+part[1]+part[2]+part[3]);
}

// ---------------------------------------------------------------- g_loss per-row: wave per row
__global__ void gloss_kernel(const float* __restrict__ agg, const float* __restrict__ gfea,
                             float* __restrict__ scal){
    __shared__ float part[4];
    int t = threadIdx.x, w = t >> 6, l = t & 63;
    long r = (long)blockIdx.x*4 + w;
    const float* a = agg + r*256;
    const float* g = gfea + r*256;
    float a0=a[l],a1=a[l+64],a2=a[l+128],a3=a[l+192];
    float g0=g[l],g1=g[l+64],g2=g[l+128],g3=g[l+192];
    float na2 = waveSum(a0*a0+a1*a1+a2*a2+a3*a3);
    float ng2 = waveSum(g0*g0+g1*g1+g2*g2+g3*g3);
    float ia = 1.f/fmaxf(sqrtf(na2), 1e-12f), ig = 1.f/fmaxf(sqrtf(ng2), 1e-12f);
    float e0=a0*ia-g0*ig, e1=a1*ia-g1*ig, e2=a2*ia-g2*ig, e3=a3*ia-g3*ig;
    float d2 = waveSum(e0*e0+e1*e1+e2*e2+e3*e3);
    if (l == 0) part[w] = sqrtf(d2);
    __syncthreads();
    if (t == 0) atomicAdd(&scal[3*64 + (blockIdx.x & 63)], part[0]+part[1]+part[2]+part[3]);
}

// ---------------------------------------------------------------- finalize
__global__ void finalize_kernel(const float* __restrict__ scal, float* __restrict__ out){
    int t = threadIdx.x;
    float s[5];
    #pragma unroll
    for (int q = 0; q < 5; ++q){
        float v = scal[q*64 + t];
        #pragma unroll
        for (int o = 32; o; o >>= 1) v += __shfl_xor(v, o, 64);
        s[q] = v;
    }
    if (t == 0){
        out[524288] = s[0] + sqrtf(s[1]) + sqrtf(s[2]);
        out[524289] = s[3]*0.5f + 1e-4f*s[4]/2048.0f;
    }
}

// ================================================================ launcher
extern "C" void kernel_launch(void* const* d_in, const int* in_sizes, int n_in,
                              void* d_out, int out_size, void* d_ws, size_t ws_size,
                              hipStream_t stream){
    const float* g_fea   = (const float*)d_in[0];
    const float* g_xyz   = (const float*)d_in[1];
    const float* p_fea_0 = (const float*)d_in[2];
    const float* p_xyz_0 = (const float*)d_in[3];
    const float* p_fea_1 = (const float*)d_in[4];
    const float* p_xyz_1 = (const float*)d_in[5];
    const float* lW1 = (const float*)d_in[6];
    const float* lb1 = (const float*)d_in[7];
    const float* lW2 = (const float*)d_in[8];
    const float* lb2 = (const float*)d_in[9];
    const float* gW1 = (const float*)d_in[10];
    const float* gb1 = (const float*)d_in[11];
    const float* gW2 = (const float*)d_in[12];
    const float* gb2 = (const float*)d_in[13];
    const float* Wq = (const float*)d_in[14];
    const float* Wk = (const float*)d_in[15];
    const float* Wv = (const float*)d_in[16];
    const float* Wo = (const float*)d_in[17];
    float* out = (float*)d_out;
    float* ws_f = (float*)d_ws;

    // ---- workspace layout (float units)
    constexpr long O_SCALS = 0;                        // 512
    constexpr long O_DEG   = 512;                      // 14336
    constexpr long O_CFEA  = 16384;                    // 65536
    constexpr long O_CXYZ  = 81920;                    // 768
    constexpr long O_DEN   = 82688;                    // 256
    constexpr long O_CFG   = 82944;                    // 8192
    constexpr long O_CXG   = 91136;                    // 96
    constexpr long O_DENG  = 91232;                    // 64
    constexpr long O_NFB   = 91296;                    // bf16 (12288,256) = 1,572,864 f
    constexpr long O_XST   = O_NFB  + 1572864;         // bf16 (2,256,4096) reuse = 1,048,576 f
    constexpr long O_FEAT  = O_XST  + 1048576;         // bf16 both levels = 1,572,864 f
    constexpr long O_YB    = O_FEAT + 1572864;         // bf16 (12288,256) = 1,572,864 f
    constexpr long O_HB    = O_YB   + 1572864;         // bf16 (12288,128) = 786,432 f
    constexpr long O_S     = O_HB   + 786432;          // f32 (12288,64) = 786,432 f
    constexpr long O_ST    = O_S    + 786432;          // bf16 (64,12288) = 393,216 f
    constexpr long O_PY    = O_ST   + 393216;          // f32 8*(4096,256) = 8,388,608 f (also "part")
    constexpr long O_A     = O_PY   + 8388608;         // bf16 (4096,4096) = 8,388,608 f
    constexpr long O_Q     = O_A    + 8388608;         // 524288
    constexpr long O_GFB   = O_Q    + 524288;          // 262144
    constexpr long O_AOB   = O_GFB  + 262144;          // 262144
    constexpr long O_KK    = O_AOB  + 262144;          // 8192
    constexpr long O_VV    = O_KK   + 8192;            // 8192
    constexpr long O_NAC   = O_VV   + 8192;            // 32768
    constexpr long O_Y2    = O_NAC  + 32768;           // 65536
    constexpr long O_H2    = O_Y2   + 65536;           // 32768
    constexpr long O_LG2   = O_H2   + 32768;           // 4096
    constexpr long O_W1T   = O_LG2  + 4096;            // 16384
    constexpr long O_W2T   = O_W1T  + 16384;           // 4096
    constexpr long O_WQT   = O_W2T  + 4096;            // 32768
    constexpr long O_WOT   = O_WQT  + 32768;           // 32768

    hipMemsetAsync(ws_f + O_SCALS, 0, (512 + 14336)*sizeof(float), stream);

    unsigned short* nfb  = (unsigned short*)(ws_f + O_NFB);
    unsigned short* xsT  = (unsigned short*)(ws_f + O_XST);
    unsigned short* feaT = (unsigned short*)(ws_f + O_FEAT);
    unsigned short* Ybb  = (unsigned short*)(ws_f + O_YB);
    unsigned short* Hb   = (unsigned short*)(ws_f + O_HB);
    unsigned short* sTb  = (unsigned short*)(ws_f + O_ST);
    unsigned short* A    = (unsigned short*)(ws_f + O_A);
    unsigned short* gfb  = (unsigned short*)(ws_f + O_GFB);
    unsigned short* aob  = (unsigned short*)(ws_f + O_AOB);
    unsigned short* lW1T = (unsigned short*)(ws_f + O_W1T);
    unsigned short* lW2T = (unsigned short*)(ws_f + O_W2T);
    unsigned short* WqT  = (unsigned short*)(ws_f + O_WQT);
    unsigned short* WoT  = (unsigned short*)(ws_f + O_WOT);
    float* sb   = ws_f + O_S;
    float* degA = ws_f + O_DEG;
    float* PY   = ws_f + O_PY;   // doubles as split-K "part" scratch after combine
    float* Qf   = ws_f + O_Q;

    // weight conversions
    tcvt_kernel<<<dim3(4, 2), 256, 0, stream>>>(lW1, lW1T, 256, 128);
    tcvt_kernel<<<dim3(2, 1), 256, 0, stream>>>(lW2, lW2T, 128, 64);
    tcvt_kernel<<<dim3(4, 4), 256, 0, stream>>>(Wq, WqT, 256, 256);
    tcvt_kernel<<<dim3(4, 4), 256, 0, stream>>>(Wo, WoT, 256, 256);
    cvt_bf16_kernel<<<512, 256, 0, stream>>>(g_fea, gfb, 131072);

    struct Lvl { const float* fea; const float* xyz; int N; int k0; int ndsSlot; long degBase;
                 long rowOff; long featOff; };
    Lvl lv[2] = {{p_fea_0, p_xyz_0, 4096, 0, 1, 0, 0, 0},
                 {p_fea_1, p_xyz_1, 2048, 64, 2, 8192, 8192, 2097152}};

    // ---- phase 1: gram + GCN-aggregate for all (level, batch)
    for (int L = 0; L < 2; ++L){
        int N = lv[L].N;
        const float* fea = lv[L].fea;
        const float* xyz = lv[L].xyz;
        unsigned short* nfbL  = nfb + lv[L].rowOff*256;
        unsigned short* feaTL = feaT + lv[L].featOff;
        l2norm_kernel<<<2*N, 256, 0, stream>>>(fea, nfbL, 2*N);
        for (int b = 0; b < 2; ++b){
            float* degb = degA + lv[L].degBase + (long)b*N;
            gram_mfma_kernel<<<dim3(N/128, N/128), 256, 0, stream>>>(nfbL + (long)b*N*256,
                                                                     xyz + (long)b*N*3, A, degb,
                                                                     N, 1.0f, 0.25f);
            transpose_scale_kernel<<<dim3(N/64, 4), 256, 0, stream>>>(fea + (long)b*N*256, degb,
                                                                      feaTL + (long)b*256*N,
                                                                      xsT + (long)b*256*N, N);
            ax_mfma_kernel<<<dim3(4, N/128, 8), 256, 0, stream>>>(A, xsT + (long)b*256*N, PY, N, 8);
            combine_kernel<<<N/8, 256, 0, stream>>>(PY, degb,
                                                    Ybb + (lv[L].rowOff + (long)b*N)*256, N, 8);
        }
    }

    // ---- phase 2: fused MLP over all 12288 rows
    gemm_XW_mfma_kernel<<<dim3(1, 96), 256, 0, stream>>>(Ybb, lW1T, lb1, nullptr, Hb,
                                                         12288, 256, 128, 1);
    gemm_XW_mfma_kernel<<<dim3(1, 96), 256, 0, stream>>>(Hb, lW2T, lb2, sb, nullptr,
                                                         12288, 128, 64, 0);
    softmaxT_kernel<<<192, 256, 0, stream>>>(sb, sTb, 12288, 10.0f);

    // ---- phase 3: per-level cluster stats + losses
    for (int L = 0; L < 2; ++L){
        int N = lv[L].N;
        const float* xyz = lv[L].xyz;
        float* sL = sb + lv[L].rowOff*64;
        cluster_xyz_kernel<<<dim3(64, 2), 256, 0, stream>>>(sL, xyz, ws_f + O_CXYZ + lv[L].k0*3,
                                                            ws_f + O_DEN + lv[L].k0, N, 64, 384, 128);
        stx_mfma_kernel<<<32, 256, 0, stream>>>(sTb + lv[L].rowOff, feaT + lv[L].featOff,
                                                PY, N, 16, 12288);
        divide_sum_kernel<<<dim3(64, 2), 256, 0, stream>>>(PY, ws_f + O_DEN + lv[L].k0,
                                                           ws_f + O_CFEA + lv[L].k0*256,
                                                           ws_f + O_CXYZ + lv[L].k0*3,
                                                           64, 16, 128*256, 384, 128);
        level_loss_kernel<<<dim3(N/4, 2), 256, 0, stream>>>(sL, xyz, ws_f + O_CXYZ + lv[L].k0*3,
                                                            ws_f + O_CFEA + lv[L].k0*256,
                                                            nfb + lv[L].rowOff*256,
                                                            ws_f + O_SCALS, N, 1.0f/(2.0f*N), lv[L].ndsSlot);
    }

    // ---- global cluster stage
    knn_nac_kernel<<<2, 128, 0, stream>>>(ws_f + O_CXYZ, ws_f + O_NAC);
    bmm_small_kernel<<<dim3(128, 2), 256, 0, stream>>>(ws_f + O_NAC, ws_f + O_CFEA, ws_f + O_Y2);
    gemm_splitk_kernel<<<dim3(2, 4, 4), 256, 0, stream>>>(ws_f + O_Y2, gW1, nullptr, PY,
                                                          256, 256, 128, 4);
    combine_bias_kernel<<<128, 256, 0, stream>>>(PY, gb1, ws_f + O_H2, 256, 128, 4, 1);
    gemm_splitk_kernel<<<dim3(1, 4, 4), 256, 0, stream>>>(ws_f + O_H2, gW2, nullptr, PY,
                                                          256, 128, 16, 4);
    combine_bias_kernel<<<16, 256, 0, stream>>>(PY, gb2, ws_f + O_LG2, 256, 16, 4, 0);
    softmax_kernel<<<256, 64, 0, stream>>>(ws_f + O_LG2, 16, 0.1f);
    cluster_xyz_kernel<<<dim3(16, 2), 256, 0, stream>>>(ws_f + O_LG2, ws_f + O_CXYZ,
                                                        ws_f + O_CXG, ws_f + O_DENG, 128, 16, 48, 16);
    gemm_sTX_kernel<<<dim3(4, 1, 8), 256, 0, stream>>>(ws_f + O_LG2, ws_f + O_CFEA, PY,
                                                       128, 16, 4, 128L*16, 128L*256);
    divide_sum_kernel<<<dim3(16, 2), 256, 0, stream>>>(PY, ws_f + O_DENG, ws_f + O_CFG,
                                                       ws_f + O_CXG, 16, 4, 16*256, 48, 16);
    cutc_kernel<<<2, 128, 0, stream>>>(ws_f + O_LG2, ws_f + O_CXYZ, ws_f + O_CXG,
                                       ws_f + O_SCALS, 1.0f/256.0f);

    // ---- cross attention
    gemm_XW_mfma_kernel<<<dim3(2, 16), 256, 0, stream>>>(gfb, WqT, nullptr, Qf, nullptr,
                                                         2048, 256, 256, 0);
    gemm_splitk_kernel<<<dim3(4, 1, 16), 256, 0, stream>>>(ws_f + O_CFG, Wk, Wv, PY,
                                                           32, 256, 256, 8);
    combine_bias_kernel<<<32, 256, 0, stream>>>(PY, nullptr, ws_f + O_KK, 32, 256, 8, 0);
    combine_bias_kernel<<<32, 256, 0, stream>>>(PY + 8L*32*256, nullptr, ws_f + O_VV, 32, 256, 8, 0);
    attn_kernel<<<dim3(1024, 2), 256, 0, stream>>>(Qf, ws_f + O_KK, ws_f + O_VV, aob);
    gemm_XW_mfma_kernel<<<dim3(2, 16), 256, 0, stream>>>(aob, WoT, nullptr, out, nullptr,
                                                         2048, 256, 256, 0);

    // ---- A_g stage (reuses nfb head + A + deg tail)
    l2norm_kernel<<<2048, 256, 0, stream>>>(g_fea, nfb, 2048);
    for (int b = 0; b < 2; ++b){
        float* degb = degA + 12288 + (long)b*1024;
        gram_mfma_kernel<<<dim3(8, 8), 256, 0, stream>>>(nfb + (long)b*1024*256, g_xyz + (long)b*1024*3,
                                                         A, degb, 1024, 16.0f, 0.25f);
        quad_kernel<<<256, 256, 0, stream>>>(A, degb, g_xyz + (long)b*1024*3, ws_f + O_SCALS);
    }

    gloss_kernel<<<512, 256, 0, stream>>>(out, g_fea, ws_f + O_SCALS);
    finalize_kernel<<<1, 64, 0, stream>>>(ws_f + O_SCALS, out);
}

// Round 8
// 739.122 us; speedup vs baseline: 3.2097x; 1.0239x over previous
//
#include <hip/hip_runtime.h>

#define EPSF 1e-4f

typedef __attribute__((ext_vector_type(8))) short bf16x8;
typedef __attribute__((ext_vector_type(4))) float f32x4;

__device__ __forceinline__ unsigned short f2bf(float f){
    unsigned int u = __float_as_uint(f);
    return (unsigned short)((u + 0x7FFF + ((u >> 16) & 1)) >> 16);
}
__device__ __forceinline__ float bf2f(unsigned short u){
    return __uint_as_float(((unsigned int)u) << 16);
}
__device__ __forceinline__ float waveSum(float v){
    #pragma unroll
    for (int o = 32; o; o >>= 1) v += __shfl_xor(v, o, 64);
    return v;
}
__device__ __forceinline__ float waveMin(float v){
    #pragma unroll
    for (int o = 32; o; o >>= 1) v = fminf(v, __shfl_xor(v, o, 64));
    return v;
}
__device__ __forceinline__ float waveMax(float v){
    #pragma unroll
    for (int o = 32; o; o >>= 1) v = fmaxf(v, __shfl_xor(v, o, 64));
    return v;
}
__device__ __forceinline__ float blockReduceSum(float v, float* red, int nthr){
    int t = threadIdx.x;
    red[t] = v; __syncthreads();
    for (int s = nthr >> 1; s > 0; s >>= 1){
        if (t < s) red[t] += red[t + s];
        __syncthreads();
    }
    float r = red[0]; __syncthreads();
    return r;
}

// ---------------------------------------------------------------- l2norm rows of 256 -> bf16
__global__ void l2norm_kernel(const float* __restrict__ x, unsigned short* __restrict__ outb, int rows){
    __shared__ float red[256];
    int row = blockIdx.x, t = threadIdx.x;
    float v = x[(long)row*256 + t];
    float s = blockReduceSum(v*v, red, 256);
    float nrm = fmaxf(sqrtf(s), 1e-12f);
    outb[(long)row*256 + t] = f2bf(v / nrm);
}

// ---------------------------------------------------------------- flat f32 -> bf16
__global__ void cvt_bf16_kernel(const float* __restrict__ in, unsigned short* __restrict__ out, long n4){
    long i = (long)blockIdx.x*256 + threadIdx.x;
    if (i < n4){
        float4 v = ((const float4*)in)[i];
        unsigned int lo = f2bf(v.x) | ((unsigned int)f2bf(v.y) << 16);
        unsigned int hi = f2bf(v.z) | ((unsigned int)f2bf(v.w) << 16);
        uint2 u; u.x = lo; u.y = hi;
        ((uint2*)out)[i] = u;
    }
}

// ---------------------------------------------------------------- transpose+cvt weight: W(Rw,Cw) -> WT(Cw,Rw) bf16
__global__ void tcvt_kernel(const float* __restrict__ W, unsigned short* __restrict__ WT,
                            int Rw, int Cw){
    __shared__ float tile[64][65];
    int r0 = blockIdx.x*64, c0 = blockIdx.y*64;
    int t = threadIdx.x;
    for (int idx = t; idx < 4096; idx += 256){
        int rr = idx >> 6, cc = idx & 63;
        tile[rr][cc] = (r0+rr < Rw && c0+cc < Cw) ? W[(long)(r0+rr)*Cw + c0+cc] : 0.f;
    }
    __syncthreads();
    for (int idx = t; idx < 4096; idx += 256){
        int cc = idx >> 6, rr = idx & 63;
        if (r0+rr < Rw && c0+cc < Cw)
            WT[(long)(c0+cc)*Rw + r0+rr] = f2bf(tile[rr][cc]);
    }
}

// ---------------------------------------------------------------- MFMA gram (pad-40 LDS): A + fused degree sums
__global__ __launch_bounds__(256) void gram_mfma_kernel(const unsigned short* __restrict__ nf,
                                                        const float* __restrict__ xyz,
                                                        unsigned short* __restrict__ A,
                                                        float* __restrict__ deg,
                                                        int N, float r2, float scale){
    __shared__ short tA[128*40], tB[128*40];
    __shared__ float xa[384], xb[384];
    int tid = threadIdx.x;
    int n0 = blockIdx.y*128, m0 = blockIdx.x*128;
    for (int i = tid; i < 384; i += 256){ xa[i] = xyz[n0*3 + i]; xb[i] = xyz[m0*3 + i]; }
    int w = tid >> 6, l = tid & 63;
    int wy = w >> 1, wx = w & 1;
    int lg = l >> 4, lr = l & 15;
    int srow = tid >> 2, sc = tid & 3;
    f32x4 zero = {0.f, 0.f, 0.f, 0.f};
    f32x4 acc[4][4];
    #pragma unroll
    for (int i = 0; i < 4; ++i)
        #pragma unroll
        for (int j = 0; j < 4; ++j) acc[i][j] = zero;
    for (int kt = 0; kt < 256; kt += 32){
        __syncthreads();
        #pragma unroll
        for (int p = 0; p < 2; ++p){
            int row = srow + p*64;
            uint4 va = *(const uint4*)(nf + (long)(n0+row)*256 + kt + sc*8);
            uint4 vb = *(const uint4*)(nf + (long)(m0+row)*256 + kt + sc*8);
            *(uint4*)(tA + row*40 + sc*8) = va;
            *(uint4*)(tB + row*40 + sc*8) = vb;
        }
        __syncthreads();
        bf16x8 af[4], bfr[4];
        #pragma unroll
        for (int f = 0; f < 4; ++f){
            af[f]  = *(const bf16x8*)(tA + (wy*64 + f*16 + lr)*40 + lg*8);
            bfr[f] = *(const bf16x8*)(tB + (wx*64 + f*16 + lr)*40 + lg*8);
        }
        #pragma unroll
        for (int i = 0; i < 4; ++i)
            #pragma unroll
            for (int j = 0; j < 4; ++j)
                acc[i][j] = __builtin_amdgcn_mfma_f32_16x16x32_bf16(af[i], bfr[j], acc[i][j], 0, 0, 0);
    }
    #pragma unroll
    for (int fi = 0; fi < 4; ++fi){
        #pragma unroll
        for (int r = 0; r < 4; ++r){
            int n_ = wy*64 + fi*16 + lg*4 + r;
            int gn = n0 + n_;
            float rowacc = 0.f;
            #pragma unroll
            for (int fj = 0; fj < 4; ++fj){
                int m_ = wx*64 + fj*16 + lr;
                float dx = xa[n_*3+0]-xb[m_*3+0];
                float dy = xa[n_*3+1]-xb[m_*3+1];
                float dz = xa[n_*3+2]-xb[m_*3+2];
                float d2x = dx*dx + dy*dy + dz*dz;
                int gm = m0 + m_;
                float dot = acc[fi][fj][r];
                float val = (d2x < r2 && gn != gm) ? expf(scale*(2.f*dot - 2.f)) : 0.f;
                A[(long)gn*N + gm] = f2bf(val);
                rowacc += val;
            }
            rowacc += __shfl_xor(rowacc, 1, 64);
            rowacc += __shfl_xor(rowacc, 2, 64);
            rowacc += __shfl_xor(rowacc, 4, 64);
            rowacc += __shfl_xor(rowacc, 8, 64);
            if (lr == 0) atomicAdd(&deg[gn], rowacc);
        }
    }
}

// ---------------------------------------------------------------- feaT / xsT transpose+scale
__global__ __launch_bounds__(256) void transpose_scale_kernel(const float* __restrict__ fea,
                                                              const float* __restrict__ deg,
                                                              unsigned short* __restrict__ feaT,
                                                              unsigned short* __restrict__ xsT, int N){
    __shared__ float tile[64][65];
    __shared__ float dl[64];
    int m0 = blockIdx.x*64, c0 = blockIdx.y*64;
    int t = threadIdx.x;
    int lr = t >> 2, lc = (t & 3)*16;
    #pragma unroll
    for (int j = 0; j < 4; ++j){
        float4 v = *(const float4*)(fea + (long)(m0+lr)*256 + c0 + lc + j*4);
        tile[lr][lc+j*4+0] = v.x; tile[lr][lc+j*4+1] = v.y;
        tile[lr][lc+j*4+2] = v.z; tile[lr][lc+j*4+3] = v.w;
    }
    if (t < 64) dl[t] = rsqrtf(deg[m0+t] + EPSF);
    __syncthreads();
    unsigned short vr[16] __attribute__((aligned(16)));
    unsigned short vs[16] __attribute__((aligned(16)));
    #pragma unroll
    for (int j = 0; j < 16; ++j){
        float raw = tile[lc+j][lr];
        vr[j] = f2bf(raw);
        vs[j] = f2bf(raw * dl[lc+j]);
    }
    long off = (long)(c0+lr)*N + m0 + lc;
    *(uint4*)(feaT + off)     = *(uint4*)&vr[0];
    *(uint4*)(feaT + off + 8) = *(uint4*)&vr[8];
    *(uint4*)(xsT + off)      = *(uint4*)&vs[0];
    *(uint4*)(xsT + off + 8)  = *(uint4*)&vs[8];
}

// ---------------------------------------------------------------- MFMA A@XsT^T -> bf16 partials, coalesced epilogue
// 128x128 tiles, grid (2, N/128, split), pad-40 LDS, reg prefetch, LDS-staged bf16 write
__global__ __launch_bounds__(256) void ax_mfma_kernel(const unsigned short* __restrict__ A,
                                                      const unsigned short* __restrict__ xsT,
                                                      unsigned short* __restrict__ PYb, int N, int split){
    __shared__ short smem[16384];          // 32 KB: tiles (2*5120) then reused as 128x128 bf16 out
    short* tA = smem;
    short* tB = smem + 5120;
    int tid = threadIdx.x;
    int c0 = blockIdx.x*128, n0 = blockIdx.y*128;
    int chunk = blockIdx.z;
    int L = N/split, kbase = chunk*L, kend = kbase + L;
    int w = tid >> 6, l = tid & 63;
    int wy = w >> 1, wx = w & 1;
    int lg = l >> 4, lr = l & 15;
    int srow = tid >> 2, sc = tid & 3;
    f32x4 zero = {0.f, 0.f, 0.f, 0.f};
    f32x4 acc[4][4];
    #pragma unroll
    for (int i = 0; i < 4; ++i)
        #pragma unroll
        for (int j = 0; j < 4; ++j) acc[i][j] = zero;
    uint4 pva[2], pvb[2];
    #pragma unroll
    for (int p = 0; p < 2; ++p){
        int row = srow + p*64;
        pva[p] = *(const uint4*)(A   + (long)(n0+row)*N + kbase + sc*8);
        pvb[p] = *(const uint4*)(xsT + (long)(c0+row)*N + kbase + sc*8);
    }
    for (int kt = kbase; kt < kend; kt += 32){
        __syncthreads();
        #pragma unroll
        for (int p = 0; p < 2; ++p){
            int row = srow + p*64;
            *(uint4*)(tA + row*40 + sc*8) = pva[p];
            *(uint4*)(tB + row*40 + sc*8) = pvb[p];
        }
        __syncthreads();
        if (kt + 32 < kend){
            #pragma unroll
            for (int p = 0; p < 2; ++p){
                int row = srow + p*64;
                pva[p] = *(const uint4*)(A   + (long)(n0+row)*N + kt + 32 + sc*8);
                pvb[p] = *(const uint4*)(xsT + (long)(c0+row)*N + kt + 32 + sc*8);
            }
        }
        bf16x8 af[4], bfr[4];
        #pragma unroll
        for (int f = 0; f < 4; ++f){
            af[f]  = *(const bf16x8*)(tA + (wy*64 + f*16 + lr)*40 + lg*8);
            bfr[f] = *(const bf16x8*)(tB + (wx*64 + f*16 + lr)*40 + lg*8);
        }
        #pragma unroll
        for (int i = 0; i < 4; ++i)
            #pragma unroll
            for (int j = 0; j < 4; ++j)
                acc[i][j] = __builtin_amdgcn_mfma_f32_16x16x32_bf16(af[i], bfr[j], acc[i][j], 0, 0, 0);
    }
    // stage to LDS as bf16, then coalesced global write
    __syncthreads();
    unsigned short* ot = (unsigned short*)smem;   // 128 x 128
    #pragma unroll
    for (int fi = 0; fi < 4; ++fi){
        #pragma unroll
        for (int fj = 0; fj < 4; ++fj){
            #pragma unroll
            for (int r = 0; r < 4; ++r){
                int n_ = wy*64 + fi*16 + lg*4 + r;
                int c_ = wx*64 + fj*16 + lr;
                ot[n_*128 + c_] = f2bf(acc[fi][fj][r]);
            }
        }
    }
    __syncthreads();
    unsigned short* outp = PYb + (long)chunk*N*256;
    #pragma unroll
    for (int q = 0; q < 8; ++q){
        int idx = q*256 + tid;
        int row = idx >> 4, coff = (idx & 15)*8;
        *(uint4*)(outp + (long)(n0+row)*256 + c0 + coff) = *(const uint4*)(ot + row*128 + coff);
    }
}

// ---------------------------------------------------------------- Yb(bf16) = rsqrt(deg[n])*sum_split(PYb bf16)
__global__ void combine_kernel(const unsigned short* __restrict__ PYb, const float* __restrict__ deg,
                               unsigned short* __restrict__ Yb, int N, int split){
    long i = (long)blockIdx.x*256 + threadIdx.x;
    long e = i*8;
    float s[8] = {0,0,0,0,0,0,0,0};
    for (int q = 0; q < split; ++q){
        uint4 u = *(const uint4*)(PYb + (long)q*N*256 + e);
        unsigned int ww[4] = {u.x, u.y, u.z, u.w};
        #pragma unroll
        for (int j = 0; j < 4; ++j){
            s[2*j]   += __uint_as_float(ww[j] << 16);
            s[2*j+1] += __uint_as_float(ww[j] & 0xFFFF0000u);
        }
    }
    float d = rsqrtf(deg[e >> 8] + EPSF);
    unsigned short vb[8] __attribute__((aligned(16)));
    #pragma unroll
    for (int j = 0; j < 8; ++j) vb[j] = f2bf(s[j]*d);
    *(uint4*)(Yb + e) = *(uint4*)vb;
}

// ---------------------------------------------------------------- MFMA X @ WT + bias [relu] (pad-40, prefetch)
__global__ __launch_bounds__(256) void gemm_XW_mfma_kernel(const unsigned short* __restrict__ X,
                                                           const unsigned short* __restrict__ WT,
                                                           const float* __restrict__ bias,
                                                           float* __restrict__ outF,
                                                           unsigned short* __restrict__ outB,
                                                           int R, int Ci, int Co, int relu){
    __shared__ short tA[128*40], tB[128*40];
    int tid = threadIdx.x;
    int c0 = blockIdx.x*128, r0 = blockIdx.y*128;
    int w = tid >> 6, l = tid & 63;
    int wy = w >> 1, wx = w & 1;
    int lg = l >> 4, lr = l & 15;
    int srow = tid >> 2, sc = tid & 3;
    f32x4 zero = {0.f, 0.f, 0.f, 0.f};
    f32x4 acc[4][4];
    #pragma unroll
    for (int i = 0; i < 4; ++i)
        #pragma unroll
        for (int j = 0; j < 4; ++j) acc[i][j] = zero;
    uint4 pva[2], pvb[2];
    #pragma unroll
    for (int p = 0; p < 2; ++p){
        int row = srow + p*64;
        int ar = r0 + row, br = c0 + row;
        pva[p] = (ar < R)  ? *(const uint4*)(X  + (long)ar*Ci + sc*8) : (uint4){0,0,0,0};
        pvb[p] = (br < Co) ? *(const uint4*)(WT + (long)br*Ci + sc*8) : (uint4){0,0,0,0};
    }
    for (int kt = 0; kt < Ci; kt += 32){
        __syncthreads();
        #pragma unroll
        for (int p = 0; p < 2; ++p){
            int row = srow + p*64;
            *(uint4*)(tA + row*40 + sc*8) = pva[p];
            *(uint4*)(tB + row*40 + sc*8) = pvb[p];
        }
        __syncthreads();
        if (kt + 32 < Ci){
            #pragma unroll
            for (int p = 0; p < 2; ++p){
                int row = srow + p*64;
                int ar = r0 + row, br = c0 + row;
                pva[p] = (ar < R)  ? *(const uint4*)(X  + (long)ar*Ci + kt + 32 + sc*8) : (uint4){0,0,0,0};
                pvb[p] = (br < Co) ? *(const uint4*)(WT + (long)br*Ci + kt + 32 + sc*8) : (uint4){0,0,0,0};
            }
        }
        bf16x8 af[4], bfr[4];
        #pragma unroll
        for (int f = 0; f < 4; ++f){
            af[f]  = *(const bf16x8*)(tA + (wy*64 + f*16 + lr)*40 + lg*8);
            bfr[f] = *(const bf16x8*)(tB + (wx*64 + f*16 + lr)*40 + lg*8);
        }
        #pragma unroll
        for (int i = 0; i < 4; ++i)
            #pragma unroll
            for (int j = 0; j < 4; ++j)
                acc[i][j] = __builtin_amdgcn_mfma_f32_16x16x32_bf16(af[i], bfr[j], acc[i][j], 0, 0, 0);
    }
    #pragma unroll
    for (int fi = 0; fi < 4; ++fi){
        #pragma unroll
        for (int fj = 0; fj < 4; ++fj){
            #pragma unroll
            for (int r = 0; r < 4; ++r){
                int rr = r0 + wy*64 + fi*16 + lg*4 + r;
                int cc = c0 + wx*64 + fj*16 + lr;
                if (rr < R && cc < Co){
                    float v = acc[fi][fj][r] + (bias ? bias[cc] : 0.f);
                    if (relu) v = fmaxf(v, 0.f);
                    if (outF) outF[(long)rr*Co + cc] = v;
                    if (outB) outB[(long)rr*Co + cc] = f2bf(v);
                }
            }
        }
    }
}

// ---------------------------------------------------------------- split-K f32 GEMM -> partials
__global__ __launch_bounds__(256) void gemm_splitk_kernel(const float* __restrict__ X,
                                                          const float* __restrict__ W0,
                                                          const float* __restrict__ W1,
                                                          float* __restrict__ part,
                                                          int R, int Ci, int Co, int Ks){
    __shared__ float sa[32][65], sb[32][65];
    int tid = threadIdx.x, tx = tid & 15, ty = tid >> 4;
    int c0 = blockIdx.x * 64, r0 = blockIdx.y * 64;
    int z = blockIdx.z;
    const float* W = (z / Ks) ? W1 : W0;
    int kchunk = Ci / Ks, kst = (z % Ks) * kchunk;
    float acc[4][4] = {};
    for (int kt = kst; kt < kst + kchunk; kt += 32){
        #pragma unroll
        for (int p = 0; p < 8; ++p){
            int idx = p*256 + tid;
            int k = idx & 31, i = idx >> 5;
            int rr = r0 + i;
            sa[k][i] = (rr < R) ? X[(long)rr*Ci + kt + k] : 0.f;
            int j = idx & 63, kk = idx >> 6;
            int cc = c0 + j;
            sb[kk][j] = (cc < Co) ? W[(long)(kt+kk)*Co + cc] : 0.f;
        }
        __syncthreads();
        #pragma unroll
        for (int k = 0; k < 32; ++k){
            float a0=sa[k][ty*4+0],a1=sa[k][ty*4+1],a2=sa[k][ty*4+2],a3=sa[k][ty*4+3];
            float b0=sb[k][tx*4+0],b1=sb[k][tx*4+1],b2=sb[k][tx*4+2],b3=sb[k][tx*4+3];
            acc[0][0]+=a0*b0; acc[0][1]+=a0*b1; acc[0][2]+=a0*b2; acc[0][3]+=a0*b3;
            acc[1][0]+=a1*b0; acc[1][1]+=a1*b1; acc[1][2]+=a1*b2; acc[1][3]+=a1*b3;
            acc[2][0]+=a2*b0; acc[2][1]+=a2*b1; acc[2][2]+=a2*b2; acc[2][3]+=a2*b3;
            acc[3][0]+=a3*b0; acc[3][1]+=a3*b1; acc[3][2]+=a3*b2; acc[3][3]+=a3*b3;
        }
        __syncthreads();
    }
    float* outp = part + (long)z*R*Co;
    #pragma unroll
    for (int r = 0; r < 4; ++r){
        #pragma unroll
        for (int c = 0; c < 4; ++c){
            int rr = r0 + ty*4 + r, cc = c0 + tx*4 + c;
            if (rr < R && cc < Co) outp[(long)rr*Co + cc] = acc[r][c];
        }
    }
}

// ---------------------------------------------------------------- sum split-K partials + bias [+relu]
__global__ void combine_bias_kernel(const float* __restrict__ part, const float* __restrict__ bias,
                                    float* __restrict__ out, int R, int Co, int Ks, int relu){
    long i = (long)blockIdx.x*256 + threadIdx.x;
    if (i < (long)R*Co){
        long zs = (long)R*Co;
        float s = 0.f;
        for (int q = 0; q < Ks; ++q) s += part[q*zs + i];
        float v = s + (bias ? bias[i % Co] : 0.f);
        if (relu) v = fmaxf(v, 0.f);
        out[i] = v;
    }
}

// ---------------------------------------------------------------- softmax rows of 64 + sT bf16
__global__ __launch_bounds__(256) void softmaxT_kernel(float* __restrict__ s,
                                                       unsigned short* __restrict__ sT,
                                                       int sStride, float invtau){
    __shared__ unsigned short st[64][65];
    int blk = blockIdx.x, t = threadIdx.x, w = t >> 6, l = t & 63;
    #pragma unroll
    for (int i = 0; i < 16; ++i){
        int rloc = w + 4*i;
        long row = (long)blk*64 + rloc;
        float v = s[row*64 + l] * invtau;
        float mx = waveMax(v);
        float e = expf(v - mx);
        float sum = waveSum(e);
        float p = e / sum;
        s[row*64 + l] = p;
        st[l][rloc] = f2bf(p);
    }
    __syncthreads();
    int k = t >> 2, j = (t & 3)*16;
    unsigned short vbuf[16] __attribute__((aligned(16)));
    #pragma unroll
    for (int q = 0; q < 16; ++q) vbuf[q] = st[k][j+q];
    long off = (long)k*sStride + (long)blk*64 + j;
    *(uint4*)(sT + off)     = *(uint4*)&vbuf[0];
    *(uint4*)(sT + off + 8) = *(uint4*)&vbuf[8];
}

// ---------------------------------------------------------------- MFMA sT @ feaT^T -> part per (b,chunk) (pad-40)
__global__ __launch_bounds__(256) void stx_mfma_kernel(const unsigned short* __restrict__ sT,
                                                       const unsigned short* __restrict__ feaT,
                                                       float* __restrict__ part,
                                                       int N, int split, int sStride){
    __shared__ short tA[64*40], tB[256*40];
    int tid = threadIdx.x;
    int z = blockIdx.x, b = z / split, chunk = z % split;
    int L = N / split, kst = chunk * L;
    const unsigned short* sTb = sT + (long)b*N;
    const unsigned short* fT  = feaT + (long)b*256*N;
    int w = tid >> 6, l = tid & 63;
    int lg = l >> 4, lr = l & 15;
    f32x4 zero = {0.f, 0.f, 0.f, 0.f};
    f32x4 acc[4][4];
    #pragma unroll
    for (int i = 0; i < 4; ++i)
        #pragma unroll
        for (int j = 0; j < 4; ++j) acc[i][j] = zero;
    int srow = tid >> 2, koff = (tid & 3)*8;
    for (int kt = kst; kt < kst + L; kt += 32){
        __syncthreads();
        *(uint4*)(tA + srow*40 + koff) = *(const uint4*)(sTb + (long)srow*sStride + kt + koff);
        #pragma unroll
        for (int p = 0; p < 4; ++p){
            int row = srow + p*64;
            *(uint4*)(tB + row*40 + koff) = *(const uint4*)(fT + (long)row*N + kt + koff);
        }
        __syncthreads();
        bf16x8 af[4], bfr[4];
        #pragma unroll
        for (int f = 0; f < 4; ++f){
            af[f]  = *(const bf16x8*)(tA + (f*16 + lr)*40 + lg*8);
            bfr[f] = *(const bf16x8*)(tB + (w*64 + f*16 + lr)*40 + lg*8);
        }
        #pragma unroll
        for (int i = 0; i < 4; ++i)
            #pragma unroll
            for (int j = 0; j < 4; ++j)
                acc[i][j] = __builtin_amdgcn_mfma_f32_16x16x32_bf16(af[i], bfr[j], acc[i][j], 0, 0, 0);
    }
    float* outp = part + (long)z*64*256;
    #pragma unroll
    for (int fi = 0; fi < 4; ++fi){
        #pragma unroll
        for (int fj = 0; fj < 4; ++fj){
            #pragma unroll
            for (int r = 0; r < 4; ++r){
                int kc = fi*16 + lg*4 + r;
                int cc = w*64 + fj*16 + lr;
                outp[(long)kc*256 + cc] = acc[fi][fj][r];
            }
        }
    }
}

// ---------------------------------------------------------------- row softmax (K<=64), in place
__global__ void softmax_kernel(float* __restrict__ x, int Kc, float tau){
    int row = blockIdx.x, lane = threadIdx.x;
    bool act = lane < Kc;
    float v = act ? x[(long)row*Kc + lane] / tau : -1e30f;
    float mx = v;
    #pragma unroll
    for (int o = 32; o; o >>= 1) mx = fmaxf(mx, __shfl_xor(mx, o, 64));
    float e = act ? expf(v - mx) : 0.f;
    float s = e;
    #pragma unroll
    for (int o = 32; o; o >>= 1) s += __shfl_xor(s, o, 64);
    if (act) x[(long)row*Kc + lane] = e / s;
}

// ---------------------------------------------------------------- cluster xyz sums + denom (raw)
__global__ void cluster_xyz_kernel(const float* __restrict__ s, const float* __restrict__ xyz,
                                   float* __restrict__ outx, float* __restrict__ outd,
                                   int N, int Kc, int xBS, int dBS){
    __shared__ float red[256];
    int b = blockIdx.y, k = blockIdx.x, t = threadIdx.x;
    s   += (long)b*N*Kc;
    xyz += (long)b*N*3;
    float a0=0,a1=0,a2=0,ad=0;
    for (int n = t; n < N; n += 256){
        float sv = s[(long)n*Kc + k];
        ad += sv;
        a0 += sv*xyz[n*3+0]; a1 += sv*xyz[n*3+1]; a2 += sv*xyz[n*3+2];
    }
    a0 = blockReduceSum(a0, red, 256);
    a1 = blockReduceSum(a1, red, 256);
    a2 = blockReduceSum(a2, red, 256);
    ad = blockReduceSum(ad, red, 256);
    if (t == 0){
        outx[b*xBS + k*3+0] = a0;
        outx[b*xBS + k*3+1] = a1;
        outx[b*xBS + k*3+2] = a2;
        outd[b*dBS + k] = ad;
    }
}

// ---------------------------------------------------------------- f32 sTX for tiny global stage (split over n)
__global__ __launch_bounds__(256) void gemm_sTX_kernel(const float* __restrict__ s,
                                                       const float* __restrict__ X,
                                                       float* __restrict__ part,
                                                       int N, int Kc, int split,
                                                       long sBS, long xBS){
    __shared__ float sa[32][65], sb[32][65];
    int tid = threadIdx.x, tx = tid & 15, ty = tid >> 4;
    int c0 = blockIdx.x * 64;
    int b = blockIdx.z / split, chunk = blockIdx.z % split;
    int L = N / split, nst = chunk * L;
    s += b*sBS; X += b*xBS;
    float* out = part + (long)blockIdx.z * Kc * 256;
    float acc[4][4] = {};
    for (int nt = nst; nt < nst + L; nt += 32){
        #pragma unroll
        for (int p = 0; p < 8; ++p){
            int idx = p*256 + tid;
            int i = idx & 63, k = idx >> 6;
            sa[k][i] = (i < Kc) ? s[(long)(nt+k)*Kc + i] : 0.f;
            int j = idx & 63, kk = idx >> 6;
            sb[kk][j] = X[(long)(nt+kk)*256 + c0 + j];
        }
        __syncthreads();
        #pragma unroll
        for (int k = 0; k < 32; ++k){
            float a0=sa[k][ty*4+0],a1=sa[k][ty*4+1],a2=sa[k][ty*4+2],a3=sa[k][ty*4+3];
            float b0=sb[k][tx*4+0],b1=sb[k][tx*4+1],b2=sb[k][tx*4+2],b3=sb[k][tx*4+3];
            acc[0][0]+=a0*b0; acc[0][1]+=a0*b1; acc[0][2]+=a0*b2; acc[0][3]+=a0*b3;
            acc[1][0]+=a1*b0; acc[1][1]+=a1*b1; acc[1][2]+=a1*b2; acc[1][3]+=a1*b3;
            acc[2][0]+=a2*b0; acc[2][1]+=a2*b1; acc[2][2]+=a2*b2; acc[2][3]+=a2*b3;
            acc[3][0]+=a3*b0; acc[3][1]+=a3*b1; acc[3][2]+=a3*b2; acc[3][3]+=a3*b3;
        }
        __syncthreads();
    }
    #pragma unroll
    for (int r = 0; r < 4; ++r){
        int kc = ty*4 + r;
        if (kc < Kc){
            #pragma unroll
            for (int c = 0; c < 4; ++c)
                out[(long)kc*256 + c0 + tx*4 + c] = acc[r][c];
        }
    }
}

// ---------------------------------------------------------------- sum partials, divide by denom
__global__ void divide_sum_kernel(const float* __restrict__ part, const float* __restrict__ den,
                                  float* __restrict__ cfea, float* __restrict__ cxyz,
                                  int Kc, int split, int fBS, int xBS, int dBS){
    int b = blockIdx.y, k = blockIdx.x, t = threadIdx.x;
    float d = den[b*dBS + k] + EPSF;
    float s = 0.f;
    for (int q = 0; q < split; ++q)
        s += part[((long)(b*split+q)*Kc + k)*256 + t];
    cfea[(long)b*fBS + k*256 + t] = s / d;
    if (t < 3) cxyz[b*xBS + k*3 + t] /= d;
}

// ---------------------------------------------------------------- level losses: wave per point, cfea staged in LDS
__global__ __launch_bounds__(256) void level_loss_kernel(const float* __restrict__ s,
                                                         const float* __restrict__ pxyz,
                                                         const float* __restrict__ cxyz,
                                                         const float* __restrict__ cfea,
                                                         const unsigned short* __restrict__ nfb,
                                                         float* __restrict__ scal,
                                                         int N, float inv, int ndsSlot){
    __shared__ float cf[64*256];
    __shared__ float cx[192];
    __shared__ float partA[4], partN[4];
    int b = blockIdx.y, t = threadIdx.x, w = t >> 6, l = t & 63;
    s    += (long)b*N*64;
    pxyz += (long)b*N*3;
    nfb  += (long)b*N*256;
    cxyz += (long)b*384;
    cfea += (long)b*32768;
    for (int i = t; i < 4096; i += 256)
        ((float4*)cf)[i] = ((const float4*)cfea)[i];
    if (t < 192) cx[t] = cxyz[t];
    __syncthreads();
    int n = blockIdx.x*4 + w;
    float sl = s[(long)n*64 + l];
    float px = pxyz[n*3+0], py = pxyz[n*3+1], pz = pxyz[n*3+2];
    float dx = px - cx[l*3+0], dy = py - cx[l*3+1], dz = pz - cx[l*3+2];
    float d2 = dx*dx + dy*dy + dz*dz;
    float assSum = waveSum(sl*d2);
    float dmin = waveMin(d2);
    float c0=0,c1=0,c2=0,c3=0;
    #pragma unroll 8
    for (int k = 0; k < 64; ++k){
        float sk = __shfl(sl, k, 64);
        const float* row = cf + k*256;
        c0 += sk*row[l]; c1 += sk*row[l+64]; c2 += sk*row[l+128]; c3 += sk*row[l+192];
    }
    float nrm2 = waveSum(c0*c0 + c1*c1 + c2*c2 + c3*c3);
    float inrm = 1.f / fmaxf(sqrtf(nrm2), 1e-12f);
    const unsigned short* nfr = nfb + (long)n*256;
    float e0 = c0*inrm - bf2f(nfr[l]);
    float e1 = c1*inrm - bf2f(nfr[l+64]);
    float e2 = c2*inrm - bf2f(nfr[l+128]);
    float e3 = c3*inrm - bf2f(nfr[l+192]);
    float nds = waveSum(e0*e0 + e1*e1 + e2*e2 + e3*e3);
    if (l == 0){
        partA[w] = inv*(assSum + 1.f - expf(-0.5f*dmin));
        partN[w] = nds;
    }
    __syncthreads();
    if (t == 0){
        int slot = blockIdx.x & 63;
        atomicAdd(&scal[slot], partA[0]+partA[1]+partA[2]+partA[3]);
        atomicAdd(&scal[ndsSlot*64 + slot], partN[0]+partN[1]+partN[2]+partN[3]);
    }
}

// ---------------------------------------------------------------- knn affinity -> normalized adjacency, fully in LDS
__global__ __launch_bounds__(128) void knn_nac_kernel(const float* __restrict__ cxyz,
                                                      float* __restrict__ nac){
    __shared__ float d2s[128][129];
    __shared__ float x[128][3];
    __shared__ float di[128];
    int b = blockIdx.x, n = threadIdx.x;
    x[n][0] = cxyz[b*384 + n*3+0];
    x[n][1] = cxyz[b*384 + n*3+1];
    x[n][2] = cxyz[b*384 + n*3+2];
    __syncthreads();
    float xn0 = x[n][0], xn1 = x[n][1], xn2 = x[n][2];
    for (int m = 0; m < 128; ++m){
        float dx = xn0-x[m][0], dy = xn1-x[m][1], dz = xn2-x[m][2];
        d2s[n][m] = dx*dx+dy*dy+dz*dz + (m==n ? 1e6f : 0.f);
    }
    float last = -1.f;
    for (int p = 0; p < 8; ++p){
        float cur = 1e30f;
        for (int m = 0; m < 128; ++m){
            float v = d2s[n][m];
            if (v > last && v < cur) cur = v;
        }
        last = cur;
    }
    for (int m = 0; m < 128; ++m){
        float d2 = d2s[n][m];
        d2s[n][m] = (m != n && d2 <= last) ? expf(-d2) : 0.f;
    }
    __syncthreads();
    for (int m = 0; m < 128; ++m){
        float v = fmaxf(d2s[n][m], d2s[m][n]);
        d2s[n][m] = v;
    }
    __syncthreads();
    float deg = 0.f;
    for (int m = 0; m < 128; ++m) deg += d2s[n][m];
    di[n] = rsqrtf(deg + EPSF);
    __syncthreads();
    float* Ab = nac + (long)b*16384;
    for (int c = 0; c < 128; ++c)
        Ab[c*128 + n] = d2s[c][n] * di[c] * di[n];
}

// ---------------------------------------------------------------- Y2 = na_c @ cfea
__global__ void bmm_small_kernel(const float* __restrict__ nac, const float* __restrict__ cfea,
                                 float* __restrict__ Y2){
    __shared__ float row[128];
    int b = blockIdx.y, n = blockIdx.x, t = threadIdx.x;
    if (t < 128) row[t] = nac[(long)b*16384 + n*128 + t];
    __syncthreads();
    float acc = 0.f;
    #pragma unroll 4
    for (int k = 0; k < 128; ++k) acc += row[k]*cfea[(long)b*32768 + k*256 + t];
    Y2[(long)b*32768 + n*256 + t] = acc;
}

// ---------------------------------------------------------------- cut_loss_c
__global__ void cutc_kernel(const float* __restrict__ gs, const float* __restrict__ cxyz,
                            const float* __restrict__ cxyzg, float* __restrict__ scal, float inv){
    __shared__ float cg[48];
    __shared__ float red[128];
    int b = blockIdx.x, t = threadIdx.x;
    if (t < 48) cg[t] = cxyzg[b*48 + t];
    __syncthreads();
    float x0 = cxyz[b*384 + t*3+0], x1 = cxyz[b*384 + t*3+1], x2 = cxyz[b*384 + t*3+2];
    float acc = 0.f;
    #pragma unroll
    for (int k = 0; k < 16; ++k){
        float dx = x0-cg[k*3+0], dy = x1-cg[k*3+1], dz = x2-cg[k*3+2];
        acc += gs[b*2048 + t*16 + k]*(dx*dx+dy*dy+dz*dz);
    }
    acc = blockReduceSum(acc, red, 128);
    if (t == 0) atomicAdd(&scal[b], acc*inv);
}

// ---------------------------------------------------------------- cross attention (M=16) -> AO bf16
__global__ __launch_bounds__(256) void attn_kernel(const float* __restrict__ q,
                                                   const float* __restrict__ kk,
                                                   const float* __restrict__ vv,
                                                   unsigned short* __restrict__ aob){
    __shared__ float Ks[16][256], Vs[16][256];
    int b = blockIdx.y, n = blockIdx.x, t = threadIdx.x;
    #pragma unroll
    for (int p = 0; p < 16; ++p){
        int j = p*256 + t;
        Ks[j>>8][j&255] = kk[b*4096 + j];
        Vs[j>>8][j&255] = vv[b*4096 + j];
    }
    __syncthreads();
    float qv = q[((long)b*1024 + n)*256 + t];
    float sc[16];
    #pragma unroll
    for (int m = 0; m < 16; ++m){
        float v = qv * Ks[m][t];
        #pragma unroll
        for (int o = 32; o; o >>= 1) v += __shfl_xor(v, o, 64);
        sc[m] = v * 0.125f;
    }
    float mx = -1e30f;
    #pragma unroll
    for (int m = 0; m < 16; ++m) mx = fmaxf(mx, sc[m]);
    float sum = 0.f;
    #pragma unroll
    for (int m = 0; m < 16; ++m){ sc[m] = expf(sc[m]-mx); sum += sc[m]; }
    float o = 0.f;
    #pragma unroll
    for (int m = 0; m < 16; ++m) o += sc[m]*Vs[m][t];
    aob[((long)b*1024 + n)*256 + t] = f2bf(o / sum);
}

// ---------------------------------------------------------------- quad: wave per row, bf16 A (N=1024), deg-based
__global__ void quad_kernel(const unsigned short* __restrict__ A, const float* __restrict__ deg,
                            const float* __restrict__ xyz, float* __restrict__ scal){
    __shared__ float part[4];
    int t = threadIdx.x, w = t >> 6, l = t & 63;
    int n = blockIdx.x*4 + w;
    float a0=0,a1=0,a2=0;
    #pragma unroll 4
    for (int i = 0; i < 16; ++i){
        int m = l + i*64;
        float wv = bf2f(A[(long)n*1024 + m])*rsqrtf(deg[m] + EPSF);
        a0 += wv*xyz[m*3+0]; a1 += wv*xyz[m*3+1]; a2 += wv*xyz[m*3+2];
    }
    a0 = waveSum(a0); a1 = waveSum(a1); a2 = waveSum(a2);
    if (l == 0){
        float x0 = xyz[n*3+0], x1 = xyz[n*3+1], x2 = xyz[n*3+2];
        float dn = rsqrtf(deg[n] + EPSF);
        part[w] = (x0*x0+x1*x1+x2*x2) - dn*(x0*a0+x1*a1+x2*a2);
    }
    __syncthreads();
    if (t == 0) atomicAdd(&scal[4*64 + (blockIdx.x & 63)], part[0]+part[1]+part[2]+part[3]);
}

// ---------------------------------------------------------------- g_loss per-row: wave per row
__global__ void gloss_kernel(const float* __restrict__ agg, const float* __restrict__ gfea,
                             float* __restrict__ scal){
    __shared__ float part[4];
    int t = threadIdx.x, w = t >> 6, l = t & 63;
    long r = (long)blockIdx.x*4 + w;
    const float* a = agg + r*256;
    const float* g = gfea + r*256;
    float a0=a[l],a1=a[l+64],a2=a[l+128],a3=a[l+192];
    float g0=g[l],g1=g[l+64],g2=g[l+128],g3=g[l+192];
    float na2 = waveSum(a0*a0+a1*a1+a2*a2+a3*a3);
    float ng2 = waveSum(g0*g0+g1*g1+g2*g2+g3*g3);
    float ia = 1.f/fmaxf(sqrtf(na2), 1e-12f), ig = 1.f/fmaxf(sqrtf(ng2), 1e-12f);
    float e0=a0*ia-g0*ig, e1=a1*ia-g1*ig, e2=a2*ia-g2*ig, e3=a3*ia-g3*ig;
    float d2 = waveSum(e0*e0+e1*e1+e2*e2+e3*e3);
    if (l == 0) part[w] = sqrtf(d2);
    __syncthreads();
    if (t == 0) atomicAdd(&scal[3*64 + (blockIdx.x & 63)], part[0]+part[1]+part[2]+part[3]);
}

// ---------------------------------------------------------------- finalize
__global__ void finalize_kernel(const float* __restrict__ scal, float* __restrict__ out){
    int t = threadIdx.x;
    float s[5];
    #pragma unroll
    for (int q = 0; q < 5; ++q){
        float v = scal[q*64 + t];
        #pragma unroll
        for (int o = 32; o; o >>= 1) v += __shfl_xor(v, o, 64);
        s[q] = v;
    }
    if (t == 0){
        out[524288] = s[0] + sqrtf(s[1]) + sqrtf(s[2]);
        out[524289] = s[3]*0.5f + 1e-4f*s[4]/2048.0f;
    }
}

// ================================================================ launcher
extern "C" void kernel_launch(void* const* d_in, const int* in_sizes, int n_in,
                              void* d_out, int out_size, void* d_ws, size_t ws_size,
                              hipStream_t stream){
    const float* g_fea   = (const float*)d_in[0];
    const float* g_xyz   = (const float*)d_in[1];
    const float* p_fea_0 = (const float*)d_in[2];
    const float* p_xyz_0 = (const float*)d_in[3];
    const float* p_fea_1 = (const float*)d_in[4];
    const float* p_xyz_1 = (const float*)d_in[5];
    const float* lW1 = (const float*)d_in[6];
    const float* lb1 = (const float*)d_in[7];
    const float* lW2 = (const float*)d_in[8];
    const float* lb2 = (const float*)d_in[9];
    const float* gW1 = (const float*)d_in[10];
    const float* gb1 = (const float*)d_in[11];
    const float* gW2 = (const float*)d_in[12];
    const float* gb2 = (const float*)d_in[13];
    const float* Wq = (const float*)d_in[14];
    const float* Wk = (const float*)d_in[15];
    const float* Wv = (const float*)d_in[16];
    const float* Wo = (const float*)d_in[17];
    float* out = (float*)d_out;
    float* ws_f = (float*)d_ws;

    // ---- workspace layout (float units)
    constexpr long O_SCALS = 0;                        // 512
    constexpr long O_DEG   = 512;                      // 14336
    constexpr long O_CFEA  = 16384;                    // 65536
    constexpr long O_CXYZ  = 81920;                    // 768
    constexpr long O_DEN   = 82688;                    // 256
    constexpr long O_CFG   = 82944;                    // 8192
    constexpr long O_CXG   = 91136;                    // 96
    constexpr long O_DENG  = 91232;                    // 64
    constexpr long O_NFB   = 91296;                    // bf16 (12288,256) = 1,572,864 f
    constexpr long O_XST   = O_NFB  + 1572864;         // bf16 (2,256,4096) = 1,048,576 f
    constexpr long O_FEAT  = O_XST  + 1048576;         // bf16 both levels = 1,572,864 f
    constexpr long O_YB    = O_FEAT + 1572864;         // bf16 (12288,256) = 1,572,864 f
    constexpr long O_HB    = O_YB   + 1572864;         // bf16 (12288,128) = 786,432 f
    constexpr long O_S     = O_HB   + 786432;          // f32 (12288,64) = 786,432 f
    constexpr long O_ST    = O_S    + 786432;          // bf16 (64,12288) = 393,216 f
    constexpr long O_PY    = O_ST   + 393216;          // 8,388,608 f: bf16 PYb (8x4096x256) / f32 part scratch
    constexpr long O_A     = O_PY   + 8388608;         // bf16 (4096,4096) = 8,388,608 f
    constexpr long O_Q     = O_A    + 8388608;         // 524288
    constexpr long O_GFB   = O_Q    + 524288;          // 262144
    constexpr long O_AOB   = O_GFB  + 262144;          // 262144
    constexpr long O_KK    = O_AOB  + 262144;          // 8192
    constexpr long O_VV    = O_KK   + 8192;            // 8192
    constexpr long O_NAC   = O_VV   + 8192;            // 32768
    constexpr long O_Y2    = O_NAC  + 32768;           // 65536
    constexpr long O_H2    = O_Y2   + 65536;           // 32768
    constexpr long O_LG2   = O_H2   + 32768;           // 4096
    constexpr long O_W1T   = O_LG2  + 4096;            // 16384
    constexpr long O_W2T   = O_W1T  + 16384;           // 4096
    constexpr long O_WQT   = O_W2T  + 4096;            // 32768
    constexpr long O_WOT   = O_WQT  + 32768;           // 32768

    hipMemsetAsync(ws_f + O_SCALS, 0, (512 + 14336)*sizeof(float), stream);

    unsigned short* nfb  = (unsigned short*)(ws_f + O_NFB);
    unsigned short* xsT  = (unsigned short*)(ws_f + O_XST);
    unsigned short* feaT = (unsigned short*)(ws_f + O_FEAT);
    unsigned short* Ybb  = (unsigned short*)(ws_f + O_YB);
    unsigned short* Hb   = (unsigned short*)(ws_f + O_HB);
    unsigned short* sTb  = (unsigned short*)(ws_f + O_ST);
    unsigned short* A    = (unsigned short*)(ws_f + O_A);
    unsigned short* gfb  = (unsigned short*)(ws_f + O_GFB);
    unsigned short* aob  = (unsigned short*)(ws_f + O_AOB);
    unsigned short* lW1T = (unsigned short*)(ws_f + O_W1T);
    unsigned short* lW2T = (unsigned short*)(ws_f + O_W2T);
    unsigned short* WqT  = (unsigned short*)(ws_f + O_WQT);
    unsigned short* WoT  = (unsigned short*)(ws_f + O_WOT);
    float* sb   = ws_f + O_S;
    float* degA = ws_f + O_DEG;
    float* PY   = ws_f + O_PY;                       // f32 scratch view
    unsigned short* PYb = (unsigned short*)(ws_f + O_PY);  // bf16 partials view
    float* Qf   = ws_f + O_Q;

    // weight conversions
    tcvt_kernel<<<dim3(4, 2), 256, 0, stream>>>(lW1, lW1T, 256, 128);
    tcvt_kernel<<<dim3(2, 1), 256, 0, stream>>>(lW2, lW2T, 128, 64);
    tcvt_kernel<<<dim3(4, 4), 256, 0, stream>>>(Wq, WqT, 256, 256);
    tcvt_kernel<<<dim3(4, 4), 256, 0, stream>>>(Wo, WoT, 256, 256);
    cvt_bf16_kernel<<<512, 256, 0, stream>>>(g_fea, gfb, 131072);

    struct Lvl { const float* fea; const float* xyz; int N; int k0; int ndsSlot; long degBase;
                 long rowOff; long featOff; };
    Lvl lv[2] = {{p_fea_0, p_xyz_0, 4096, 0, 1, 0, 0, 0},
                 {p_fea_1, p_xyz_1, 2048, 64, 2, 8192, 8192, 2097152}};

    // ---- phase 1: gram + GCN-aggregate for all (level, batch)
    for (int L = 0; L < 2; ++L){
        int N = lv[L].N;
        const float* fea = lv[L].fea;
        const float* xyz = lv[L].xyz;
        unsigned short* nfbL  = nfb + lv[L].rowOff*256;
        unsigned short* feaTL = feaT + lv[L].featOff;
        l2norm_kernel<<<2*N, 256, 0, stream>>>(fea, nfbL, 2*N);
        for (int b = 0; b < 2; ++b){
            float* degb = degA + lv[L].degBase + (long)b*N;
            gram_mfma_kernel<<<dim3(N/128, N/128), 256, 0, stream>>>(nfbL + (long)b*N*256,
                                                                     xyz + (long)b*N*3, A, degb,
                                                                     N, 1.0f, 0.25f);
            transpose_scale_kernel<<<dim3(N/64, 4), 256, 0, stream>>>(fea + (long)b*N*256, degb,
                                                                      feaTL + (long)b*256*N,
                                                                      xsT + (long)b*256*N, N);
            ax_mfma_kernel<<<dim3(2, N/128, 8), 256, 0, stream>>>(A, xsT + (long)b*256*N, PYb, N, 8);
            combine_kernel<<<N/8, 256, 0, stream>>>(PYb, degb,
                                                    Ybb + (lv[L].rowOff + (long)b*N)*256, N, 8);
        }
    }

    // ---- phase 2: fused MLP over all 12288 rows
    gemm_XW_mfma_kernel<<<dim3(1, 96), 256, 0, stream>>>(Ybb, lW1T, lb1, nullptr, Hb,
                                                         12288, 256, 128, 1);
    gemm_XW_mfma_kernel<<<dim3(1, 96), 256, 0, stream>>>(Hb, lW2T, lb2, sb, nullptr,
                                                         12288, 128, 64, 0);
    softmaxT_kernel<<<192, 256, 0, stream>>>(sb, sTb, 12288, 10.0f);

    // ---- phase 3: per-level cluster stats + losses
    for (int L = 0; L < 2; ++L){
        int N = lv[L].N;
        const float* xyz = lv[L].xyz;
        float* sL = sb + lv[L].rowOff*64;
        cluster_xyz_kernel<<<dim3(64, 2), 256, 0, stream>>>(sL, xyz, ws_f + O_CXYZ + lv[L].k0*3,
                                                            ws_f + O_DEN + lv[L].k0, N, 64, 384, 128);
        stx_mfma_kernel<<<32, 256, 0, stream>>>(sTb + lv[L].rowOff, feaT + lv[L].featOff,
                                                PY, N, 16, 12288);
        divide_sum_kernel<<<dim3(64, 2), 256, 0, stream>>>(PY, ws_f + O_DEN + lv[L].k0,
                                                           ws_f + O_CFEA + lv[L].k0*256,
                                                           ws_f + O_CXYZ + lv[L].k0*3,
                                                           64, 16, 128*256, 384, 128);
        level_loss_kernel<<<dim3(N/4, 2), 256, 0, stream>>>(sL, xyz, ws_f + O_CXYZ + lv[L].k0*3,
                                                            ws_f + O_CFEA + lv[L].k0*256,
                                                            nfb + lv[L].rowOff*256,
                                                            ws_f + O_SCALS, N, 1.0f/(2.0f*N), lv[L].ndsSlot);
    }

    // ---- global cluster stage
    knn_nac_kernel<<<2, 128, 0, stream>>>(ws_f + O_CXYZ, ws_f + O_NAC);
    bmm_small_kernel<<<dim3(128, 2), 256, 0, stream>>>(ws_f + O_NAC, ws_f + O_CFEA, ws_f + O_Y2);
    gemm_splitk_kernel<<<dim3(2, 4, 4), 256, 0, stream>>>(ws_f + O_Y2, gW1, nullptr, PY,
                                                          256, 256, 128, 4);
    combine_bias_kernel<<<128, 256, 0, stream>>>(PY, gb1, ws_f + O_H2, 256, 128, 4, 1);
    gemm_splitk_kernel<<<dim3(1, 4, 4), 256, 0, stream>>>(ws_f + O_H2, gW2, nullptr, PY,
                                                          256, 128, 16, 4);
    combine_bias_kernel<<<16, 256, 0, stream>>>(PY, gb2, ws_f + O_LG2, 256, 16, 4, 0);
    softmax_kernel<<<256, 64, 0, stream>>>(ws_f + O_LG2, 16, 0.1f);
    cluster_xyz_kernel<<<dim3(16, 2), 256, 0, stream>>>(ws_f + O_LG2, ws_f + O_CXYZ,
                                                        ws_f + O_CXG, ws_f + O_DENG, 128, 16, 48, 16);
    gemm_sTX_kernel<<<dim3(4, 1, 8), 256, 0, stream>>>(ws_f + O_LG2, ws_f + O_CFEA, PY,
                                                       128, 16, 4, 128L*16, 128L*256);
    divide_sum_kernel<<<dim3(16, 2), 256, 0, stream>>>(PY, ws_f + O_DENG, ws_f + O_CFG,
                                                       ws_f + O_CXG, 16, 4, 16*256, 48, 16);
    cutc_kernel<<<2, 128, 0, stream>>>(ws_f + O_LG2, ws_f + O_CXYZ, ws_f + O_CXG,
                                       ws_f + O_SCALS, 1.0f/256.0f);

    // ---- cross attention
    gemm_XW_mfma_kernel<<<dim3(2, 16), 256, 0, stream>>>(gfb, WqT, nullptr, Qf, nullptr,
                                                         2048, 256, 256, 0);
    gemm_splitk_kernel<<<dim3(4, 1, 16), 256, 0, stream>>>(ws_f + O_CFG, Wk, Wv, PY,
                                                           32, 256, 256, 8);
    combine_bias_kernel<<<32, 256, 0, stream>>>(PY, nullptr, ws_f + O_KK, 32, 256, 8, 0);
    combine_bias_kernel<<<32, 256, 0, stream>>>(PY + 8L*32*256, nullptr, ws_f + O_VV, 32, 256, 8, 0);
    attn_kernel<<<dim3(1024, 2), 256, 0, stream>>>(Qf, ws_f + O_KK, ws_f + O_VV, aob);
    gemm_XW_mfma_kernel<<<dim3(2, 16), 256, 0, stream>>>(aob, WoT, nullptr, out, nullptr,
                                                         2048, 256, 256, 0);

    // ---- A_g stage (reuses nfb head + A + deg tail)
    l2norm_kernel<<<2048, 256, 0, stream>>>(g_fea, nfb, 2048);
    for (int b = 0; b < 2; ++b){
        float* degb = degA + 12288 + (long)b*1024;
        gram_mfma_kernel<<<dim3(8, 8), 256, 0, stream>>>(nfb + (long)b*1024*256, g_xyz + (long)b*1024*3,
                                                         A, degb, 1024, 16.0f, 0.25f);
        quad_kernel<<<256, 256, 0, stream>>>(A, degb, g_xyz + (long)b*1024*3, ws_f + O_SCALS);
    }

    gloss_kernel<<<512, 256, 0, stream>>>(out, g_fea, ws_f + O_SCALS);
    finalize_kernel<<<1, 64, 0, stream>>>(ws_f + O_SCALS, out);
}